// Round 1
// baseline (2403.179 us; speedup 1.0000x reference)
//
#include <hip/hip_runtime.h>
#include <math.h>

#define NEG_SLOPE 0.2f

// ---------------- GEMM: C[N,M] = A[N,K] @ B[K,M] (+bias) ----------------
// 256 threads/block. Each thread: 1 col x 8 rows. rows/block = 2048/M.
template<int M>
__global__ void gemm_kernel(const float* __restrict__ A, const float* __restrict__ B,
                            const float* __restrict__ bias, float* __restrict__ C,
                            int Nrows, int K, int kshift) {
    constexpr int ROWS = 2048 / M;                 // 8 (M=256) or 32 (M=64)
    const int col  = threadIdx.x & (M - 1);
    const int rsub = threadIdx.x / M;
    const int rowBase = rsub * 8;
    const int blockRow = blockIdx.x * ROWS;
    extern __shared__ float ldsA[];
    const int total = ROWS << kshift;
    for (int i = threadIdx.x; i < total; i += 256) {
        int r = i >> kshift;
        int k = i & (K - 1);
        int row = blockRow + r;
        ldsA[i] = (row < Nrows) ? A[((size_t)row << kshift) + k] : 0.0f;
    }
    __syncthreads();
    float acc[8] = {0,0,0,0,0,0,0,0};
    for (int k = 0; k < K; k += 4) {
        float b0 = B[(k+0)*M + col];
        float b1 = B[(k+1)*M + col];
        float b2 = B[(k+2)*M + col];
        float b3 = B[(k+3)*M + col];
        #pragma unroll
        for (int r = 0; r < 8; r++) {
            const float4 a = *(const float4*)&ldsA[((rowBase + r) << kshift) + k];
            acc[r] += a.x*b0 + a.y*b1 + a.z*b2 + a.w*b3;
        }
    }
    float bv = bias ? bias[col] : 0.0f;
    #pragma unroll
    for (int r = 0; r < 8; r++) {
        int row = blockRow + rowBase + r;
        if (row < Nrows) C[(size_t)row * M + col] = acc[r] + bv;
    }
}

// ------------- per-node attention scores: a_s[n,h] = sum_c hW[n,h,c]*att_s[h,c] -------------
template<int H>
__global__ void att_scores_kernel(const float* __restrict__ hW,
                                  const float* __restrict__ att_s, const float* __restrict__ att_d,
                                  float* __restrict__ a_s, float* __restrict__ a_d, int N) {
    const int lane = threadIdx.x & 63;
    const int n = blockIdx.x * 4 + (threadIdx.x >> 6);
    if (n >= N) return;
    #pragma unroll
    for (int h = 0; h < H; h++) {
        float v = hW[(size_t)n * (H * 64) + h * 64 + lane];
        float s = v * att_s[h * 64 + lane];
        float d = v * att_d[h * 64 + lane];
        #pragma unroll
        for (int off = 32; off > 0; off >>= 1) {
            s += __shfl_xor(s, off);
            d += __shfl_xor(d, off);
        }
        if (lane == 0) { a_s[n * H + h] = s; a_d[n * H + h] = d; }
    }
}

// ------------- edge pass 1: den[dst,h] += exp(leaky(a_s[src,h]+a_d[dst,h])) -------------
// Note: softmax is shift-invariant; we use m=0 (scores are O(0.1), exp is safe).
template<int H>
__global__ void edge_den_kernel(const int* __restrict__ ei, const float* __restrict__ a_s,
                                const float* __restrict__ a_d, float* __restrict__ den,
                                int E, int Et) {
    int t = blockIdx.x * 256 + threadIdx.x;
    if (t >= Et * H) return;
    int e = (H == 1) ? t : (t >> 2);
    int h = (H == 1) ? 0 : (t & 3);
    int s, d;
    if (e < E) { s = ei[e]; d = ei[E + e]; } else { s = d = e - E; }
    float ev = a_s[s * H + h] + a_d[d * H + h];
    ev = (ev >= 0.0f) ? ev : NEG_SLOPE * ev;
    atomicAdd(&den[d * H + h], expf(ev));
}

// ------------- edge pass 2: out[dst,h,c] += hW[src,h,c] * alpha(e,h) -------------
// one wave per edge; lane = channel
template<int H>
__global__ void edge_scatter_kernel(const int* __restrict__ ei, const float* __restrict__ hW,
                                    const float* __restrict__ a_s, const float* __restrict__ a_d,
                                    const float* __restrict__ den, float* __restrict__ out,
                                    int E, int Et) {
    const int e = blockIdx.x * 4 + (threadIdx.x >> 6);
    if (e >= Et) return;
    const int lane = threadIdx.x & 63;
    int s, d;
    if (e < E) { s = ei[e]; d = ei[E + e]; } else { s = d = e - E; }
    #pragma unroll
    for (int h = 0; h < H; h++) {
        float ev = a_s[s * H + h] + a_d[d * H + h];
        ev = (ev >= 0.0f) ? ev : NEG_SLOPE * ev;
        float alpha = expf(ev) / (den[d * H + h] + 1e-16f);
        float v = hW[(size_t)s * (H * 64) + h * 64 + lane];
        atomicAdd(&out[(size_t)d * (H * 64) + h * 64 + lane], v * alpha);
    }
}

// ------------- bias + optional ELU, elementwise -------------
template<bool ELU>
__global__ void bias_act_kernel(float* __restrict__ buf, const float* __restrict__ bias,
                                int total, int Mmask) {
    int i = blockIdx.x * 256 + threadIdx.x;
    if (i >= total) return;
    float v = buf[i] + bias[i & Mmask];
    if (ELU) v = (v > 0.0f) ? v : expm1f(v);
    buf[i] = v;
}

// ------------- per-graph mean pool (batch is sorted) -------------
// wave per contiguous node chunk; register accumulate, flush on graph change
__global__ void pool_kernel(const float* __restrict__ h, const int* __restrict__ batch,
                            float* __restrict__ pooled, float* __restrict__ cnt,
                            int N, int nWaves) {
    const int w = blockIdx.x * 4 + (threadIdx.x >> 6);
    const int lane = threadIdx.x & 63;
    const int chunk = (N + nWaves - 1) / nWaves;
    int start = w * chunk;
    int end = min(N, start + chunk);
    if (start >= end) return;
    int curg = batch[start];
    int runStart = start;
    float acc = 0.0f;
    for (int n = start; n < end; n++) {
        int g = batch[n];
        if (g != curg) {
            atomicAdd(&pooled[curg * 64 + lane], acc);
            if (lane == 0) atomicAdd(&cnt[curg], (float)(n - runStart));
            acc = 0.0f; curg = g; runStart = n;
        }
        acc += h[(size_t)n * 64 + lane];
    }
    atomicAdd(&pooled[curg * 64 + lane], acc);
    if (lane == 0) atomicAdd(&cnt[curg], (float)(end - runStart));
}

// ------------- decoder head: tiny, single block -------------
__global__ void final_kernel(const float* __restrict__ pooled, const float* __restrict__ cnt,
                             const float* __restrict__ gf, const float* __restrict__ Wg,
                             const float* __restrict__ bg, const float* __restrict__ Wd1,
                             const float* __restrict__ bd1, const float* __restrict__ gamma,
                             const float* __restrict__ beta, const float* __restrict__ Wd2,
                             const float* __restrict__ bd2, float* __restrict__ out, int G) {
    __shared__ float sp[16 * 64], sg[16 * 64], sz[16 * 64], slog[16 * 256];
    const int tid = threadIdx.x;
    for (int i = tid; i < G * 64; i += 256) {
        int g = i >> 6;
        sp[i] = pooled[i] / fmaxf(cnt[g], 1.0f);
    }
    for (int i = tid; i < G * 64; i += 256) {
        int g = i >> 6, c = i & 63;
        float v = bg[c];
        #pragma unroll
        for (int k = 0; k < 4; k++) v += gf[g * 4 + k] * Wg[k * 64 + c];
        sg[i] = fmaxf(v, 0.0f);
    }
    __syncthreads();
    for (int i = tid; i < G * 64; i += 256) {
        int g = i >> 6, c = i & 63;
        float v = bd1[c];
        for (int k = 0; k < 64; k++) v += sp[g * 64 + k] * Wd1[k * 64 + c];
        for (int k = 0; k < 64; k++) v += sg[g * 64 + k] * Wd1[(64 + k) * 64 + c];
        v = v * gamma[c] + beta[c];
        sz[i] = fmaxf(v, 0.0f);
    }
    __syncthreads();
    for (int i = tid; i < G * 256; i += 256) {
        int g = i >> 8, j = i & 255;
        float v = bd2[j];
        for (int k = 0; k < 64; k++) v += sz[g * 64 + k] * Wd2[k * 256 + j];
        slog[i] = v;
    }
    __syncthreads();
    const int wid = tid >> 6, lane = tid & 63;
    for (int g = wid; g < G; g += 4) {
        float v0 = slog[g * 256 + lane],       v1 = slog[g * 256 + 64 + lane],
              v2 = slog[g * 256 + 128 + lane], v3 = slog[g * 256 + 192 + lane];
        float m = fmaxf(fmaxf(v0, v1), fmaxf(v2, v3));
        #pragma unroll
        for (int off = 32; off > 0; off >>= 1) m = fmaxf(m, __shfl_xor(m, off));
        float e0 = expf(v0 - m), e1 = expf(v1 - m), e2 = expf(v2 - m), e3 = expf(v3 - m);
        float s = e0 + e1 + e2 + e3;
        #pragma unroll
        for (int off = 32; off > 0; off >>= 1) s += __shfl_xor(s, off);
        float inv = 1.0f / s;
        out[g * 256 + lane]        = e0 * inv;
        out[g * 256 + 64 + lane]   = e1 * inv;
        out[g * 256 + 128 + lane]  = e2 * inv;
        out[g * 256 + 192 + lane]  = e3 * inv;
    }
}

extern "C" void kernel_launch(void* const* d_in, const int* in_sizes, int n_in,
                              void* d_out, int out_size, void* d_ws, size_t ws_size,
                              hipStream_t stream) {
    const float* x     = (const float*)d_in[0];
    const int*   ei    = (const int*)  d_in[1];
    const int*   batch = (const int*)  d_in[2];
    const float* gf    = (const float*)d_in[3];
    const float* W_enc = (const float*)d_in[4];
    const float* b_enc = (const float*)d_in[5];
    const float* W1  = (const float*)d_in[6];
    const float* as1 = (const float*)d_in[7];
    const float* ad1 = (const float*)d_in[8];
    const float* b1  = (const float*)d_in[9];
    const float* W2  = (const float*)d_in[10];
    const float* as2 = (const float*)d_in[11];
    const float* ad2 = (const float*)d_in[12];
    const float* b2  = (const float*)d_in[13];
    const float* W3  = (const float*)d_in[14];
    const float* as3 = (const float*)d_in[15];
    const float* ad3 = (const float*)d_in[16];
    const float* b3  = (const float*)d_in[17];
    const float* Wg  = (const float*)d_in[18];
    const float* bg  = (const float*)d_in[19];
    const float* Wd1 = (const float*)d_in[20];
    const float* bd1 = (const float*)d_in[21];
    const float* gm  = (const float*)d_in[22];
    const float* bt  = (const float*)d_in[23];
    const float* Wd2 = (const float*)d_in[24];
    const float* bd2 = (const float*)d_in[25];

    const int N  = in_sizes[2];
    const int E  = in_sizes[1] / 2;
    const int G  = in_sizes[3] / 4;
    const int Et = E + N;

    float* bufA   = (float*)d_ws;                 // [N,256]
    float* bufB   = bufA + (size_t)N * 256;       // [N,256]
    float* a_s    = bufB + (size_t)N * 256;       // [N,4]
    float* a_d    = a_s  + (size_t)N * 4;         // [N,4]
    float* den    = a_d  + (size_t)N * 4;         // [N,4]
    float* pooled = den  + (size_t)N * 4;         // [G,64]
    float* cnt    = pooled + (size_t)G * 64;      // [G]

    dim3 blk(256);
    auto cdiv = [](int a, int b) { return (a + b - 1) / b; };

    // encoder: bufA[:, :64] = x @ W_enc + b_enc   (stored dense [N,64])
    gemm_kernel<64><<<cdiv(N, 32), blk, 32 * 32 * 4, stream>>>(x, W_enc, b_enc, bufA, N, 32, 5);

    // ---------------- conv1 (H=4, in=64) ----------------
    gemm_kernel<256><<<cdiv(N, 8), blk, 8 * 64 * 4, stream>>>(bufA, W1, nullptr, bufB, N, 64, 6);
    att_scores_kernel<4><<<cdiv(N, 4), blk, 0, stream>>>(bufB, as1, ad1, a_s, a_d, N);
    hipMemsetAsync(den, 0, (size_t)N * 4 * sizeof(float), stream);
    hipMemsetAsync(bufA, 0, (size_t)N * 256 * sizeof(float), stream);
    edge_den_kernel<4><<<cdiv(Et * 4, 256), blk, 0, stream>>>(ei, a_s, a_d, den, E, Et);
    edge_scatter_kernel<4><<<cdiv(Et, 4), blk, 0, stream>>>(ei, bufB, a_s, a_d, den, bufA, E, Et);
    bias_act_kernel<true><<<cdiv(N * 256, 256), blk, 0, stream>>>(bufA, b1, N * 256, 255);

    // ---------------- conv2 (H=4, in=256) ----------------
    gemm_kernel<256><<<cdiv(N, 8), blk, 8 * 256 * 4, stream>>>(bufA, W2, nullptr, bufB, N, 256, 8);
    att_scores_kernel<4><<<cdiv(N, 4), blk, 0, stream>>>(bufB, as2, ad2, a_s, a_d, N);
    hipMemsetAsync(den, 0, (size_t)N * 4 * sizeof(float), stream);
    hipMemsetAsync(bufA, 0, (size_t)N * 256 * sizeof(float), stream);
    edge_den_kernel<4><<<cdiv(Et * 4, 256), blk, 0, stream>>>(ei, a_s, a_d, den, E, Et);
    edge_scatter_kernel<4><<<cdiv(Et, 4), blk, 0, stream>>>(ei, bufB, a_s, a_d, den, bufA, E, Et);
    bias_act_kernel<true><<<cdiv(N * 256, 256), blk, 0, stream>>>(bufA, b2, N * 256, 255);

    // ---------------- conv3 (H=1, in=256, no concat) ----------------
    gemm_kernel<64><<<cdiv(N, 32), blk, 32 * 256 * 4, stream>>>(bufA, W3, nullptr, bufB, N, 256, 8);
    att_scores_kernel<1><<<cdiv(N, 4), blk, 0, stream>>>(bufB, as3, ad3, a_s, a_d, N);
    hipMemsetAsync(den, 0, (size_t)N * 1 * sizeof(float), stream);
    hipMemsetAsync(bufA, 0, (size_t)N * 64 * sizeof(float), stream);
    edge_den_kernel<1><<<cdiv(Et, 256), blk, 0, stream>>>(ei, a_s, a_d, den, E, Et);
    edge_scatter_kernel<1><<<cdiv(Et, 4), blk, 0, stream>>>(ei, bufB, a_s, a_d, den, bufA, E, Et);
    bias_act_kernel<false><<<cdiv(N * 64, 256), blk, 0, stream>>>(bufA, b3, N * 64, 63);

    // ---------------- mean pool + decoder head ----------------
    hipMemsetAsync(pooled, 0, (size_t)G * 64 * sizeof(float), stream);
    hipMemsetAsync(cnt, 0, (size_t)G * sizeof(float), stream);
    pool_kernel<<<512, blk, 0, stream>>>(bufA, batch, pooled, cnt, N, 512 * 4);
    final_kernel<<<1, blk, 0, stream>>>(pooled, cnt, gf, Wg, bg, Wd1, bd1, gm, bt, Wd2, bd2,
                                        (float*)d_out, G);
}

// Round 2
// 1301.011 us; speedup vs baseline: 1.8472x; 1.8472x over previous
//
#include <hip/hip_runtime.h>
#include <math.h>

#define NEG_SLOPE 0.2f

// ---------------- GEMM: C[N,M] = A[N,K] @ B[K,M] (+bias) ----------------
template<int M>
__global__ void gemm_kernel(const float* __restrict__ A, const float* __restrict__ B,
                            const float* __restrict__ bias, float* __restrict__ C,
                            int Nrows, int K, int kshift) {
    constexpr int ROWS = 2048 / M;                 // 8 (M=256) or 32 (M=64)
    const int col  = threadIdx.x & (M - 1);
    const int rsub = threadIdx.x / M;
    const int rowBase = rsub * 8;
    const int blockRow = blockIdx.x * ROWS;
    extern __shared__ float ldsA[];
    const int total = ROWS << kshift;
    for (int i = threadIdx.x; i < total; i += 256) {
        int r = i >> kshift;
        int k = i & (K - 1);
        int row = blockRow + r;
        ldsA[i] = (row < Nrows) ? A[((size_t)row << kshift) + k] : 0.0f;
    }
    __syncthreads();
    float acc[8] = {0,0,0,0,0,0,0,0};
    for (int k = 0; k < K; k += 4) {
        float b0 = B[(k+0)*M + col];
        float b1 = B[(k+1)*M + col];
        float b2 = B[(k+2)*M + col];
        float b3 = B[(k+3)*M + col];
        #pragma unroll
        for (int r = 0; r < 8; r++) {
            const float4 a = *(const float4*)&ldsA[((rowBase + r) << kshift) + k];
            acc[r] += a.x*b0 + a.y*b1 + a.z*b2 + a.w*b3;
        }
    }
    float bv = bias ? bias[col] : 0.0f;
    #pragma unroll
    for (int r = 0; r < 8; r++) {
        int row = blockRow + rowBase + r;
        if (row < Nrows) C[(size_t)row * M + col] = acc[r] + bv;
    }
}

// ------------- per-node attention scores -------------
template<int H>
__global__ void att_scores_kernel(const float* __restrict__ hW,
                                  const float* __restrict__ att_s, const float* __restrict__ att_d,
                                  float* __restrict__ a_s, float* __restrict__ a_d, int N) {
    const int lane = threadIdx.x & 63;
    const int n = blockIdx.x * 4 + (threadIdx.x >> 6);
    if (n >= N) return;
    #pragma unroll
    for (int h = 0; h < H; h++) {
        float v = hW[(size_t)n * (H * 64) + h * 64 + lane];
        float s = v * att_s[h * 64 + lane];
        float d = v * att_d[h * 64 + lane];
        #pragma unroll
        for (int off = 32; off > 0; off >>= 1) {
            s += __shfl_xor(s, off);
            d += __shfl_xor(d, off);
        }
        if (lane == 0) { a_s[n * H + h] = s; a_d[n * H + h] = d; }
    }
}

// ------------- CSR build: histogram / scan / scatter-sort -------------
__global__ void edge_hist_kernel(const int* __restrict__ ei, int* __restrict__ counts,
                                 int E, int Et) {
    int e = blockIdx.x * 256 + threadIdx.x;
    if (e >= Et) return;
    int d = (e < E) ? ei[E + e] : e - E;
    atomicAdd(&counts[d], 1);
}

__global__ __launch_bounds__(1024) void scan_kernel(const int* __restrict__ counts,
                                                    int* __restrict__ offsets,
                                                    int* __restrict__ cursor, int N, int Et) {
    __shared__ int lds[1024];
    __shared__ int carry;
    if (threadIdx.x == 0) carry = 0;
    __syncthreads();
    for (int base = 0; base < N; base += 1024) {
        int i = base + threadIdx.x;
        int v = (i < N) ? counts[i] : 0;
        lds[threadIdx.x] = v;
        __syncthreads();
        for (int off = 1; off < 1024; off <<= 1) {
            int t = (threadIdx.x >= off) ? lds[threadIdx.x - off] : 0;
            __syncthreads();
            lds[threadIdx.x] += t;
            __syncthreads();
        }
        int c = carry;
        int excl = c + lds[threadIdx.x] - v;
        if (i < N) { offsets[i] = excl; cursor[i] = excl; }
        __syncthreads();
        if (threadIdx.x == 0) carry = c + lds[1023];
        __syncthreads();
    }
    if (threadIdx.x == 0) offsets[N] = Et;
}

__global__ void edge_sort_kernel(const int* __restrict__ ei, int* __restrict__ cursor,
                                 int* __restrict__ srcS, int E, int Et) {
    int e = blockIdx.x * 256 + threadIdx.x;
    if (e >= Et) return;
    int s, d;
    if (e < E) { s = ei[e]; d = ei[E + e]; } else { s = d = e - E; }
    int pos = atomicAdd(&cursor[d], 1);
    srcS[pos] = s;
}

// ------------- fused gather-aggregate: out[n] = sum_e w*hW[src] / sum_e w  + bias (+ELU) -------------
// H=4: one block per node, wave = head, lane = channel.
__global__ void gat_aggregate4(const int* __restrict__ offsets, const int* __restrict__ srcS,
                               const float* __restrict__ a_s, const float* __restrict__ a_d,
                               const float* __restrict__ hW, const float* __restrict__ bias,
                               float* __restrict__ out, int N) {
    const int n = blockIdx.x;
    if (n >= N) return;
    const int h = threadIdx.x >> 6;
    const int lane = threadIdx.x & 63;
    const int start = offsets[n], end = offsets[n + 1];
    const float ad = a_d[n * 4 + h];
    float acc = 0.0f, den = 0.0f;
    int sNext = srcS[start];
    for (int e = start; e < end; e++) {
        int s = sNext;
        if (e + 1 < end) sNext = srcS[e + 1];
        float ev = a_s[s * 4 + h] + ad;
        ev = (ev >= 0.0f) ? ev : NEG_SLOPE * ev;
        float w = expf(ev);
        acc += w * hW[(size_t)s * 256 + h * 64 + lane];
        den += w;
    }
    float v = acc / (den + 1e-16f) + bias[h * 64 + lane];
    v = (v > 0.0f) ? v : expm1f(v);               // ELU
    out[(size_t)n * 256 + h * 64 + lane] = v;
}

// H=1: 4 nodes per block, wave = node, lane = channel. No ELU.
__global__ void gat_aggregate1(const int* __restrict__ offsets, const int* __restrict__ srcS,
                               const float* __restrict__ a_s, const float* __restrict__ a_d,
                               const float* __restrict__ hW, const float* __restrict__ bias,
                               float* __restrict__ out, int N) {
    const int n = blockIdx.x * 4 + (threadIdx.x >> 6);
    if (n >= N) return;
    const int lane = threadIdx.x & 63;
    const int start = offsets[n], end = offsets[n + 1];
    const float ad = a_d[n];
    float acc = 0.0f, den = 0.0f;
    int sNext = srcS[start];
    for (int e = start; e < end; e++) {
        int s = sNext;
        if (e + 1 < end) sNext = srcS[e + 1];
        float ev = a_s[s] + ad;
        ev = (ev >= 0.0f) ? ev : NEG_SLOPE * ev;
        float w = expf(ev);
        acc += w * hW[(size_t)s * 64 + lane];
        den += w;
    }
    out[(size_t)n * 64 + lane] = acc / (den + 1e-16f) + bias[lane];
}

// ------------- per-graph mean pool (batch is sorted) -------------
__global__ void pool_kernel(const float* __restrict__ h, const int* __restrict__ batch,
                            float* __restrict__ pooled, float* __restrict__ cnt,
                            int N, int nWaves) {
    const int w = blockIdx.x * 4 + (threadIdx.x >> 6);
    const int lane = threadIdx.x & 63;
    const int chunk = (N + nWaves - 1) / nWaves;
    int start = w * chunk;
    int end = min(N, start + chunk);
    if (start >= end) return;
    int curg = batch[start];
    int runStart = start;
    float acc = 0.0f;
    for (int n = start; n < end; n++) {
        int g = batch[n];
        if (g != curg) {
            atomicAdd(&pooled[curg * 64 + lane], acc);
            if (lane == 0) atomicAdd(&cnt[curg], (float)(n - runStart));
            acc = 0.0f; curg = g; runStart = n;
        }
        acc += h[(size_t)n * 64 + lane];
    }
    atomicAdd(&pooled[curg * 64 + lane], acc);
    if (lane == 0) atomicAdd(&cnt[curg], (float)(end - runStart));
}

// ------------- decoder head -------------
__global__ void final_kernel(const float* __restrict__ pooled, const float* __restrict__ cnt,
                             const float* __restrict__ gf, const float* __restrict__ Wg,
                             const float* __restrict__ bg, const float* __restrict__ Wd1,
                             const float* __restrict__ bd1, const float* __restrict__ gamma,
                             const float* __restrict__ beta, const float* __restrict__ Wd2,
                             const float* __restrict__ bd2, float* __restrict__ out, int G) {
    __shared__ float sp[16 * 64], sg[16 * 64], sz[16 * 64], slog[16 * 256];
    const int tid = threadIdx.x;
    for (int i = tid; i < G * 64; i += 256) {
        int g = i >> 6;
        sp[i] = pooled[i] / fmaxf(cnt[g], 1.0f);
    }
    for (int i = tid; i < G * 64; i += 256) {
        int g = i >> 6, c = i & 63;
        float v = bg[c];
        #pragma unroll
        for (int k = 0; k < 4; k++) v += gf[g * 4 + k] * Wg[k * 64 + c];
        sg[i] = fmaxf(v, 0.0f);
    }
    __syncthreads();
    for (int i = tid; i < G * 64; i += 256) {
        int g = i >> 6, c = i & 63;
        float v = bd1[c];
        for (int k = 0; k < 64; k++) v += sp[g * 64 + k] * Wd1[k * 64 + c];
        for (int k = 0; k < 64; k++) v += sg[g * 64 + k] * Wd1[(64 + k) * 64 + c];
        v = v * gamma[c] + beta[c];
        sz[i] = fmaxf(v, 0.0f);
    }
    __syncthreads();
    for (int i = tid; i < G * 256; i += 256) {
        int g = i >> 8, j = i & 255;
        float v = bd2[j];
        for (int k = 0; k < 64; k++) v += sz[g * 64 + k] * Wd2[k * 256 + j];
        slog[i] = v;
    }
    __syncthreads();
    const int wid = tid >> 6, lane = tid & 63;
    for (int g = wid; g < G; g += 4) {
        float v0 = slog[g * 256 + lane],       v1 = slog[g * 256 + 64 + lane],
              v2 = slog[g * 256 + 128 + lane], v3 = slog[g * 256 + 192 + lane];
        float m = fmaxf(fmaxf(v0, v1), fmaxf(v2, v3));
        #pragma unroll
        for (int off = 32; off > 0; off >>= 1) m = fmaxf(m, __shfl_xor(m, off));
        float e0 = expf(v0 - m), e1 = expf(v1 - m), e2 = expf(v2 - m), e3 = expf(v3 - m);
        float s = e0 + e1 + e2 + e3;
        #pragma unroll
        for (int off = 32; off > 0; off >>= 1) s += __shfl_xor(s, off);
        float inv = 1.0f / s;
        out[g * 256 + lane]        = e0 * inv;
        out[g * 256 + 64 + lane]   = e1 * inv;
        out[g * 256 + 128 + lane]  = e2 * inv;
        out[g * 256 + 192 + lane]  = e3 * inv;
    }
}

extern "C" void kernel_launch(void* const* d_in, const int* in_sizes, int n_in,
                              void* d_out, int out_size, void* d_ws, size_t ws_size,
                              hipStream_t stream) {
    const float* x     = (const float*)d_in[0];
    const int*   ei    = (const int*)  d_in[1];
    const int*   batch = (const int*)  d_in[2];
    const float* gf    = (const float*)d_in[3];
    const float* W_enc = (const float*)d_in[4];
    const float* b_enc = (const float*)d_in[5];
    const float* W1  = (const float*)d_in[6];
    const float* as1 = (const float*)d_in[7];
    const float* ad1 = (const float*)d_in[8];
    const float* b1  = (const float*)d_in[9];
    const float* W2  = (const float*)d_in[10];
    const float* as2 = (const float*)d_in[11];
    const float* ad2 = (const float*)d_in[12];
    const float* b2  = (const float*)d_in[13];
    const float* W3  = (const float*)d_in[14];
    const float* as3 = (const float*)d_in[15];
    const float* ad3 = (const float*)d_in[16];
    const float* b3  = (const float*)d_in[17];
    const float* Wg  = (const float*)d_in[18];
    const float* bg  = (const float*)d_in[19];
    const float* Wd1 = (const float*)d_in[20];
    const float* bd1 = (const float*)d_in[21];
    const float* gm  = (const float*)d_in[22];
    const float* bt  = (const float*)d_in[23];
    const float* Wd2 = (const float*)d_in[24];
    const float* bd2 = (const float*)d_in[25];

    const int N  = in_sizes[2];
    const int E  = in_sizes[1] / 2;
    const int G  = in_sizes[3] / 4;
    const int Et = E + N;

    float* bufA   = (float*)d_ws;                 // [N,256]
    float* bufB   = bufA + (size_t)N * 256;       // [N,256]
    float* a_s    = bufB + (size_t)N * 256;       // [N,4]
    float* a_d    = a_s  + (size_t)N * 4;         // [N,4]
    float* pooled = a_d  + (size_t)N * 4;         // [G,64]
    float* cnt    = pooled + (size_t)G * 64;      // [G]
    int*   offsets = (int*)(cnt + G);             // [N+1]
    int*   srcS    = offsets + (N + 1);           // [Et]
    // counts/cursor alias bufB (dead before bufB's first GEMM write)
    int*   counts  = (int*)bufB;
    int*   cursor  = counts + N;

    dim3 blk(256);
    auto cdiv = [](int a, int b) { return (a + b - 1) / b; };

    // ---------------- CSR build (once, reused by all 3 convs) ----------------
    hipMemsetAsync(counts, 0, (size_t)N * sizeof(int), stream);
    edge_hist_kernel<<<cdiv(Et, 256), blk, 0, stream>>>(ei, counts, E, Et);
    scan_kernel<<<1, 1024, 0, stream>>>(counts, offsets, cursor, N, Et);
    edge_sort_kernel<<<cdiv(Et, 256), blk, 0, stream>>>(ei, cursor, srcS, E, Et);

    // encoder: bufA = x @ W_enc + b_enc   [N,64]
    gemm_kernel<64><<<cdiv(N, 32), blk, 32 * 32 * 4, stream>>>(x, W_enc, b_enc, bufA, N, 32, 5);

    // ---------------- conv1 (H=4, in=64) ----------------
    gemm_kernel<256><<<cdiv(N, 8), blk, 8 * 64 * 4, stream>>>(bufA, W1, nullptr, bufB, N, 64, 6);
    att_scores_kernel<4><<<cdiv(N, 4), blk, 0, stream>>>(bufB, as1, ad1, a_s, a_d, N);
    gat_aggregate4<<<N, blk, 0, stream>>>(offsets, srcS, a_s, a_d, bufB, b1, bufA, N);

    // ---------------- conv2 (H=4, in=256) ----------------
    gemm_kernel<256><<<cdiv(N, 8), blk, 8 * 256 * 4, stream>>>(bufA, W2, nullptr, bufB, N, 256, 8);
    att_scores_kernel<4><<<cdiv(N, 4), blk, 0, stream>>>(bufB, as2, ad2, a_s, a_d, N);
    gat_aggregate4<<<N, blk, 0, stream>>>(offsets, srcS, a_s, a_d, bufB, b2, bufA, N);

    // ---------------- conv3 (H=1, in=256, no concat) ----------------
    gemm_kernel<64><<<cdiv(N, 32), blk, 32 * 256 * 4, stream>>>(bufA, W3, nullptr, bufB, N, 256, 8);
    att_scores_kernel<1><<<cdiv(N, 4), blk, 0, stream>>>(bufB, as3, ad3, a_s, a_d, N);
    gat_aggregate1<<<cdiv(N, 4), blk, 0, stream>>>(offsets, srcS, a_s, a_d, bufB, b3, bufA, N);

    // ---------------- mean pool + decoder head ----------------
    hipMemsetAsync(pooled, 0, (size_t)G * 64 * sizeof(float), stream);
    hipMemsetAsync(cnt, 0, (size_t)G * sizeof(float), stream);
    pool_kernel<<<512, blk, 0, stream>>>(bufA, batch, pooled, cnt, N, 512 * 4);
    final_kernel<<<1, blk, 0, stream>>>(pooled, cnt, gf, Wg, bg, Wd1, bd1, gm, bt, Wd2, bd2,
                                        (float*)d_out, G);
}

// Round 3
// 1016.459 us; speedup vs baseline: 2.3643x; 1.2799x over previous
//
#include <hip/hip_runtime.h>
#include <math.h>

#define NEG_SLOPE 0.2f

// ---------------- GEMM: C[N,M] = A[N,K] @ B[K,M] (+bias) ----------------
// 64x64 tile, 256 threads, 4x4 micro-tile per thread, k-sliced by 16,
// software-pipelined global->reg->LDS staging. Requires M%64==0, K%16==0.
__global__ __launch_bounds__(256) void gemm64(const float* __restrict__ A,
                                              const float* __restrict__ B,
                                              const float* __restrict__ bias,
                                              float* __restrict__ C,
                                              int Nrows, int K, int M) {
    __shared__ float sA[16][64];   // [k][row]  (A transposed on store)
    __shared__ float sB[16][64];   // [k][col]
    const int tx = threadIdx.x & 15;         // micro-col group
    const int ty = threadIdx.x >> 4;         // micro-row group
    const int row0 = blockIdx.x * 64;
    const int col0 = blockIdx.y * 64;
    // staging addressing
    const int lr = threadIdx.x >> 2;          // 0..63   A row
    const int lk = (threadIdx.x & 3) << 2;    // 0,4,8,12 A k-offset
    const int br = threadIdx.x >> 4;          // 0..15   B k-row
    const int bc = (threadIdx.x & 15) << 2;   // B col*4

    const int aRow = row0 + lr;
    const bool aValid = aRow < Nrows;
    const float* Aptr = A + (size_t)aRow * K + lk;
    const float* Bptr = B + (size_t)br * M + col0 + bc;

    float acc[4][4] = {{0,0,0,0},{0,0,0,0},{0,0,0,0},{0,0,0,0}};

    float4 a = aValid ? *(const float4*)Aptr : float4{0,0,0,0};
    float4 b = *(const float4*)Bptr;

    for (int kt = 0; kt < K; kt += 16) {
        __syncthreads();
        sA[lk+0][lr] = a.x; sA[lk+1][lr] = a.y; sA[lk+2][lr] = a.z; sA[lk+3][lr] = a.w;
        *(float4*)&sB[br][bc] = b;
        __syncthreads();
        if (kt + 16 < K) {                     // prefetch next k-slice
            a = aValid ? *(const float4*)(Aptr + kt + 16) : float4{0,0,0,0};
            b = *(const float4*)(Bptr + (size_t)(kt + 16) * M);
        }
        #pragma unroll
        for (int k = 0; k < 16; k++) {
            const float4 av = *(const float4*)&sA[k][ty << 2];
            const float4 bv = *(const float4*)&sB[k][tx << 2];
            acc[0][0] += av.x*bv.x; acc[0][1] += av.x*bv.y; acc[0][2] += av.x*bv.z; acc[0][3] += av.x*bv.w;
            acc[1][0] += av.y*bv.x; acc[1][1] += av.y*bv.y; acc[1][2] += av.y*bv.z; acc[1][3] += av.y*bv.w;
            acc[2][0] += av.z*bv.x; acc[2][1] += av.z*bv.y; acc[2][2] += av.z*bv.z; acc[2][3] += av.z*bv.w;
            acc[3][0] += av.w*bv.x; acc[3][1] += av.w*bv.y; acc[3][2] += av.w*bv.z; acc[3][3] += av.w*bv.w;
        }
    }

    float4 bb = {0,0,0,0};
    if (bias) bb = *(const float4*)&bias[col0 + (tx << 2)];
    #pragma unroll
    for (int i = 0; i < 4; i++) {
        int r = row0 + (ty << 2) + i;
        if (r < Nrows) {
            float4 o = {acc[i][0] + bb.x, acc[i][1] + bb.y, acc[i][2] + bb.z, acc[i][3] + bb.w};
            *(float4*)&C[(size_t)r * M + col0 + (tx << 2)] = o;
        }
    }
}

// ------------- per-node attention scores -------------
template<int H>
__global__ void att_scores_kernel(const float* __restrict__ hW,
                                  const float* __restrict__ att_s, const float* __restrict__ att_d,
                                  float* __restrict__ a_s, float* __restrict__ a_d, int N) {
    const int lane = threadIdx.x & 63;
    const int n = blockIdx.x * 4 + (threadIdx.x >> 6);
    if (n >= N) return;
    #pragma unroll
    for (int h = 0; h < H; h++) {
        float v = hW[(size_t)n * (H * 64) + h * 64 + lane];
        float s = v * att_s[h * 64 + lane];
        float d = v * att_d[h * 64 + lane];
        #pragma unroll
        for (int off = 32; off > 0; off >>= 1) {
            s += __shfl_xor(s, off);
            d += __shfl_xor(d, off);
        }
        if (lane == 0) { a_s[n * H + h] = s; a_d[n * H + h] = d; }
    }
}

// ------------- CSR build: histogram / scan / scatter-sort -------------
__global__ void edge_hist_kernel(const int* __restrict__ ei, int* __restrict__ counts,
                                 int E, int Et) {
    int e = blockIdx.x * 256 + threadIdx.x;
    if (e >= Et) return;
    int d = (e < E) ? ei[E + e] : e - E;
    atomicAdd(&counts[d], 1);
}

__global__ __launch_bounds__(1024) void scan_kernel(const int* __restrict__ counts,
                                                    int* __restrict__ offsets,
                                                    int* __restrict__ cursor, int N, int Et) {
    __shared__ int lds[1024];
    __shared__ int carry;
    if (threadIdx.x == 0) carry = 0;
    __syncthreads();
    for (int base = 0; base < N; base += 1024) {
        int i = base + threadIdx.x;
        int v = (i < N) ? counts[i] : 0;
        lds[threadIdx.x] = v;
        __syncthreads();
        for (int off = 1; off < 1024; off <<= 1) {
            int t = (threadIdx.x >= off) ? lds[threadIdx.x - off] : 0;
            __syncthreads();
            lds[threadIdx.x] += t;
            __syncthreads();
        }
        int c = carry;
        int excl = c + lds[threadIdx.x] - v;
        if (i < N) { offsets[i] = excl; cursor[i] = excl; }
        __syncthreads();
        if (threadIdx.x == 0) carry = c + lds[1023];
        __syncthreads();
    }
    if (threadIdx.x == 0) offsets[N] = Et;
}

__global__ void edge_sort_kernel(const int* __restrict__ ei, int* __restrict__ cursor,
                                 int* __restrict__ srcS, int E, int Et) {
    int e = blockIdx.x * 256 + threadIdx.x;
    if (e >= Et) return;
    int s, d;
    if (e < E) { s = ei[e]; d = ei[E + e]; } else { s = d = e - E; }
    int pos = atomicAdd(&cursor[d], 1);
    srcS[pos] = s;
}

// ------------- fused gather-aggregate (H=4): block=node, wave=head, lane=channel -------------
__global__ void gat_aggregate4(const int* __restrict__ offsets, const int* __restrict__ srcS,
                               const float* __restrict__ a_s, const float* __restrict__ a_d,
                               const float* __restrict__ hW, const float* __restrict__ bias,
                               float* __restrict__ out, int N) {
    const int n = blockIdx.x;
    if (n >= N) return;
    const int h = threadIdx.x >> 6;
    const int lane = threadIdx.x & 63;
    const int start = offsets[n], end = offsets[n + 1];
    const float ad = a_d[n * 4 + h];
    float acc = 0.0f, den = 0.0f;
    int e = start;
    for (; e + 2 <= end; e += 2) {             // unroll-2 for MLP
        int s0 = srcS[e], s1 = srcS[e + 1];
        float as0 = a_s[s0 * 4 + h];
        float as1 = a_s[s1 * 4 + h];
        float v0 = hW[(size_t)s0 * 256 + h * 64 + lane];
        float v1 = hW[(size_t)s1 * 256 + h * 64 + lane];
        float e0 = as0 + ad; e0 = (e0 >= 0.0f) ? e0 : NEG_SLOPE * e0;
        float e1 = as1 + ad; e1 = (e1 >= 0.0f) ? e1 : NEG_SLOPE * e1;
        float w0 = expf(e0), w1 = expf(e1);
        acc += w0 * v0 + w1 * v1;
        den += w0 + w1;
    }
    if (e < end) {
        int s0 = srcS[e];
        float e0 = a_s[s0 * 4 + h] + ad; e0 = (e0 >= 0.0f) ? e0 : NEG_SLOPE * e0;
        float w0 = expf(e0);
        acc += w0 * hW[(size_t)s0 * 256 + h * 64 + lane];
        den += w0;
    }
    float v = acc / (den + 1e-16f) + bias[h * 64 + lane];
    v = (v > 0.0f) ? v : expm1f(v);            // ELU
    out[(size_t)n * 256 + h * 64 + lane] = v;
}

// ------------- H=1 variant: 4 nodes/block, wave=node. No ELU. -------------
__global__ void gat_aggregate1(const int* __restrict__ offsets, const int* __restrict__ srcS,
                               const float* __restrict__ a_s, const float* __restrict__ a_d,
                               const float* __restrict__ hW, const float* __restrict__ bias,
                               float* __restrict__ out, int N) {
    const int n = blockIdx.x * 4 + (threadIdx.x >> 6);
    if (n >= N) return;
    const int lane = threadIdx.x & 63;
    const int start = offsets[n], end = offsets[n + 1];
    const float ad = a_d[n];
    float acc = 0.0f, den = 0.0f;
    int e = start;
    for (; e + 2 <= end; e += 2) {
        int s0 = srcS[e], s1 = srcS[e + 1];
        float as0 = a_s[s0], as1 = a_s[s1];
        float v0 = hW[(size_t)s0 * 64 + lane];
        float v1 = hW[(size_t)s1 * 64 + lane];
        float e0 = as0 + ad; e0 = (e0 >= 0.0f) ? e0 : NEG_SLOPE * e0;
        float e1 = as1 + ad; e1 = (e1 >= 0.0f) ? e1 : NEG_SLOPE * e1;
        float w0 = expf(e0), w1 = expf(e1);
        acc += w0 * v0 + w1 * v1;
        den += w0 + w1;
    }
    if (e < end) {
        int s0 = srcS[e];
        float e0 = a_s[s0] + ad; e0 = (e0 >= 0.0f) ? e0 : NEG_SLOPE * e0;
        float w0 = expf(e0);
        acc += w0 * hW[(size_t)s0 * 64 + lane];
        den += w0;
    }
    out[(size_t)n * 64 + lane] = acc / (den + 1e-16f) + bias[lane];
}

// ------------- per-graph mean pool (batch is sorted) -------------
__global__ void pool_kernel(const float* __restrict__ h, const int* __restrict__ batch,
                            float* __restrict__ pooled, float* __restrict__ cnt,
                            int N, int nWaves) {
    const int w = blockIdx.x * 4 + (threadIdx.x >> 6);
    const int lane = threadIdx.x & 63;
    const int chunk = (N + nWaves - 1) / nWaves;
    int start = w * chunk;
    int end = min(N, start + chunk);
    if (start >= end) return;
    int curg = batch[start];
    int runStart = start;
    float acc = 0.0f;
    for (int n = start; n < end; n++) {
        int g = batch[n];
        if (g != curg) {
            atomicAdd(&pooled[curg * 64 + lane], acc);
            if (lane == 0) atomicAdd(&cnt[curg], (float)(n - runStart));
            acc = 0.0f; curg = g; runStart = n;
        }
        acc += h[(size_t)n * 64 + lane];
    }
    atomicAdd(&pooled[curg * 64 + lane], acc);
    if (lane == 0) atomicAdd(&cnt[curg], (float)(end - runStart));
}

// ------------- decoder head -------------
__global__ void final_kernel(const float* __restrict__ pooled, const float* __restrict__ cnt,
                             const float* __restrict__ gf, const float* __restrict__ Wg,
                             const float* __restrict__ bg, const float* __restrict__ Wd1,
                             const float* __restrict__ bd1, const float* __restrict__ gamma,
                             const float* __restrict__ beta, const float* __restrict__ Wd2,
                             const float* __restrict__ bd2, float* __restrict__ out, int G) {
    __shared__ float sp[16 * 64], sg[16 * 64], sz[16 * 64], slog[16 * 256];
    const int tid = threadIdx.x;
    for (int i = tid; i < G * 64; i += 256) {
        int g = i >> 6;
        sp[i] = pooled[i] / fmaxf(cnt[g], 1.0f);
    }
    for (int i = tid; i < G * 64; i += 256) {
        int g = i >> 6, c = i & 63;
        float v = bg[c];
        #pragma unroll
        for (int k = 0; k < 4; k++) v += gf[g * 4 + k] * Wg[k * 64 + c];
        sg[i] = fmaxf(v, 0.0f);
    }
    __syncthreads();
    for (int i = tid; i < G * 64; i += 256) {
        int g = i >> 6, c = i & 63;
        float v = bd1[c];
        for (int k = 0; k < 64; k++) v += sp[g * 64 + k] * Wd1[k * 64 + c];
        for (int k = 0; k < 64; k++) v += sg[g * 64 + k] * Wd1[(64 + k) * 64 + c];
        v = v * gamma[c] + beta[c];
        sz[i] = fmaxf(v, 0.0f);
    }
    __syncthreads();
    for (int i = tid; i < G * 256; i += 256) {
        int g = i >> 8, j = i & 255;
        float v = bd2[j];
        for (int k = 0; k < 64; k++) v += sz[g * 64 + k] * Wd2[k * 256 + j];
        slog[i] = v;
    }
    __syncthreads();
    const int wid = tid >> 6, lane = tid & 63;
    for (int g = wid; g < G; g += 4) {
        float v0 = slog[g * 256 + lane],       v1 = slog[g * 256 + 64 + lane],
              v2 = slog[g * 256 + 128 + lane], v3 = slog[g * 256 + 192 + lane];
        float m = fmaxf(fmaxf(v0, v1), fmaxf(v2, v3));
        #pragma unroll
        for (int off = 32; off > 0; off >>= 1) m = fmaxf(m, __shfl_xor(m, off));
        float e0 = expf(v0 - m), e1 = expf(v1 - m), e2 = expf(v2 - m), e3 = expf(v3 - m);
        float s = e0 + e1 + e2 + e3;
        #pragma unroll
        for (int off = 32; off > 0; off >>= 1) s += __shfl_xor(s, off);
        float inv = 1.0f / s;
        out[g * 256 + lane]        = e0 * inv;
        out[g * 256 + 64 + lane]   = e1 * inv;
        out[g * 256 + 128 + lane]  = e2 * inv;
        out[g * 256 + 192 + lane]  = e3 * inv;
    }
}

extern "C" void kernel_launch(void* const* d_in, const int* in_sizes, int n_in,
                              void* d_out, int out_size, void* d_ws, size_t ws_size,
                              hipStream_t stream) {
    const float* x     = (const float*)d_in[0];
    const int*   ei    = (const int*)  d_in[1];
    const int*   batch = (const int*)  d_in[2];
    const float* gf    = (const float*)d_in[3];
    const float* W_enc = (const float*)d_in[4];
    const float* b_enc = (const float*)d_in[5];
    const float* W1  = (const float*)d_in[6];
    const float* as1 = (const float*)d_in[7];
    const float* ad1 = (const float*)d_in[8];
    const float* b1  = (const float*)d_in[9];
    const float* W2  = (const float*)d_in[10];
    const float* as2 = (const float*)d_in[11];
    const float* ad2 = (const float*)d_in[12];
    const float* b2  = (const float*)d_in[13];
    const float* W3  = (const float*)d_in[14];
    const float* as3 = (const float*)d_in[15];
    const float* ad3 = (const float*)d_in[16];
    const float* b3  = (const float*)d_in[17];
    const float* Wg  = (const float*)d_in[18];
    const float* bg  = (const float*)d_in[19];
    const float* Wd1 = (const float*)d_in[20];
    const float* bd1 = (const float*)d_in[21];
    const float* gm  = (const float*)d_in[22];
    const float* bt  = (const float*)d_in[23];
    const float* Wd2 = (const float*)d_in[24];
    const float* bd2 = (const float*)d_in[25];

    const int N  = in_sizes[2];
    const int E  = in_sizes[1] / 2;
    const int G  = in_sizes[3] / 4;
    const int Et = E + N;

    float* bufA   = (float*)d_ws;                 // [N,256]
    float* bufB   = bufA + (size_t)N * 256;       // [N,256]
    float* a_s    = bufB + (size_t)N * 256;       // [N,4]
    float* a_d    = a_s  + (size_t)N * 4;         // [N,4]
    float* pooled = a_d  + (size_t)N * 4;         // [G,64]
    float* cnt    = pooled + (size_t)G * 64;      // [G]
    int*   offsets = (int*)(cnt + G);             // [N+1]
    int*   srcS    = offsets + (N + 1);           // [Et]
    // counts/cursor alias bufB (dead before bufB's first GEMM write)
    int*   counts  = (int*)bufB;
    int*   cursor  = counts + N;

    dim3 blk(256);
    auto cdiv = [](int a, int b) { return (a + b - 1) / b; };

    // ---------------- CSR build (once, reused by all 3 convs) ----------------
    hipMemsetAsync(counts, 0, (size_t)N * sizeof(int), stream);
    edge_hist_kernel<<<cdiv(Et, 256), blk, 0, stream>>>(ei, counts, E, Et);
    scan_kernel<<<1, 1024, 0, stream>>>(counts, offsets, cursor, N, Et);
    edge_sort_kernel<<<cdiv(Et, 256), blk, 0, stream>>>(ei, cursor, srcS, E, Et);

    const int rowBlocks = cdiv(N, 64);

    // encoder: bufA = x @ W_enc + b_enc   [N,64]
    gemm64<<<dim3(rowBlocks, 1), blk, 0, stream>>>(x, W_enc, b_enc, bufA, N, 32, 64);

    // ---------------- conv1 (H=4, in=64) ----------------
    gemm64<<<dim3(rowBlocks, 4), blk, 0, stream>>>(bufA, W1, nullptr, bufB, N, 64, 256);
    att_scores_kernel<4><<<cdiv(N, 4), blk, 0, stream>>>(bufB, as1, ad1, a_s, a_d, N);
    gat_aggregate4<<<N, blk, 0, stream>>>(offsets, srcS, a_s, a_d, bufB, b1, bufA, N);

    // ---------------- conv2 (H=4, in=256) ----------------
    gemm64<<<dim3(rowBlocks, 4), blk, 0, stream>>>(bufA, W2, nullptr, bufB, N, 256, 256);
    att_scores_kernel<4><<<cdiv(N, 4), blk, 0, stream>>>(bufB, as2, ad2, a_s, a_d, N);
    gat_aggregate4<<<N, blk, 0, stream>>>(offsets, srcS, a_s, a_d, bufB, b2, bufA, N);

    // ---------------- conv3 (H=1, in=256, no concat) ----------------
    gemm64<<<dim3(rowBlocks, 1), blk, 0, stream>>>(bufA, W3, nullptr, bufB, N, 256, 64);
    att_scores_kernel<1><<<cdiv(N, 4), blk, 0, stream>>>(bufB, as3, ad3, a_s, a_d, N);
    gat_aggregate1<<<cdiv(N, 4), blk, 0, stream>>>(offsets, srcS, a_s, a_d, bufB, b3, bufA, N);

    // ---------------- mean pool + decoder head ----------------
    hipMemsetAsync(pooled, 0, (size_t)G * 64 * sizeof(float), stream);
    hipMemsetAsync(cnt, 0, (size_t)G * sizeof(float), stream);
    pool_kernel<<<512, blk, 0, stream>>>(bufA, batch, pooled, cnt, N, 512 * 4);
    final_kernel<<<1, blk, 0, stream>>>(pooled, cnt, gf, Wg, bg, Wd1, bd1, gm, bt, Wd2, bd2,
                                        (float*)d_out, G);
}

// Round 4
// 981.315 us; speedup vs baseline: 2.4489x; 1.0358x over previous
//
#include <hip/hip_runtime.h>
#include <math.h>

#define NEG_SLOPE 0.2f

// ---------------- GEMM: C[N,M] = A[N,K] @ B[K,M] (+bias) ----------------
// 64x64 tile, 256 threads, 4x4 micro-tile per thread, k-sliced by 16,
// software-pipelined global->reg->LDS staging. Requires M%64==0, K%16==0.
__global__ __launch_bounds__(256) void gemm64(const float* __restrict__ A,
                                              const float* __restrict__ B,
                                              const float* __restrict__ bias,
                                              float* __restrict__ C,
                                              int Nrows, int K, int M) {
    __shared__ float sA[16][64];   // [k][row]  (A transposed on store)
    __shared__ float sB[16][64];   // [k][col]
    const int tx = threadIdx.x & 15;         // micro-col group
    const int ty = threadIdx.x >> 4;         // micro-row group
    const int row0 = blockIdx.x * 64;
    const int col0 = blockIdx.y * 64;
    const int lr = threadIdx.x >> 2;          // 0..63   A row
    const int lk = (threadIdx.x & 3) << 2;    // 0,4,8,12 A k-offset
    const int br = threadIdx.x >> 4;          // 0..15   B k-row
    const int bc = (threadIdx.x & 15) << 2;   // B col*4

    const int aRow = row0 + lr;
    const bool aValid = aRow < Nrows;
    const float* Aptr = A + (size_t)aRow * K + lk;
    const float* Bptr = B + (size_t)br * M + col0 + bc;

    float acc[4][4] = {{0,0,0,0},{0,0,0,0},{0,0,0,0},{0,0,0,0}};

    float4 a = aValid ? *(const float4*)Aptr : float4{0,0,0,0};
    float4 b = *(const float4*)Bptr;

    for (int kt = 0; kt < K; kt += 16) {
        __syncthreads();
        sA[lk+0][lr] = a.x; sA[lk+1][lr] = a.y; sA[lk+2][lr] = a.z; sA[lk+3][lr] = a.w;
        *(float4*)&sB[br][bc] = b;
        __syncthreads();
        if (kt + 16 < K) {                     // prefetch next k-slice
            a = aValid ? *(const float4*)(Aptr + kt + 16) : float4{0,0,0,0};
            b = *(const float4*)(Bptr + (size_t)(kt + 16) * M);
        }
        #pragma unroll
        for (int k = 0; k < 16; k++) {
            const float4 av = *(const float4*)&sA[k][ty << 2];
            const float4 bv = *(const float4*)&sB[k][tx << 2];
            acc[0][0] += av.x*bv.x; acc[0][1] += av.x*bv.y; acc[0][2] += av.x*bv.z; acc[0][3] += av.x*bv.w;
            acc[1][0] += av.y*bv.x; acc[1][1] += av.y*bv.y; acc[1][2] += av.y*bv.z; acc[1][3] += av.y*bv.w;
            acc[2][0] += av.z*bv.x; acc[2][1] += av.z*bv.y; acc[2][2] += av.z*bv.z; acc[2][3] += av.z*bv.w;
            acc[3][0] += av.w*bv.x; acc[3][1] += av.w*bv.y; acc[3][2] += av.w*bv.z; acc[3][3] += av.w*bv.w;
        }
    }

    float4 bb = {0,0,0,0};
    if (bias) bb = *(const float4*)&bias[col0 + (tx << 2)];
    #pragma unroll
    for (int i = 0; i < 4; i++) {
        int r = row0 + (ty << 2) + i;
        if (r < Nrows) {
            float4 o = {acc[i][0] + bb.x, acc[i][1] + bb.y, acc[i][2] + bb.z, acc[i][3] + bb.w};
            *(float4*)&C[(size_t)r * M + col0 + (tx << 2)] = o;
        }
    }
}

// ------------- per-node attention scores -------------
template<int H>
__global__ void att_scores_kernel(const float* __restrict__ hW,
                                  const float* __restrict__ att_s, const float* __restrict__ att_d,
                                  float* __restrict__ a_s, float* __restrict__ a_d, int N) {
    const int lane = threadIdx.x & 63;
    const int n = blockIdx.x * 4 + (threadIdx.x >> 6);
    if (n >= N) return;
    #pragma unroll
    for (int h = 0; h < H; h++) {
        float v = hW[(size_t)n * (H * 64) + h * 64 + lane];
        float s = v * att_s[h * 64 + lane];
        float d = v * att_d[h * 64 + lane];
        #pragma unroll
        for (int off = 32; off > 0; off >>= 1) {
            s += __shfl_xor(s, off);
            d += __shfl_xor(d, off);
        }
        if (lane == 0) { a_s[n * H + h] = s; a_d[n * H + h] = d; }
    }
}

// ------------- CSR build: histogram / scan / scatter-sort -------------
__global__ void edge_hist_kernel(const int* __restrict__ ei, int* __restrict__ counts,
                                 int E, int Et) {
    int e = blockIdx.x * 256 + threadIdx.x;
    if (e >= Et) return;
    int d = (e < E) ? ei[E + e] : e - E;
    atomicAdd(&counts[d], 1);
}

__global__ __launch_bounds__(1024) void scan_kernel(const int* __restrict__ counts,
                                                    int* __restrict__ offsets,
                                                    int* __restrict__ cursor, int N, int Et) {
    __shared__ int lds[1024];
    __shared__ int carry;
    if (threadIdx.x == 0) carry = 0;
    __syncthreads();
    for (int base = 0; base < N; base += 1024) {
        int i = base + threadIdx.x;
        int v = (i < N) ? counts[i] : 0;
        lds[threadIdx.x] = v;
        __syncthreads();
        for (int off = 1; off < 1024; off <<= 1) {
            int t = (threadIdx.x >= off) ? lds[threadIdx.x - off] : 0;
            __syncthreads();
            lds[threadIdx.x] += t;
            __syncthreads();
        }
        int c = carry;
        int excl = c + lds[threadIdx.x] - v;
        if (i < N) { offsets[i] = excl; cursor[i] = excl; }
        __syncthreads();
        if (threadIdx.x == 0) carry = c + lds[1023];
        __syncthreads();
    }
    if (threadIdx.x == 0) offsets[N] = Et;
}

__global__ void edge_sort_kernel(const int* __restrict__ ei, int* __restrict__ cursor,
                                 int* __restrict__ srcS, int* __restrict__ dstS, int E, int Et) {
    int e = blockIdx.x * 256 + threadIdx.x;
    if (e >= Et) return;
    int s, d;
    if (e < E) { s = ei[e]; d = ei[E + e]; } else { s = d = e - E; }
    int pos = atomicAdd(&cursor[d], 1);
    srcS[pos] = s;
    dstS[pos] = d;
}

// ------------- per-(edge,head) softmax weights, CSR order, head-major -------------
template<int H>
__global__ void edge_weights_kernel(const int* __restrict__ srcS, const int* __restrict__ dstS,
                                    const float* __restrict__ a_s, const float* __restrict__ a_d,
                                    float* __restrict__ wbuf, int Et) {
    int e = blockIdx.x * 256 + threadIdx.x;
    if (e >= Et) return;
    int h = blockIdx.y;
    int s = srcS[e], d = dstS[e];
    float ev = a_s[s * H + h] + a_d[d * H + h];
    ev = (ev >= 0.0f) ? ev : NEG_SLOPE * ev;
    wbuf[(size_t)h * Et + e] = __expf(ev);
}

// ------------- fused gather-aggregate (H=4): block=node, wave=head, lane=channel -------------
// srcS/wbuf reads are wave-uniform (scalarized); one vector load + FMA per edge.
__global__ void gat_aggregate4(const int* __restrict__ offsets, const int* __restrict__ srcS,
                               const float* __restrict__ wbuf,
                               const float* __restrict__ hW, const float* __restrict__ bias,
                               float* __restrict__ out, int N, int Et) {
    const int n = blockIdx.x;
    if (n >= N) return;
    const int h = threadIdx.x >> 6;
    const int lane = threadIdx.x & 63;
    const int start = offsets[n], end = offsets[n + 1];
    const float* __restrict__ wrow = wbuf + (size_t)h * Et;
    const int voff = h * 64 + lane;
    float acc = 0.0f, den = 0.0f;
    int e = start;
    for (; e + 4 <= end; e += 4) {
        int s0 = srcS[e], s1 = srcS[e+1], s2 = srcS[e+2], s3 = srcS[e+3];
        float w0 = wrow[e], w1 = wrow[e+1], w2 = wrow[e+2], w3 = wrow[e+3];
        float v0 = hW[(size_t)s0 * 256 + voff];
        float v1 = hW[(size_t)s1 * 256 + voff];
        float v2 = hW[(size_t)s2 * 256 + voff];
        float v3 = hW[(size_t)s3 * 256 + voff];
        acc += w0 * v0; den += w0;
        acc += w1 * v1; den += w1;
        acc += w2 * v2; den += w2;
        acc += w3 * v3; den += w3;
    }
    for (; e < end; e++) {
        int s = srcS[e];
        float w = wrow[e];
        acc += w * hW[(size_t)s * 256 + voff];
        den += w;
    }
    float v = acc / (den + 1e-16f) + bias[voff];
    v = (v > 0.0f) ? v : expm1f(v);            // ELU
    out[(size_t)n * 256 + voff] = v;
}

// ------------- H=1 variant: 4 nodes/block, wave=node. No ELU. -------------
__global__ void gat_aggregate1(const int* __restrict__ offsets, const int* __restrict__ srcS,
                               const float* __restrict__ wbuf,
                               const float* __restrict__ hW, const float* __restrict__ bias,
                               float* __restrict__ out, int N) {
    const int n = blockIdx.x * 4 + (threadIdx.x >> 6);
    if (n >= N) return;
    const int lane = threadIdx.x & 63;
    const int start = offsets[n], end = offsets[n + 1];
    float acc = 0.0f, den = 0.0f;
    int e = start;
    for (; e + 4 <= end; e += 4) {
        int s0 = srcS[e], s1 = srcS[e+1], s2 = srcS[e+2], s3 = srcS[e+3];
        float w0 = wbuf[e], w1 = wbuf[e+1], w2 = wbuf[e+2], w3 = wbuf[e+3];
        float v0 = hW[(size_t)s0 * 64 + lane];
        float v1 = hW[(size_t)s1 * 64 + lane];
        float v2 = hW[(size_t)s2 * 64 + lane];
        float v3 = hW[(size_t)s3 * 64 + lane];
        acc += w0 * v0; den += w0;
        acc += w1 * v1; den += w1;
        acc += w2 * v2; den += w2;
        acc += w3 * v3; den += w3;
    }
    for (; e < end; e++) {
        int s = srcS[e];
        float w = wbuf[e];
        acc += w * hW[(size_t)s * 64 + lane];
        den += w;
    }
    out[(size_t)n * 64 + lane] = acc / (den + 1e-16f) + bias[lane];
}

// ------------- per-graph mean pool (batch is sorted) -------------
__global__ void pool_kernel(const float* __restrict__ h, const int* __restrict__ batch,
                            float* __restrict__ pooled, float* __restrict__ cnt,
                            int N, int nWaves) {
    const int w = blockIdx.x * 4 + (threadIdx.x >> 6);
    const int lane = threadIdx.x & 63;
    const int chunk = (N + nWaves - 1) / nWaves;
    int start = w * chunk;
    int end = min(N, start + chunk);
    if (start >= end) return;
    int curg = batch[start];
    int runStart = start;
    float acc = 0.0f;
    for (int n = start; n < end; n++) {
        int g = batch[n];
        if (g != curg) {
            atomicAdd(&pooled[curg * 64 + lane], acc);
            if (lane == 0) atomicAdd(&cnt[curg], (float)(n - runStart));
            acc = 0.0f; curg = g; runStart = n;
        }
        acc += h[(size_t)n * 64 + lane];
    }
    atomicAdd(&pooled[curg * 64 + lane], acc);
    if (lane == 0) atomicAdd(&cnt[curg], (float)(end - runStart));
}

// ------------- decoder head -------------
__global__ void final_kernel(const float* __restrict__ pooled, const float* __restrict__ cnt,
                             const float* __restrict__ gf, const float* __restrict__ Wg,
                             const float* __restrict__ bg, const float* __restrict__ Wd1,
                             const float* __restrict__ bd1, const float* __restrict__ gamma,
                             const float* __restrict__ beta, const float* __restrict__ Wd2,
                             const float* __restrict__ bd2, float* __restrict__ out, int G) {
    __shared__ float sp[16 * 64], sg[16 * 64], sz[16 * 64], slog[16 * 256];
    const int tid = threadIdx.x;
    for (int i = tid; i < G * 64; i += 256) {
        int g = i >> 6;
        sp[i] = pooled[i] / fmaxf(cnt[g], 1.0f);
    }
    for (int i = tid; i < G * 64; i += 256) {
        int g = i >> 6, c = i & 63;
        float v = bg[c];
        #pragma unroll
        for (int k = 0; k < 4; k++) v += gf[g * 4 + k] * Wg[k * 64 + c];
        sg[i] = fmaxf(v, 0.0f);
    }
    __syncthreads();
    for (int i = tid; i < G * 64; i += 256) {
        int g = i >> 6, c = i & 63;
        float v = bd1[c];
        for (int k = 0; k < 64; k++) v += sp[g * 64 + k] * Wd1[k * 64 + c];
        for (int k = 0; k < 64; k++) v += sg[g * 64 + k] * Wd1[(64 + k) * 64 + c];
        v = v * gamma[c] + beta[c];
        sz[i] = fmaxf(v, 0.0f);
    }
    __syncthreads();
    for (int i = tid; i < G * 256; i += 256) {
        int g = i >> 8, j = i & 255;
        float v = bd2[j];
        for (int k = 0; k < 64; k++) v += sz[g * 64 + k] * Wd2[k * 256 + j];
        slog[i] = v;
    }
    __syncthreads();
    const int wid = tid >> 6, lane = tid & 63;
    for (int g = wid; g < G; g += 4) {
        float v0 = slog[g * 256 + lane],       v1 = slog[g * 256 + 64 + lane],
              v2 = slog[g * 256 + 128 + lane], v3 = slog[g * 256 + 192 + lane];
        float m = fmaxf(fmaxf(v0, v1), fmaxf(v2, v3));
        #pragma unroll
        for (int off = 32; off > 0; off >>= 1) m = fmaxf(m, __shfl_xor(m, off));
        float e0 = expf(v0 - m), e1 = expf(v1 - m), e2 = expf(v2 - m), e3 = expf(v3 - m);
        float s = e0 + e1 + e2 + e3;
        #pragma unroll
        for (int off = 32; off > 0; off >>= 1) s += __shfl_xor(s, off);
        float inv = 1.0f / s;
        out[g * 256 + lane]        = e0 * inv;
        out[g * 256 + 64 + lane]   = e1 * inv;
        out[g * 256 + 128 + lane]  = e2 * inv;
        out[g * 256 + 192 + lane]  = e3 * inv;
    }
}

extern "C" void kernel_launch(void* const* d_in, const int* in_sizes, int n_in,
                              void* d_out, int out_size, void* d_ws, size_t ws_size,
                              hipStream_t stream) {
    const float* x     = (const float*)d_in[0];
    const int*   ei    = (const int*)  d_in[1];
    const int*   batch = (const int*)  d_in[2];
    const float* gf    = (const float*)d_in[3];
    const float* W_enc = (const float*)d_in[4];
    const float* b_enc = (const float*)d_in[5];
    const float* W1  = (const float*)d_in[6];
    const float* as1 = (const float*)d_in[7];
    const float* ad1 = (const float*)d_in[8];
    const float* b1  = (const float*)d_in[9];
    const float* W2  = (const float*)d_in[10];
    const float* as2 = (const float*)d_in[11];
    const float* ad2 = (const float*)d_in[12];
    const float* b2  = (const float*)d_in[13];
    const float* W3  = (const float*)d_in[14];
    const float* as3 = (const float*)d_in[15];
    const float* ad3 = (const float*)d_in[16];
    const float* b3  = (const float*)d_in[17];
    const float* Wg  = (const float*)d_in[18];
    const float* bg  = (const float*)d_in[19];
    const float* Wd1 = (const float*)d_in[20];
    const float* bd1 = (const float*)d_in[21];
    const float* gm  = (const float*)d_in[22];
    const float* bt  = (const float*)d_in[23];
    const float* Wd2 = (const float*)d_in[24];
    const float* bd2 = (const float*)d_in[25];

    const int N  = in_sizes[2];
    const int E  = in_sizes[1] / 2;
    const int G  = in_sizes[3] / 4;
    const int Et = E + N;

    float* bufA   = (float*)d_ws;                 // [N,256]
    float* bufB   = bufA + (size_t)N * 256;       // [N,256]
    float* a_s    = bufB + (size_t)N * 256;       // [N,4]
    float* a_d    = a_s  + (size_t)N * 4;         // [N,4]
    float* pooled = a_d  + (size_t)N * 4;         // [G,64]
    float* cnt    = pooled + (size_t)G * 64;      // [G]
    int*   offsets = (int*)(cnt + G);             // [N+1]
    int*   srcS    = offsets + (N + 1);           // [Et]
    int*   dstS    = srcS + Et;                   // [Et]
    float* wbuf    = (float*)(dstS + Et);         // [4,Et]
    // counts/cursor alias bufB (dead before bufB's first GEMM write)
    int*   counts  = (int*)bufB;
    int*   cursor  = counts + N;

    dim3 blk(256);
    auto cdiv = [](int a, int b) { return (a + b - 1) / b; };
    const int eBlocks = cdiv(Et, 256);

    // ---------------- CSR build (once, reused by all 3 convs) ----------------
    hipMemsetAsync(counts, 0, (size_t)N * sizeof(int), stream);
    edge_hist_kernel<<<eBlocks, blk, 0, stream>>>(ei, counts, E, Et);
    scan_kernel<<<1, 1024, 0, stream>>>(counts, offsets, cursor, N, Et);
    edge_sort_kernel<<<eBlocks, blk, 0, stream>>>(ei, cursor, srcS, dstS, E, Et);

    const int rowBlocks = cdiv(N, 64);

    // encoder: bufA = x @ W_enc + b_enc   [N,64]
    gemm64<<<dim3(rowBlocks, 1), blk, 0, stream>>>(x, W_enc, b_enc, bufA, N, 32, 64);

    // ---------------- conv1 (H=4, in=64) ----------------
    gemm64<<<dim3(rowBlocks, 4), blk, 0, stream>>>(bufA, W1, nullptr, bufB, N, 64, 256);
    att_scores_kernel<4><<<cdiv(N, 4), blk, 0, stream>>>(bufB, as1, ad1, a_s, a_d, N);
    edge_weights_kernel<4><<<dim3(eBlocks, 4), blk, 0, stream>>>(srcS, dstS, a_s, a_d, wbuf, Et);
    gat_aggregate4<<<N, blk, 0, stream>>>(offsets, srcS, wbuf, bufB, b1, bufA, N, Et);

    // ---------------- conv2 (H=4, in=256) ----------------
    gemm64<<<dim3(rowBlocks, 4), blk, 0, stream>>>(bufA, W2, nullptr, bufB, N, 256, 256);
    att_scores_kernel<4><<<cdiv(N, 4), blk, 0, stream>>>(bufB, as2, ad2, a_s, a_d, N);
    edge_weights_kernel<4><<<dim3(eBlocks, 4), blk, 0, stream>>>(srcS, dstS, a_s, a_d, wbuf, Et);
    gat_aggregate4<<<N, blk, 0, stream>>>(offsets, srcS, wbuf, bufB, b2, bufA, N, Et);

    // ---------------- conv3 (H=1, in=256, no concat) ----------------
    gemm64<<<dim3(rowBlocks, 1), blk, 0, stream>>>(bufA, W3, nullptr, bufB, N, 256, 64);
    att_scores_kernel<1><<<cdiv(N, 4), blk, 0, stream>>>(bufB, as3, ad3, a_s, a_d, N);
    edge_weights_kernel<1><<<dim3(eBlocks, 1), blk, 0, stream>>>(srcS, dstS, a_s, a_d, wbuf, Et);
    gat_aggregate1<<<cdiv(N, 4), blk, 0, stream>>>(offsets, srcS, wbuf, bufB, b3, bufA, N);

    // ---------------- mean pool + decoder head ----------------
    hipMemsetAsync(pooled, 0, (size_t)G * 64 * sizeof(float), stream);
    hipMemsetAsync(cnt, 0, (size_t)G * sizeof(float), stream);
    pool_kernel<<<512, blk, 0, stream>>>(bufA, batch, pooled, cnt, N, 512 * 4);
    final_kernel<<<1, blk, 0, stream>>>(pooled, cnt, gf, Wg, bg, Wd1, bd1, gm, bt, Wd2, bd2,
                                        (float*)d_out, G);
}

// Round 5
// 902.115 us; speedup vs baseline: 2.6639x; 1.0878x over previous
//
#include <hip/hip_runtime.h>
#include <math.h>

#define NEG_SLOPE 0.2f

__device__ inline float b2f(unsigned short u) {
    union { unsigned int i; float f; } x; x.i = ((unsigned int)u) << 16; return x.f;
}
__device__ inline unsigned short f2b(float f) {
    union { float f; unsigned int i; } u; u.f = f;
    unsigned int r = u.i + 0x7FFF + ((u.i >> 16) & 1);   // round-to-nearest-even
    return (unsigned short)(r >> 16);
}

// ---------------- GEMM: C[N,M] = A[N,K] @ B[K,M] ----------------
// 64x64 tile, 256 threads, 4x4 micro-tile, k-sliced by 16, prefetched staging.
// MODE 0: fp32 out + bias (encoder).
// MODE 1: bf16 out (no bias) + fused per-head attention scores:
//         blockIdx.y is the head; this block owns the head's full 64-channel
//         slice for its 64 rows, so a_s/a_d are complete (shfl-reduce, store).
template<int MODE>
__global__ __launch_bounds__(256) void gemm64(const float* __restrict__ A,
                                              const float* __restrict__ B,
                                              const float* __restrict__ bias,
                                              float* __restrict__ C,
                                              unsigned short* __restrict__ C16,
                                              const float* __restrict__ att_s,
                                              const float* __restrict__ att_d,
                                              float* __restrict__ a_s,
                                              float* __restrict__ a_d,
                                              int Nrows, int K, int M, int H) {
    __shared__ float sA[16][64];   // [k][row]
    __shared__ float sB[16][64];   // [k][col]
    const int tx = threadIdx.x & 15;
    const int ty = threadIdx.x >> 4;
    const int row0 = blockIdx.x * 64;
    const int col0 = blockIdx.y * 64;
    const int lr = threadIdx.x >> 2;
    const int lk = (threadIdx.x & 3) << 2;
    const int br = threadIdx.x >> 4;
    const int bc = (threadIdx.x & 15) << 2;

    const int aRow = row0 + lr;
    const bool aValid = aRow < Nrows;
    const float* Aptr = A + (size_t)aRow * K + lk;
    const float* Bptr = B + (size_t)br * M + col0 + bc;

    float acc[4][4] = {{0,0,0,0},{0,0,0,0},{0,0,0,0},{0,0,0,0}};

    float4 a = aValid ? *(const float4*)Aptr : float4{0,0,0,0};
    float4 b = *(const float4*)Bptr;

    for (int kt = 0; kt < K; kt += 16) {
        __syncthreads();
        sA[lk+0][lr] = a.x; sA[lk+1][lr] = a.y; sA[lk+2][lr] = a.z; sA[lk+3][lr] = a.w;
        *(float4*)&sB[br][bc] = b;
        __syncthreads();
        if (kt + 16 < K) {
            a = aValid ? *(const float4*)(Aptr + kt + 16) : float4{0,0,0,0};
            b = *(const float4*)(Bptr + (size_t)(kt + 16) * M);
        }
        #pragma unroll
        for (int k = 0; k < 16; k++) {
            const float4 av = *(const float4*)&sA[k][ty << 2];
            const float4 bv = *(const float4*)&sB[k][tx << 2];
            acc[0][0] += av.x*bv.x; acc[0][1] += av.x*bv.y; acc[0][2] += av.x*bv.z; acc[0][3] += av.x*bv.w;
            acc[1][0] += av.y*bv.x; acc[1][1] += av.y*bv.y; acc[1][2] += av.y*bv.z; acc[1][3] += av.y*bv.w;
            acc[2][0] += av.z*bv.x; acc[2][1] += av.z*bv.y; acc[2][2] += av.z*bv.z; acc[2][3] += av.z*bv.w;
            acc[3][0] += av.w*bv.x; acc[3][1] += av.w*bv.y; acc[3][2] += av.w*bv.z; acc[3][3] += av.w*bv.w;
        }
    }

    if (MODE == 0) {
        float4 bb = {0,0,0,0};
        if (bias) bb = *(const float4*)&bias[col0 + (tx << 2)];
        #pragma unroll
        for (int i = 0; i < 4; i++) {
            int r = row0 + (ty << 2) + i;
            if (r < Nrows) {
                float4 o = {acc[i][0] + bb.x, acc[i][1] + bb.y, acc[i][2] + bb.z, acc[i][3] + bb.w};
                *(float4*)&C[(size_t)r * M + col0 + (tx << 2)] = o;
            }
        }
    } else {
        const int h = blockIdx.y;
        // fused attention scores (fp32 accumulators)
        const float4 asv = *(const float4*)&att_s[h * 64 + (tx << 2)];
        const float4 adv = *(const float4*)&att_d[h * 64 + (tx << 2)];
        float ps[4], pd[4];
        #pragma unroll
        for (int i = 0; i < 4; i++) {
            ps[i] = acc[i][0]*asv.x + acc[i][1]*asv.y + acc[i][2]*asv.z + acc[i][3]*asv.w;
            pd[i] = acc[i][0]*adv.x + acc[i][1]*adv.y + acc[i][2]*adv.z + acc[i][3]*adv.w;
        }
        #pragma unroll
        for (int m = 1; m < 16; m <<= 1) {
            #pragma unroll
            for (int i = 0; i < 4; i++) {
                ps[i] += __shfl_xor(ps[i], m);
                pd[i] += __shfl_xor(pd[i], m);
            }
        }
        if (tx == 0) {
            #pragma unroll
            for (int i = 0; i < 4; i++) {
                int r = row0 + (ty << 2) + i;
                if (r < Nrows) { a_s[r * H + h] = ps[i]; a_d[r * H + h] = pd[i]; }
            }
        }
        // bf16 store
        #pragma unroll
        for (int i = 0; i < 4; i++) {
            int r = row0 + (ty << 2) + i;
            if (r < Nrows) {
                ushort4 o = {f2b(acc[i][0]), f2b(acc[i][1]), f2b(acc[i][2]), f2b(acc[i][3])};
                *(ushort4*)&C16[(size_t)r * M + col0 + (tx << 2)] = o;
            }
        }
    }
}

// ------------- CSR build: histogram / scan / scatter-sort -------------
__global__ void edge_hist_kernel(const int* __restrict__ ei, int* __restrict__ counts,
                                 int E, int Et) {
    int e = blockIdx.x * 256 + threadIdx.x;
    if (e >= Et) return;
    int d = (e < E) ? ei[E + e] : e - E;
    atomicAdd(&counts[d], 1);
}

// blocked serial scan: 1024 threads x ~N/1024 elements, one Hillis-Steele pass
__global__ __launch_bounds__(1024) void scan_kernel(const int* __restrict__ counts,
                                                    int* __restrict__ offsets,
                                                    int* __restrict__ cursor, int N, int Et) {
    __shared__ int lds[1024];
    const int PER = (N + 1023) >> 10;
    const int base = threadIdx.x * PER;
    int sum = 0;
    for (int j = 0; j < PER; j++) {
        int i = base + j;
        if (i < N) sum += counts[i];
    }
    lds[threadIdx.x] = sum;
    __syncthreads();
    for (int off = 1; off < 1024; off <<= 1) {
        int t = (threadIdx.x >= off) ? lds[threadIdx.x - off] : 0;
        __syncthreads();
        lds[threadIdx.x] += t;
        __syncthreads();
    }
    int running = lds[threadIdx.x] - sum;      // exclusive prefix of this thread's block
    for (int j = 0; j < PER; j++) {
        int i = base + j;
        if (i < N) {
            offsets[i] = running;
            cursor[i] = running;
            running += counts[i];
        }
    }
    if (threadIdx.x == 0) offsets[N] = Et;
}

__global__ void edge_sort_kernel(const int* __restrict__ ei, int* __restrict__ cursor,
                                 int* __restrict__ srcS, int* __restrict__ dstS, int E, int Et) {
    int e = blockIdx.x * 256 + threadIdx.x;
    if (e >= Et) return;
    int s, d;
    if (e < E) { s = ei[e]; d = ei[E + e]; } else { s = d = e - E; }
    int pos = atomicAdd(&cursor[d], 1);
    srcS[pos] = s;
    dstS[pos] = d;
}

// ------------- per-(edge,head) softmax weights, CSR order, head-major -------------
template<int H>
__global__ void edge_weights_kernel(const int* __restrict__ srcS, const int* __restrict__ dstS,
                                    const float* __restrict__ a_s, const float* __restrict__ a_d,
                                    float* __restrict__ wbuf, int Et) {
    int e = blockIdx.x * 256 + threadIdx.x;
    if (e >= Et) return;
    int h = blockIdx.y;
    int s = srcS[e], d = dstS[e];
    float ev = a_s[s * H + h] + a_d[d * H + h];
    ev = (ev >= 0.0f) ? ev : NEG_SLOPE * ev;
    wbuf[(size_t)h * Et + e] = __expf(ev);
}

// ------------- fused gather-aggregate (H=4): block=node, wave=head, lane=channel -------------
// bf16 message gather; srcS/wbuf reads are wave-uniform (scalarized).
__global__ void gat_aggregate4(const int* __restrict__ offsets, const int* __restrict__ srcS,
                               const float* __restrict__ wbuf,
                               const unsigned short* __restrict__ hW16,
                               const float* __restrict__ bias,
                               float* __restrict__ out, int N, int Et) {
    const int n = blockIdx.x;
    if (n >= N) return;
    const int h = threadIdx.x >> 6;
    const int lane = threadIdx.x & 63;
    const int start = offsets[n], end = offsets[n + 1];
    const float* __restrict__ wrow = wbuf + (size_t)h * Et;
    const int voff = h * 64 + lane;
    float acc = 0.0f, den = 0.0f;
    int e = start;
    for (; e + 4 <= end; e += 4) {
        int s0 = srcS[e], s1 = srcS[e+1], s2 = srcS[e+2], s3 = srcS[e+3];
        float w0 = wrow[e], w1 = wrow[e+1], w2 = wrow[e+2], w3 = wrow[e+3];
        float v0 = b2f(hW16[(size_t)s0 * 256 + voff]);
        float v1 = b2f(hW16[(size_t)s1 * 256 + voff]);
        float v2 = b2f(hW16[(size_t)s2 * 256 + voff]);
        float v3 = b2f(hW16[(size_t)s3 * 256 + voff]);
        acc += w0 * v0; den += w0;
        acc += w1 * v1; den += w1;
        acc += w2 * v2; den += w2;
        acc += w3 * v3; den += w3;
    }
    for (; e < end; e++) {
        int s = srcS[e];
        float w = wrow[e];
        acc += w * b2f(hW16[(size_t)s * 256 + voff]);
        den += w;
    }
    float v = acc / (den + 1e-16f) + bias[voff];
    v = (v > 0.0f) ? v : expm1f(v);            // ELU
    out[(size_t)n * 256 + voff] = v;
}

// ------------- H=1 variant: 4 nodes/block, wave=node. No ELU. -------------
__global__ void gat_aggregate1(const int* __restrict__ offsets, const int* __restrict__ srcS,
                               const float* __restrict__ wbuf,
                               const unsigned short* __restrict__ hW16,
                               const float* __restrict__ bias,
                               float* __restrict__ out, int N) {
    const int n = blockIdx.x * 4 + (threadIdx.x >> 6);
    if (n >= N) return;
    const int lane = threadIdx.x & 63;
    const int start = offsets[n], end = offsets[n + 1];
    float acc = 0.0f, den = 0.0f;
    int e = start;
    for (; e + 4 <= end; e += 4) {
        int s0 = srcS[e], s1 = srcS[e+1], s2 = srcS[e+2], s3 = srcS[e+3];
        float w0 = wbuf[e], w1 = wbuf[e+1], w2 = wbuf[e+2], w3 = wbuf[e+3];
        float v0 = b2f(hW16[(size_t)s0 * 64 + lane]);
        float v1 = b2f(hW16[(size_t)s1 * 64 + lane]);
        float v2 = b2f(hW16[(size_t)s2 * 64 + lane]);
        float v3 = b2f(hW16[(size_t)s3 * 64 + lane]);
        acc += w0 * v0; den += w0;
        acc += w1 * v1; den += w1;
        acc += w2 * v2; den += w2;
        acc += w3 * v3; den += w3;
    }
    for (; e < end; e++) {
        int s = srcS[e];
        float w = wbuf[e];
        acc += w * b2f(hW16[(size_t)s * 64 + lane]);
        den += w;
    }
    out[(size_t)n * 64 + lane] = acc / (den + 1e-16f) + bias[lane];
}

// ------------- per-graph mean pool (batch is sorted) -------------
__global__ void pool_kernel(const float* __restrict__ h, const int* __restrict__ batch,
                            float* __restrict__ pooled, float* __restrict__ cnt,
                            int N, int nWaves) {
    const int w = blockIdx.x * 4 + (threadIdx.x >> 6);
    const int lane = threadIdx.x & 63;
    const int chunk = (N + nWaves - 1) / nWaves;
    int start = w * chunk;
    int end = min(N, start + chunk);
    if (start >= end) return;
    int curg = batch[start];
    int runStart = start;
    float acc = 0.0f;
    for (int n = start; n < end; n++) {
        int g = batch[n];
        if (g != curg) {
            atomicAdd(&pooled[curg * 64 + lane], acc);
            if (lane == 0) atomicAdd(&cnt[curg], (float)(n - runStart));
            acc = 0.0f; curg = g; runStart = n;
        }
        acc += h[(size_t)n * 64 + lane];
    }
    atomicAdd(&pooled[curg * 64 + lane], acc);
    if (lane == 0) atomicAdd(&cnt[curg], (float)(end - runStart));
}

// ------------- decoder head -------------
__global__ void final_kernel(const float* __restrict__ pooled, const float* __restrict__ cnt,
                             const float* __restrict__ gf, const float* __restrict__ Wg,
                             const float* __restrict__ bg, const float* __restrict__ Wd1,
                             const float* __restrict__ bd1, const float* __restrict__ gamma,
                             const float* __restrict__ beta, const float* __restrict__ Wd2,
                             const float* __restrict__ bd2, float* __restrict__ out, int G) {
    __shared__ float sp[16 * 64], sg[16 * 64], sz[16 * 64], slog[16 * 256];
    const int tid = threadIdx.x;
    for (int i = tid; i < G * 64; i += 256) {
        int g = i >> 6;
        sp[i] = pooled[i] / fmaxf(cnt[g], 1.0f);
    }
    for (int i = tid; i < G * 64; i += 256) {
        int g = i >> 6, c = i & 63;
        float v = bg[c];
        #pragma unroll
        for (int k = 0; k < 4; k++) v += gf[g * 4 + k] * Wg[k * 64 + c];
        sg[i] = fmaxf(v, 0.0f);
    }
    __syncthreads();
    for (int i = tid; i < G * 64; i += 256) {
        int g = i >> 6, c = i & 63;
        float v = bd1[c];
        for (int k = 0; k < 64; k++) v += sp[g * 64 + k] * Wd1[k * 64 + c];
        for (int k = 0; k < 64; k++) v += sg[g * 64 + k] * Wd1[(64 + k) * 64 + c];
        v = v * gamma[c] + beta[c];
        sz[i] = fmaxf(v, 0.0f);
    }
    __syncthreads();
    for (int i = tid; i < G * 256; i += 256) {
        int g = i >> 8, j = i & 255;
        float v = bd2[j];
        for (int k = 0; k < 64; k++) v += sz[g * 64 + k] * Wd2[k * 256 + j];
        slog[i] = v;
    }
    __syncthreads();
    const int wid = tid >> 6, lane = tid & 63;
    for (int g = wid; g < G; g += 4) {
        float v0 = slog[g * 256 + lane],       v1 = slog[g * 256 + 64 + lane],
              v2 = slog[g * 256 + 128 + lane], v3 = slog[g * 256 + 192 + lane];
        float m = fmaxf(fmaxf(v0, v1), fmaxf(v2, v3));
        #pragma unroll
        for (int off = 32; off > 0; off >>= 1) m = fmaxf(m, __shfl_xor(m, off));
        float e0 = expf(v0 - m), e1 = expf(v1 - m), e2 = expf(v2 - m), e3 = expf(v3 - m);
        float s = e0 + e1 + e2 + e3;
        #pragma unroll
        for (int off = 32; off > 0; off >>= 1) s += __shfl_xor(s, off);
        float inv = 1.0f / s;
        out[g * 256 + lane]        = e0 * inv;
        out[g * 256 + 64 + lane]   = e1 * inv;
        out[g * 256 + 128 + lane]  = e2 * inv;
        out[g * 256 + 192 + lane]  = e3 * inv;
    }
}

extern "C" void kernel_launch(void* const* d_in, const int* in_sizes, int n_in,
                              void* d_out, int out_size, void* d_ws, size_t ws_size,
                              hipStream_t stream) {
    const float* x     = (const float*)d_in[0];
    const int*   ei    = (const int*)  d_in[1];
    const int*   batch = (const int*)  d_in[2];
    const float* gf    = (const float*)d_in[3];
    const float* W_enc = (const float*)d_in[4];
    const float* b_enc = (const float*)d_in[5];
    const float* W1  = (const float*)d_in[6];
    const float* as1 = (const float*)d_in[7];
    const float* ad1 = (const float*)d_in[8];
    const float* b1  = (const float*)d_in[9];
    const float* W2  = (const float*)d_in[10];
    const float* as2 = (const float*)d_in[11];
    const float* ad2 = (const float*)d_in[12];
    const float* b2  = (const float*)d_in[13];
    const float* W3  = (const float*)d_in[14];
    const float* as3 = (const float*)d_in[15];
    const float* ad3 = (const float*)d_in[16];
    const float* b3  = (const float*)d_in[17];
    const float* Wg  = (const float*)d_in[18];
    const float* bg  = (const float*)d_in[19];
    const float* Wd1 = (const float*)d_in[20];
    const float* bd1 = (const float*)d_in[21];
    const float* gm  = (const float*)d_in[22];
    const float* bt  = (const float*)d_in[23];
    const float* Wd2 = (const float*)d_in[24];
    const float* bd2 = (const float*)d_in[25];

    const int N  = in_sizes[2];
    const int E  = in_sizes[1] / 2;
    const int G  = in_sizes[3] / 4;
    const int Et = E + N;

    float*          bufA   = (float*)d_ws;                       // [N,256] fp32
    unsigned short* hW16   = (unsigned short*)(bufA + (size_t)N * 256);  // [N,256] bf16
    float* a_s    = (float*)(hW16 + (size_t)N * 256);            // [N,4]
    float* a_d    = a_s  + (size_t)N * 4;                        // [N,4]
    float* wbuf   = a_d  + (size_t)N * 4;                        // [4,Et]
    float* pooled = wbuf + (size_t)4 * Et;                       // [G,64]
    float* cnt    = pooled + (size_t)G * 64;                     // [G]
    int*   offsets = (int*)(cnt + G);                            // [N+1]
    int*   srcS    = offsets + (N + 1);                          // [Et]
    int*   dstS    = srcS + Et;                                  // [Et]
    int*   counts  = dstS + Et;                                  // [N]
    int*   cursor  = counts + N;                                 // [N]

    dim3 blk(256);
    auto cdiv = [](int a, int b) { return (a + b - 1) / b; };
    const int eBlocks = cdiv(Et, 256);
    const int rowBlocks = cdiv(N, 64);

    // ---------------- CSR build (once, reused by all 3 convs) ----------------
    hipMemsetAsync(counts, 0, (size_t)N * sizeof(int), stream);
    edge_hist_kernel<<<eBlocks, blk, 0, stream>>>(ei, counts, E, Et);
    scan_kernel<<<1, 1024, 0, stream>>>(counts, offsets, cursor, N, Et);
    edge_sort_kernel<<<eBlocks, blk, 0, stream>>>(ei, cursor, srcS, dstS, E, Et);

    // encoder: bufA = x @ W_enc + b_enc   [N,64] fp32
    gemm64<0><<<dim3(rowBlocks, 1), blk, 0, stream>>>(x, W_enc, b_enc, bufA, nullptr,
                                                      nullptr, nullptr, nullptr, nullptr,
                                                      N, 32, 64, 1);

    // ---------------- conv1 (H=4, in=64) ----------------
    gemm64<1><<<dim3(rowBlocks, 4), blk, 0, stream>>>(bufA, W1, nullptr, nullptr, hW16,
                                                      as1, ad1, a_s, a_d, N, 64, 256, 4);
    edge_weights_kernel<4><<<dim3(eBlocks, 4), blk, 0, stream>>>(srcS, dstS, a_s, a_d, wbuf, Et);
    gat_aggregate4<<<N, blk, 0, stream>>>(offsets, srcS, wbuf, hW16, b1, bufA, N, Et);

    // ---------------- conv2 (H=4, in=256) ----------------
    gemm64<1><<<dim3(rowBlocks, 4), blk, 0, stream>>>(bufA, W2, nullptr, nullptr, hW16,
                                                      as2, ad2, a_s, a_d, N, 256, 256, 4);
    edge_weights_kernel<4><<<dim3(eBlocks, 4), blk, 0, stream>>>(srcS, dstS, a_s, a_d, wbuf, Et);
    gat_aggregate4<<<N, blk, 0, stream>>>(offsets, srcS, wbuf, hW16, b2, bufA, N, Et);

    // ---------------- conv3 (H=1, in=256, no concat) ----------------
    gemm64<1><<<dim3(rowBlocks, 1), blk, 0, stream>>>(bufA, W3, nullptr, nullptr, hW16,
                                                      as3, ad3, a_s, a_d, N, 256, 64, 1);
    edge_weights_kernel<1><<<dim3(eBlocks, 1), blk, 0, stream>>>(srcS, dstS, a_s, a_d, wbuf, Et);
    gat_aggregate1<<<cdiv(N, 4), blk, 0, stream>>>(offsets, srcS, wbuf, hW16, b3, bufA, N);

    // ---------------- mean pool + decoder head ----------------
    hipMemsetAsync(pooled, 0, (size_t)G * 64 * sizeof(float), stream);
    hipMemsetAsync(cnt, 0, (size_t)G * sizeof(float), stream);
    pool_kernel<<<512, blk, 0, stream>>>(bufA, batch, pooled, cnt, N, 512 * 4);
    final_kernel<<<1, blk, 0, stream>>>(pooled, cnt, gf, Wg, bg, Wd1, bd1, gm, bt, Wd2, bd2,
                                        (float*)d_out, G);
}

// Round 6
// 786.128 us; speedup vs baseline: 3.0570x; 1.1475x over previous
//
#include <hip/hip_runtime.h>
#include <math.h>

#define NEG_SLOPE 0.2f

__device__ inline float b2f(unsigned short u) {
    union { unsigned int i; float f; } x; x.i = ((unsigned int)u) << 16; return x.f;
}
__device__ inline unsigned short f2b(float f) {
    union { float f; unsigned int i; } u; u.f = f;
    unsigned int r = u.i + 0x7FFF + ((u.i >> 16) & 1);   // round-to-nearest-even
    return (unsigned short)(r >> 16);
}

// ---------------- GEMM: C[N,M] = A[N,K] @ B[K,M] ----------------
// 64x64 tile, 256 threads, 4x4 micro-tile, k-sliced by 16, prefetched staging.
// MODE 0: fp32 out + bias (encoder).
// MODE 1: bf16 out (no bias) + fused per-head attention scores.
template<int MODE>
__global__ __launch_bounds__(256) void gemm64(const float* __restrict__ A,
                                              const float* __restrict__ B,
                                              const float* __restrict__ bias,
                                              float* __restrict__ C,
                                              unsigned short* __restrict__ C16,
                                              const float* __restrict__ att_s,
                                              const float* __restrict__ att_d,
                                              float* __restrict__ a_s,
                                              float* __restrict__ a_d,
                                              int Nrows, int K, int M, int H) {
    __shared__ float sA[16][64];   // [k][row]
    __shared__ float sB[16][64];   // [k][col]
    const int tx = threadIdx.x & 15;
    const int ty = threadIdx.x >> 4;
    const int row0 = blockIdx.x * 64;
    const int col0 = blockIdx.y * 64;
    const int lr = threadIdx.x >> 2;
    const int lk = (threadIdx.x & 3) << 2;
    const int br = threadIdx.x >> 4;
    const int bc = (threadIdx.x & 15) << 2;

    const int aRow = row0 + lr;
    const bool aValid = aRow < Nrows;
    const float* Aptr = A + (size_t)aRow * K + lk;
    const float* Bptr = B + (size_t)br * M + col0 + bc;

    float acc[4][4] = {{0,0,0,0},{0,0,0,0},{0,0,0,0},{0,0,0,0}};

    float4 a = aValid ? *(const float4*)Aptr : float4{0,0,0,0};
    float4 b = *(const float4*)Bptr;

    for (int kt = 0; kt < K; kt += 16) {
        __syncthreads();
        sA[lk+0][lr] = a.x; sA[lk+1][lr] = a.y; sA[lk+2][lr] = a.z; sA[lk+3][lr] = a.w;
        *(float4*)&sB[br][bc] = b;
        __syncthreads();
        if (kt + 16 < K) {
            a = aValid ? *(const float4*)(Aptr + kt + 16) : float4{0,0,0,0};
            b = *(const float4*)(Bptr + (size_t)(kt + 16) * M);
        }
        #pragma unroll
        for (int k = 0; k < 16; k++) {
            const float4 av = *(const float4*)&sA[k][ty << 2];
            const float4 bv = *(const float4*)&sB[k][tx << 2];
            acc[0][0] += av.x*bv.x; acc[0][1] += av.x*bv.y; acc[0][2] += av.x*bv.z; acc[0][3] += av.x*bv.w;
            acc[1][0] += av.y*bv.x; acc[1][1] += av.y*bv.y; acc[1][2] += av.y*bv.z; acc[1][3] += av.y*bv.w;
            acc[2][0] += av.z*bv.x; acc[2][1] += av.z*bv.y; acc[2][2] += av.z*bv.z; acc[2][3] += av.z*bv.w;
            acc[3][0] += av.w*bv.x; acc[3][1] += av.w*bv.y; acc[3][2] += av.w*bv.z; acc[3][3] += av.w*bv.w;
        }
    }

    if (MODE == 0) {
        float4 bb = {0,0,0,0};
        if (bias) bb = *(const float4*)&bias[col0 + (tx << 2)];
        #pragma unroll
        for (int i = 0; i < 4; i++) {
            int r = row0 + (ty << 2) + i;
            if (r < Nrows) {
                float4 o = {acc[i][0] + bb.x, acc[i][1] + bb.y, acc[i][2] + bb.z, acc[i][3] + bb.w};
                *(float4*)&C[(size_t)r * M + col0 + (tx << 2)] = o;
            }
        }
    } else {
        const int h = blockIdx.y;
        const float4 asv = *(const float4*)&att_s[h * 64 + (tx << 2)];
        const float4 adv = *(const float4*)&att_d[h * 64 + (tx << 2)];
        float ps[4], pd[4];
        #pragma unroll
        for (int i = 0; i < 4; i++) {
            ps[i] = acc[i][0]*asv.x + acc[i][1]*asv.y + acc[i][2]*asv.z + acc[i][3]*asv.w;
            pd[i] = acc[i][0]*adv.x + acc[i][1]*adv.y + acc[i][2]*adv.z + acc[i][3]*adv.w;
        }
        #pragma unroll
        for (int m = 1; m < 16; m <<= 1) {
            #pragma unroll
            for (int i = 0; i < 4; i++) {
                ps[i] += __shfl_xor(ps[i], m);
                pd[i] += __shfl_xor(pd[i], m);
            }
        }
        if (tx == 0) {
            #pragma unroll
            for (int i = 0; i < 4; i++) {
                int r = row0 + (ty << 2) + i;
                if (r < Nrows) { a_s[r * H + h] = ps[i]; a_d[r * H + h] = pd[i]; }
            }
        }
        #pragma unroll
        for (int i = 0; i < 4; i++) {
            int r = row0 + (ty << 2) + i;
            if (r < Nrows) {
                ushort4 o = {f2b(acc[i][0]), f2b(acc[i][1]), f2b(acc[i][2]), f2b(acc[i][3])};
                *(ushort4*)&C16[(size_t)r * M + col0 + (tx << 2)] = o;
            }
        }
    }
}

// ------------- CSR build: histogram / 3-phase scan / scatter-sort -------------
__global__ void edge_hist_kernel(const int* __restrict__ ei, int* __restrict__ counts,
                                 int E, int Et) {
    int e = blockIdx.x * 256 + threadIdx.x;
    if (e >= Et) return;
    int d = (e < E) ? ei[E + e] : e - E;
    atomicAdd(&counts[d], 1);
}

// phase 1: per-block (1024-elem) scan, coalesced, wave-shfl based.
// Writes exclusive partials in-place over counts; one sum per block.
__global__ __launch_bounds__(1024) void scan_blocks(int* __restrict__ counts,
                                                    int* __restrict__ blockSums, int N) {
    __shared__ int wsum[16];
    const int tid = threadIdx.x;
    const int lane = tid & 63;
    const int wave = tid >> 6;
    int i = blockIdx.x * 1024 + tid;
    int v = (i < N) ? counts[i] : 0;
    int s = v;                                   // inclusive scan within wave
    #pragma unroll
    for (int off = 1; off < 64; off <<= 1) {
        int t = __shfl_up(s, off);
        if (lane >= off) s += t;
    }
    if (lane == 63) wsum[wave] = s;
    __syncthreads();
    if (wave == 0 && lane < 16) {
        int ws = wsum[lane];
        #pragma unroll
        for (int off = 1; off < 16; off <<= 1) {
            int t = __shfl_up(ws, off);
            if (lane >= off) ws += t;
        }
        wsum[lane] = ws;                         // inclusive wave sums
    }
    __syncthreads();
    int waveOff = (wave > 0) ? wsum[wave - 1] : 0;
    int incl = s + waveOff;
    if (i < N) counts[i] = incl - v;             // exclusive within block
    if (tid == 1023) blockSums[blockIdx.x] = incl;
}

// phase 2: single wave scans block sums (handles up to 64*chunks serially)
__global__ void scan_sums(int* __restrict__ bs, int nb) {
    const int lane = threadIdx.x;                // 64 threads
    int carry = 0;
    for (int base = 0; base < nb; base += 64) {
        int i = base + lane;
        int v = (i < nb) ? bs[i] : 0;
        int s = v;
        #pragma unroll
        for (int off = 1; off < 64; off <<= 1) {
            int t = __shfl_up(s, off);
            if (lane >= off) s += t;
        }
        if (i < nb) bs[i] = carry + s - v;       // exclusive
        carry += __shfl(s, 63);
    }
}

// phase 3: add block offset, write offsets + cursor
__global__ void scan_add(const int* __restrict__ excl, const int* __restrict__ blockSums,
                         int* __restrict__ offsets, int* __restrict__ cursor, int N, int Et) {
    int i = blockIdx.x * 256 + threadIdx.x;
    if (i < N) {
        int o = excl[i] + blockSums[i >> 10];
        offsets[i] = o;
        cursor[i] = o;
    }
    if (i == N) offsets[N] = Et;
}

__global__ void edge_sort_kernel(const int* __restrict__ ei, int* __restrict__ cursor,
                                 int* __restrict__ srcS, int* __restrict__ dstS, int E, int Et) {
    int e = blockIdx.x * 256 + threadIdx.x;
    if (e >= Et) return;
    int s, d;
    if (e < E) { s = ei[e]; d = ei[E + e]; } else { s = d = e - E; }
    int pos = atomicAdd(&cursor[d], 1);
    srcS[pos] = s;
    dstS[pos] = d;
}

// ------------- per-(edge,head) softmax weights, CSR order, head-major -------------
template<int H>
__global__ void edge_weights_kernel(const int* __restrict__ srcS, const int* __restrict__ dstS,
                                    const float* __restrict__ a_s, const float* __restrict__ a_d,
                                    float* __restrict__ wbuf, int Et) {
    int e = blockIdx.x * 256 + threadIdx.x;
    if (e >= Et) return;
    int h = blockIdx.y;
    int s = srcS[e], d = dstS[e];
    float ev = a_s[s * H + h] + a_d[d * H + h];
    ev = (ev >= 0.0f) ? ev : NEG_SLOPE * ev;
    wbuf[(size_t)h * Et + e] = __expf(ev);
}

// ------------- fused gather-aggregate (H=4): block=node, wave=head, lane=channel -------------
__global__ void gat_aggregate4(const int* __restrict__ offsets, const int* __restrict__ srcS,
                               const float* __restrict__ wbuf,
                               const unsigned short* __restrict__ hW16,
                               const float* __restrict__ bias,
                               float* __restrict__ out, int N, int Et) {
    const int n = blockIdx.x;
    if (n >= N) return;
    const int h = threadIdx.x >> 6;
    const int lane = threadIdx.x & 63;
    const int start = offsets[n], end = offsets[n + 1];
    const float* __restrict__ wrow = wbuf + (size_t)h * Et;
    const int voff = h * 64 + lane;
    float acc = 0.0f, den = 0.0f;
    int e = start;
    for (; e + 4 <= end; e += 4) {
        int s0 = srcS[e], s1 = srcS[e+1], s2 = srcS[e+2], s3 = srcS[e+3];
        float w0 = wrow[e], w1 = wrow[e+1], w2 = wrow[e+2], w3 = wrow[e+3];
        float v0 = b2f(hW16[(size_t)s0 * 256 + voff]);
        float v1 = b2f(hW16[(size_t)s1 * 256 + voff]);
        float v2 = b2f(hW16[(size_t)s2 * 256 + voff]);
        float v3 = b2f(hW16[(size_t)s3 * 256 + voff]);
        acc += w0 * v0; den += w0;
        acc += w1 * v1; den += w1;
        acc += w2 * v2; den += w2;
        acc += w3 * v3; den += w3;
    }
    for (; e < end; e++) {
        int s = srcS[e];
        float w = wrow[e];
        acc += w * b2f(hW16[(size_t)s * 256 + voff]);
        den += w;
    }
    float v = acc / (den + 1e-16f) + bias[voff];
    v = (v > 0.0f) ? v : expm1f(v);            // ELU
    out[(size_t)n * 256 + voff] = v;
}

// ------------- H=1 variant: 4 nodes/block, wave=node. No ELU. -------------
__global__ void gat_aggregate1(const int* __restrict__ offsets, const int* __restrict__ srcS,
                               const float* __restrict__ wbuf,
                               const unsigned short* __restrict__ hW16,
                               const float* __restrict__ bias,
                               float* __restrict__ out, int N) {
    const int n = blockIdx.x * 4 + (threadIdx.x >> 6);
    if (n >= N) return;
    const int lane = threadIdx.x & 63;
    const int start = offsets[n], end = offsets[n + 1];
    float acc = 0.0f, den = 0.0f;
    int e = start;
    for (; e + 4 <= end; e += 4) {
        int s0 = srcS[e], s1 = srcS[e+1], s2 = srcS[e+2], s3 = srcS[e+3];
        float w0 = wbuf[e], w1 = wbuf[e+1], w2 = wbuf[e+2], w3 = wbuf[e+3];
        float v0 = b2f(hW16[(size_t)s0 * 64 + lane]);
        float v1 = b2f(hW16[(size_t)s1 * 64 + lane]);
        float v2 = b2f(hW16[(size_t)s2 * 64 + lane]);
        float v3 = b2f(hW16[(size_t)s3 * 64 + lane]);
        acc += w0 * v0; den += w0;
        acc += w1 * v1; den += w1;
        acc += w2 * v2; den += w2;
        acc += w3 * v3; den += w3;
    }
    for (; e < end; e++) {
        int s = srcS[e];
        float w = wbuf[e];
        acc += w * b2f(hW16[(size_t)s * 64 + lane]);
        den += w;
    }
    out[(size_t)n * 64 + lane] = acc / (den + 1e-16f) + bias[lane];
}

// ------------- per-graph mean pool (batch is sorted) -------------
__global__ void pool_kernel(const float* __restrict__ h, const int* __restrict__ batch,
                            float* __restrict__ pooled, float* __restrict__ cnt,
                            int N, int nWaves) {
    const int w = blockIdx.x * 4 + (threadIdx.x >> 6);
    const int lane = threadIdx.x & 63;
    const int chunk = (N + nWaves - 1) / nWaves;
    int start = w * chunk;
    int end = min(N, start + chunk);
    if (start >= end) return;
    int curg = batch[start];
    int runStart = start;
    float acc = 0.0f;
    for (int n = start; n < end; n++) {
        int g = batch[n];
        if (g != curg) {
            atomicAdd(&pooled[curg * 64 + lane], acc);
            if (lane == 0) atomicAdd(&cnt[curg], (float)(n - runStart));
            acc = 0.0f; curg = g; runStart = n;
        }
        acc += h[(size_t)n * 64 + lane];
    }
    atomicAdd(&pooled[curg * 64 + lane], acc);
    if (lane == 0) atomicAdd(&cnt[curg], (float)(end - runStart));
}

// ------------- decoder head -------------
__global__ void final_kernel(const float* __restrict__ pooled, const float* __restrict__ cnt,
                             const float* __restrict__ gf, const float* __restrict__ Wg,
                             const float* __restrict__ bg, const float* __restrict__ Wd1,
                             const float* __restrict__ bd1, const float* __restrict__ gamma,
                             const float* __restrict__ beta, const float* __restrict__ Wd2,
                             const float* __restrict__ bd2, float* __restrict__ out, int G) {
    __shared__ float sp[16 * 64], sg[16 * 64], sz[16 * 64], slog[16 * 256];
    const int tid = threadIdx.x;
    for (int i = tid; i < G * 64; i += 256) {
        int g = i >> 6;
        sp[i] = pooled[i] / fmaxf(cnt[g], 1.0f);
    }
    for (int i = tid; i < G * 64; i += 256) {
        int g = i >> 6, c = i & 63;
        float v = bg[c];
        #pragma unroll
        for (int k = 0; k < 4; k++) v += gf[g * 4 + k] * Wg[k * 64 + c];
        sg[i] = fmaxf(v, 0.0f);
    }
    __syncthreads();
    for (int i = tid; i < G * 64; i += 256) {
        int g = i >> 6, c = i & 63;
        float v = bd1[c];
        for (int k = 0; k < 64; k++) v += sp[g * 64 + k] * Wd1[k * 64 + c];
        for (int k = 0; k < 64; k++) v += sg[g * 64 + k] * Wd1[(64 + k) * 64 + c];
        v = v * gamma[c] + beta[c];
        sz[i] = fmaxf(v, 0.0f);
    }
    __syncthreads();
    for (int i = tid; i < G * 256; i += 256) {
        int g = i >> 8, j = i & 255;
        float v = bd2[j];
        for (int k = 0; k < 64; k++) v += sz[g * 64 + k] * Wd2[k * 256 + j];
        slog[i] = v;
    }
    __syncthreads();
    const int wid = tid >> 6, lane = tid & 63;
    for (int g = wid; g < G; g += 4) {
        float v0 = slog[g * 256 + lane],       v1 = slog[g * 256 + 64 + lane],
              v2 = slog[g * 256 + 128 + lane], v3 = slog[g * 256 + 192 + lane];
        float m = fmaxf(fmaxf(v0, v1), fmaxf(v2, v3));
        #pragma unroll
        for (int off = 32; off > 0; off >>= 1) m = fmaxf(m, __shfl_xor(m, off));
        float e0 = expf(v0 - m), e1 = expf(v1 - m), e2 = expf(v2 - m), e3 = expf(v3 - m);
        float s = e0 + e1 + e2 + e3;
        #pragma unroll
        for (int off = 32; off > 0; off >>= 1) s += __shfl_xor(s, off);
        float inv = 1.0f / s;
        out[g * 256 + lane]        = e0 * inv;
        out[g * 256 + 64 + lane]   = e1 * inv;
        out[g * 256 + 128 + lane]  = e2 * inv;
        out[g * 256 + 192 + lane]  = e3 * inv;
    }
}

extern "C" void kernel_launch(void* const* d_in, const int* in_sizes, int n_in,
                              void* d_out, int out_size, void* d_ws, size_t ws_size,
                              hipStream_t stream) {
    const float* x     = (const float*)d_in[0];
    const int*   ei    = (const int*)  d_in[1];
    const int*   batch = (const int*)  d_in[2];
    const float* gf    = (const float*)d_in[3];
    const float* W_enc = (const float*)d_in[4];
    const float* b_enc = (const float*)d_in[5];
    const float* W1  = (const float*)d_in[6];
    const float* as1 = (const float*)d_in[7];
    const float* ad1 = (const float*)d_in[8];
    const float* b1  = (const float*)d_in[9];
    const float* W2  = (const float*)d_in[10];
    const float* as2 = (const float*)d_in[11];
    const float* ad2 = (const float*)d_in[12];
    const float* b2  = (const float*)d_in[13];
    const float* W3  = (const float*)d_in[14];
    const float* as3 = (const float*)d_in[15];
    const float* ad3 = (const float*)d_in[16];
    const float* b3  = (const float*)d_in[17];
    const float* Wg  = (const float*)d_in[18];
    const float* bg  = (const float*)d_in[19];
    const float* Wd1 = (const float*)d_in[20];
    const float* bd1 = (const float*)d_in[21];
    const float* gm  = (const float*)d_in[22];
    const float* bt  = (const float*)d_in[23];
    const float* Wd2 = (const float*)d_in[24];
    const float* bd2 = (const float*)d_in[25];

    const int N  = in_sizes[2];
    const int E  = in_sizes[1] / 2;
    const int G  = in_sizes[3] / 4;
    const int Et = E + N;

    float*          bufA   = (float*)d_ws;                       // [N,256] fp32
    unsigned short* hW16   = (unsigned short*)(bufA + (size_t)N * 256);  // [N,256] bf16
    float* a_s    = (float*)(hW16 + (size_t)N * 256);            // [N,4]
    float* a_d    = a_s  + (size_t)N * 4;                        // [N,4]
    float* wbuf   = a_d  + (size_t)N * 4;                        // [4,Et]
    float* pooled = wbuf + (size_t)4 * Et;                       // [G,64]
    float* cnt    = pooled + (size_t)G * 64;                     // [G]
    int*   offsets = (int*)(cnt + G);                            // [N+1]
    int*   srcS    = offsets + (N + 1);                          // [Et]
    int*   dstS    = srcS + Et;                                  // [Et]
    int*   counts  = dstS + Et;                                  // [N]
    int*   cursor  = counts + N;                                 // [N]
    int*   blockSums = cursor + N;                               // [cdiv(N,1024)]

    dim3 blk(256);
    auto cdiv = [](int a, int b) { return (a + b - 1) / b; };
    const int eBlocks = cdiv(Et, 256);
    const int rowBlocks = cdiv(N, 64);
    const int nScanBlocks = cdiv(N, 1024);

    // ---------------- CSR build (once, reused by all 3 convs) ----------------
    hipMemsetAsync(counts, 0, (size_t)N * sizeof(int), stream);
    edge_hist_kernel<<<eBlocks, blk, 0, stream>>>(ei, counts, E, Et);
    scan_blocks<<<nScanBlocks, 1024, 0, stream>>>(counts, blockSums, N);
    scan_sums<<<1, 64, 0, stream>>>(blockSums, nScanBlocks);
    scan_add<<<cdiv(N + 1, 256), blk, 0, stream>>>(counts, blockSums, offsets, cursor, N, Et);
    edge_sort_kernel<<<eBlocks, blk, 0, stream>>>(ei, cursor, srcS, dstS, E, Et);

    // encoder: bufA = x @ W_enc + b_enc   [N,64] fp32
    gemm64<0><<<dim3(rowBlocks, 1), blk, 0, stream>>>(x, W_enc, b_enc, bufA, nullptr,
                                                      nullptr, nullptr, nullptr, nullptr,
                                                      N, 32, 64, 1);

    // ---------------- conv1 (H=4, in=64) ----------------
    gemm64<1><<<dim3(rowBlocks, 4), blk, 0, stream>>>(bufA, W1, nullptr, nullptr, hW16,
                                                      as1, ad1, a_s, a_d, N, 64, 256, 4);
    edge_weights_kernel<4><<<dim3(eBlocks, 4), blk, 0, stream>>>(srcS, dstS, a_s, a_d, wbuf, Et);
    gat_aggregate4<<<N, blk, 0, stream>>>(offsets, srcS, wbuf, hW16, b1, bufA, N, Et);

    // ---------------- conv2 (H=4, in=256) ----------------
    gemm64<1><<<dim3(rowBlocks, 4), blk, 0, stream>>>(bufA, W2, nullptr, nullptr, hW16,
                                                      as2, ad2, a_s, a_d, N, 256, 256, 4);
    edge_weights_kernel<4><<<dim3(eBlocks, 4), blk, 0, stream>>>(srcS, dstS, a_s, a_d, wbuf, Et);
    gat_aggregate4<<<N, blk, 0, stream>>>(offsets, srcS, wbuf, hW16, b2, bufA, N, Et);

    // ---------------- conv3 (H=1, in=256, no concat) ----------------
    gemm64<1><<<dim3(rowBlocks, 1), blk, 0, stream>>>(bufA, W3, nullptr, nullptr, hW16,
                                                      as3, ad3, a_s, a_d, N, 256, 64, 1);
    edge_weights_kernel<1><<<dim3(eBlocks, 1), blk, 0, stream>>>(srcS, dstS, a_s, a_d, wbuf, Et);
    gat_aggregate1<<<cdiv(N, 4), blk, 0, stream>>>(offsets, srcS, wbuf, hW16, b3, bufA, N);

    // ---------------- mean pool + decoder head ----------------
    hipMemsetAsync(pooled, 0, (size_t)G * 64 * sizeof(float), stream);
    hipMemsetAsync(cnt, 0, (size_t)G * sizeof(float), stream);
    pool_kernel<<<512, blk, 0, stream>>>(bufA, batch, pooled, cnt, N, 512 * 4);
    final_kernel<<<1, blk, 0, stream>>>(pooled, cnt, gf, Wg, bg, Wd1, bd1, gm, bt, Wd2, bd2,
                                        (float*)d_out, G);
}

// Round 7
// 725.661 us; speedup vs baseline: 3.3117x; 1.0833x over previous
//
#include <hip/hip_runtime.h>
#include <math.h>

#define NEG_SLOPE 0.2f

typedef __attribute__((ext_vector_type(8))) short short8;   // 8 bf16 = 4 VGPRs
typedef __attribute__((ext_vector_type(4))) float f32x4;    // MFMA acc

__device__ inline float b2f(unsigned short u) {
    union { unsigned int i; float f; } x; x.i = ((unsigned int)u) << 16; return x.f;
}
__device__ inline unsigned short f2b(float f) {
    union { float f; unsigned int i; } u; u.f = f;
    unsigned int r = u.i + 0x7FFF + ((u.i >> 16) & 1);   // round-to-nearest-even
    return (unsigned short)(r >> 16);
}

// ---------------- encoder GEMM: fp32 compute, bf16 out + bias ----------------
// 64x64 tile, 256 threads, 4x4 micro-tile, k-sliced by 16.
__global__ __launch_bounds__(256) void gemm_enc(const float* __restrict__ A,
                                                const float* __restrict__ B,
                                                const float* __restrict__ bias,
                                                unsigned short* __restrict__ C16,
                                                int Nrows, int K, int M) {
    __shared__ float sA[16][64];
    __shared__ float sB[16][64];
    const int tx = threadIdx.x & 15;
    const int ty = threadIdx.x >> 4;
    const int row0 = blockIdx.x * 64;
    const int lr = threadIdx.x >> 2;
    const int lk = (threadIdx.x & 3) << 2;
    const int br = threadIdx.x >> 4;
    const int bc = (threadIdx.x & 15) << 2;

    const int aRow = row0 + lr;
    const bool aValid = aRow < Nrows;
    const float* Aptr = A + (size_t)aRow * K + lk;
    const float* Bptr = B + (size_t)br * M + bc;

    float acc[4][4] = {{0,0,0,0},{0,0,0,0},{0,0,0,0},{0,0,0,0}};
    float4 a = aValid ? *(const float4*)Aptr : float4{0,0,0,0};
    float4 b = *(const float4*)Bptr;

    for (int kt = 0; kt < K; kt += 16) {
        __syncthreads();
        sA[lk+0][lr] = a.x; sA[lk+1][lr] = a.y; sA[lk+2][lr] = a.z; sA[lk+3][lr] = a.w;
        *(float4*)&sB[br][bc] = b;
        __syncthreads();
        if (kt + 16 < K) {
            a = aValid ? *(const float4*)(Aptr + kt + 16) : float4{0,0,0,0};
            b = *(const float4*)(Bptr + (size_t)(kt + 16) * M);
        }
        #pragma unroll
        for (int k = 0; k < 16; k++) {
            const float4 av = *(const float4*)&sA[k][ty << 2];
            const float4 bv = *(const float4*)&sB[k][tx << 2];
            acc[0][0] += av.x*bv.x; acc[0][1] += av.x*bv.y; acc[0][2] += av.x*bv.z; acc[0][3] += av.x*bv.w;
            acc[1][0] += av.y*bv.x; acc[1][1] += av.y*bv.y; acc[1][2] += av.y*bv.z; acc[1][3] += av.y*bv.w;
            acc[2][0] += av.z*bv.x; acc[2][1] += av.z*bv.y; acc[2][2] += av.z*bv.z; acc[2][3] += av.z*bv.w;
            acc[3][0] += av.w*bv.x; acc[3][1] += av.w*bv.y; acc[3][2] += av.w*bv.z; acc[3][3] += av.w*bv.w;
        }
    }
    float4 bb = *(const float4*)&bias[tx << 2];
    #pragma unroll
    for (int i = 0; i < 4; i++) {
        int r = row0 + (ty << 2) + i;
        if (r < Nrows) {
            ushort4 o = {f2b(acc[i][0]+bb.x), f2b(acc[i][1]+bb.y), f2b(acc[i][2]+bb.z), f2b(acc[i][3]+bb.w)};
            *(ushort4*)&C16[(size_t)r * M + (tx << 2)] = o;
        }
    }
}

// ---------------- weight prep: Wt[m][k] = bf16(W[k][m]) ----------------
__global__ void wtrans_kernel(const float* __restrict__ W, unsigned short* __restrict__ Wt,
                              int K, int M) {
    int i = blockIdx.x * 256 + threadIdx.x;
    if (i >= K * M) return;
    int k = i / M, m = i - k * M;
    Wt[(size_t)m * K + k] = f2b(W[i]);
}

// ---------------- MFMA GEMM: C16[N,M] = A16[N,K] @ Wt16^T  (bf16 in, bf16 out) ----------------
// 64 rows x (CPW*64) cols per block, 4 waves; wave covers CPW 16-col tiles x 4 16-row tiles.
// LDS rows padded +8 bf16 to kill b128 bank conflicts.
template<int CPW>
__global__ __launch_bounds__(256) void gemm_mfma(const unsigned short* __restrict__ A16,
                                                 const unsigned short* __restrict__ Bt16,
                                                 unsigned short* __restrict__ C16,
                                                 int Nrows, int K, int M) {
    constexpr int BN = CPW * 64;
    __shared__ unsigned short sA[64][40];
    __shared__ unsigned short sB[BN][40];
    const int tid = threadIdx.x;
    const int wave = tid >> 6;
    const int lane = tid & 63;
    const int quad = lane >> 4;
    const int l16 = lane & 15;
    const int row0 = blockIdx.x * 64;
    const int col0 = blockIdx.y * BN;
    const int sr = tid >> 2;           // staging row 0..63
    const int sk = (tid & 3) << 3;     // staging k offset 0,8,16,24

    f32x4 acc[4][CPW];
    #pragma unroll
    for (int i = 0; i < 4; i++)
        #pragma unroll
        for (int j = 0; j < CPW; j++) acc[i][j] = (f32x4){0,0,0,0};

    for (int kt = 0; kt < K; kt += 32) {
        __syncthreads();
        {
            int r = row0 + sr;
            uint4 z = {0,0,0,0};
            *(uint4*)&sA[sr][sk] = (r < Nrows) ? *(const uint4*)&A16[(size_t)r * K + kt + sk] : z;
        }
        #pragma unroll
        for (int i = 0; i < CPW; i++) {
            int c = col0 + sr + i * 64;
            *(uint4*)&sB[sr + i * 64][sk] = *(const uint4*)&Bt16[(size_t)c * K + kt + sk];
        }
        __syncthreads();
        short8 bf[CPW];
        #pragma unroll
        for (int j = 0; j < CPW; j++)
            bf[j] = *(const short8*)&sB[wave * (CPW * 16) + j * 16 + l16][quad * 8];
        #pragma unroll
        for (int i = 0; i < 4; i++) {
            short8 af = *(const short8*)&sA[i * 16 + l16][quad * 8];
            #pragma unroll
            for (int j = 0; j < CPW; j++)
                acc[i][j] = __builtin_amdgcn_mfma_f32_16x16x32_bf16(af, bf[j], acc[i][j], 0, 0, 0);
        }
    }
    // epilogue: C/D layout col=lane&15, row=quad*4+reg
    #pragma unroll
    for (int i = 0; i < 4; i++) {
        #pragma unroll
        for (int j = 0; j < CPW; j++) {
            int col = col0 + wave * (CPW * 16) + j * 16 + l16;
            #pragma unroll
            for (int r = 0; r < 4; r++) {
                int row = row0 + i * 16 + quad * 4 + r;
                if (row < Nrows) C16[(size_t)row * M + col] = f2b(acc[i][j][r]);
            }
        }
    }
}

// ------------- per-node attention scores (bf16 h input) -------------
template<int H>
__global__ void att_scores16(const unsigned short* __restrict__ hW16,
                             const float* __restrict__ att_s, const float* __restrict__ att_d,
                             float* __restrict__ a_s, float* __restrict__ a_d, int N) {
    const int lane = threadIdx.x & 63;
    const int n = blockIdx.x * 4 + (threadIdx.x >> 6);
    if (n >= N) return;
    #pragma unroll
    for (int h = 0; h < H; h++) {
        float v = b2f(hW16[(size_t)n * (H * 64) + h * 64 + lane]);
        float s = v * att_s[h * 64 + lane];
        float d = v * att_d[h * 64 + lane];
        #pragma unroll
        for (int off = 32; off > 0; off >>= 1) {
            s += __shfl_xor(s, off);
            d += __shfl_xor(d, off);
        }
        if (lane == 0) { a_s[n * H + h] = s; a_d[n * H + h] = d; }
    }
}

// ------------- CSR build: histogram / 3-phase scan / scatter-sort -------------
__global__ void edge_hist_kernel(const int* __restrict__ ei, int* __restrict__ counts,
                                 int E, int Et) {
    int e = blockIdx.x * 256 + threadIdx.x;
    if (e >= Et) return;
    int d = (e < E) ? ei[E + e] : e - E;
    atomicAdd(&counts[d], 1);
}

__global__ __launch_bounds__(1024) void scan_blocks(int* __restrict__ counts,
                                                    int* __restrict__ blockSums, int N) {
    __shared__ int wsum[16];
    const int tid = threadIdx.x;
    const int lane = tid & 63;
    const int wave = tid >> 6;
    int i = blockIdx.x * 1024 + tid;
    int v = (i < N) ? counts[i] : 0;
    int s = v;
    #pragma unroll
    for (int off = 1; off < 64; off <<= 1) {
        int t = __shfl_up(s, off);
        if (lane >= off) s += t;
    }
    if (lane == 63) wsum[wave] = s;
    __syncthreads();
    if (wave == 0 && lane < 16) {
        int ws = wsum[lane];
        #pragma unroll
        for (int off = 1; off < 16; off <<= 1) {
            int t = __shfl_up(ws, off);
            if (lane >= off) ws += t;
        }
        wsum[lane] = ws;
    }
    __syncthreads();
    int waveOff = (wave > 0) ? wsum[wave - 1] : 0;
    int incl = s + waveOff;
    if (i < N) counts[i] = incl - v;
    if (tid == 1023) blockSums[blockIdx.x] = incl;
}

__global__ void scan_sums(int* __restrict__ bs, int nb) {
    const int lane = threadIdx.x;
    int carry = 0;
    for (int base = 0; base < nb; base += 64) {
        int i = base + lane;
        int v = (i < nb) ? bs[i] : 0;
        int s = v;
        #pragma unroll
        for (int off = 1; off < 64; off <<= 1) {
            int t = __shfl_up(s, off);
            if (lane >= off) s += t;
        }
        if (i < nb) bs[i] = carry + s - v;
        carry += __shfl(s, 63);
    }
}

__global__ void scan_add(const int* __restrict__ excl, const int* __restrict__ blockSums,
                         int* __restrict__ offsets, int* __restrict__ cursor, int N, int Et) {
    int i = blockIdx.x * 256 + threadIdx.x;
    if (i < N) {
        int o = excl[i] + blockSums[i >> 10];
        offsets[i] = o;
        cursor[i] = o;
    }
    if (i == N) offsets[N] = Et;
}

__global__ void edge_sort_kernel(const int* __restrict__ ei, int* __restrict__ cursor,
                                 int* __restrict__ srcS, int* __restrict__ dstS, int E, int Et) {
    int e = blockIdx.x * 256 + threadIdx.x;
    if (e >= Et) return;
    int s, d;
    if (e < E) { s = ei[e]; d = ei[E + e]; } else { s = d = e - E; }
    int pos = atomicAdd(&cursor[d], 1);
    srcS[pos] = s;
    dstS[pos] = d;
}

// ------------- per-(edge,head) softmax weights, CSR order, head-major -------------
template<int H>
__global__ void edge_weights_kernel(const int* __restrict__ srcS, const int* __restrict__ dstS,
                                    const float* __restrict__ a_s, const float* __restrict__ a_d,
                                    float* __restrict__ wbuf, int Et) {
    int e = blockIdx.x * 256 + threadIdx.x;
    if (e >= Et) return;
    int h = blockIdx.y;
    int s = srcS[e], d = dstS[e];
    float ev = a_s[s * H + h] + a_d[d * H + h];
    ev = (ev >= 0.0f) ? ev : NEG_SLOPE * ev;
    wbuf[(size_t)h * Et + e] = __expf(ev);
}

// ------------- fused gather-aggregate (H=4): block=node, wave=head, lane=channel -------------
// bf16 out (feeds next MFMA GEMM); + bias + ELU
__global__ void gat_aggregate4(const int* __restrict__ offsets, const int* __restrict__ srcS,
                               const float* __restrict__ wbuf,
                               const unsigned short* __restrict__ hW16,
                               const float* __restrict__ bias,
                               unsigned short* __restrict__ out16, int N, int Et) {
    const int n = blockIdx.x;
    if (n >= N) return;
    const int h = threadIdx.x >> 6;
    const int lane = threadIdx.x & 63;
    const int start = offsets[n], end = offsets[n + 1];
    const float* __restrict__ wrow = wbuf + (size_t)h * Et;
    const int voff = h * 64 + lane;
    float acc = 0.0f, den = 0.0f;
    int e = start;
    for (; e + 4 <= end; e += 4) {
        int s0 = srcS[e], s1 = srcS[e+1], s2 = srcS[e+2], s3 = srcS[e+3];
        float w0 = wrow[e], w1 = wrow[e+1], w2 = wrow[e+2], w3 = wrow[e+3];
        float v0 = b2f(hW16[(size_t)s0 * 256 + voff]);
        float v1 = b2f(hW16[(size_t)s1 * 256 + voff]);
        float v2 = b2f(hW16[(size_t)s2 * 256 + voff]);
        float v3 = b2f(hW16[(size_t)s3 * 256 + voff]);
        acc += w0 * v0; den += w0;
        acc += w1 * v1; den += w1;
        acc += w2 * v2; den += w2;
        acc += w3 * v3; den += w3;
    }
    for (; e < end; e++) {
        int s = srcS[e];
        float w = wrow[e];
        acc += w * b2f(hW16[(size_t)s * 256 + voff]);
        den += w;
    }
    float v = acc / (den + 1e-16f) + bias[voff];
    v = (v > 0.0f) ? v : expm1f(v);            // ELU
    out16[(size_t)n * 256 + voff] = f2b(v);
}

// ------------- H=1 variant: 4 nodes/block, wave=node; fp32 out (feeds pool) -------------
__global__ void gat_aggregate1(const int* __restrict__ offsets, const int* __restrict__ srcS,
                               const float* __restrict__ wbuf,
                               const unsigned short* __restrict__ hW16,
                               const float* __restrict__ bias,
                               float* __restrict__ out, int N) {
    const int n = blockIdx.x * 4 + (threadIdx.x >> 6);
    if (n >= N) return;
    const int lane = threadIdx.x & 63;
    const int start = offsets[n], end = offsets[n + 1];
    float acc = 0.0f, den = 0.0f;
    int e = start;
    for (; e + 4 <= end; e += 4) {
        int s0 = srcS[e], s1 = srcS[e+1], s2 = srcS[e+2], s3 = srcS[e+3];
        float w0 = wbuf[e], w1 = wbuf[e+1], w2 = wbuf[e+2], w3 = wbuf[e+3];
        float v0 = b2f(hW16[(size_t)s0 * 64 + lane]);
        float v1 = b2f(hW16[(size_t)s1 * 64 + lane]);
        float v2 = b2f(hW16[(size_t)s2 * 64 + lane]);
        float v3 = b2f(hW16[(size_t)s3 * 64 + lane]);
        acc += w0 * v0; den += w0;
        acc += w1 * v1; den += w1;
        acc += w2 * v2; den += w2;
        acc += w3 * v3; den += w3;
    }
    for (; e < end; e++) {
        int s = srcS[e];
        float w = wbuf[e];
        acc += w * b2f(hW16[(size_t)s * 64 + lane]);
        den += w;
    }
    out[(size_t)n * 64 + lane] = acc / (den + 1e-16f) + bias[lane];
}

// ------------- per-graph mean pool (batch is sorted) -------------
__global__ void pool_kernel(const float* __restrict__ h, const int* __restrict__ batch,
                            float* __restrict__ pooled, float* __restrict__ cnt,
                            int N, int nWaves) {
    const int w = blockIdx.x * 4 + (threadIdx.x >> 6);
    const int lane = threadIdx.x & 63;
    const int chunk = (N + nWaves - 1) / nWaves;
    int start = w * chunk;
    int end = min(N, start + chunk);
    if (start >= end) return;
    int curg = batch[start];
    int runStart = start;
    float acc = 0.0f;
    for (int n = start; n < end; n++) {
        int g = batch[n];
        if (g != curg) {
            atomicAdd(&pooled[curg * 64 + lane], acc);
            if (lane == 0) atomicAdd(&cnt[curg], (float)(n - runStart));
            acc = 0.0f; curg = g; runStart = n;
        }
        acc += h[(size_t)n * 64 + lane];
    }
    atomicAdd(&pooled[curg * 64 + lane], acc);
    if (lane == 0) atomicAdd(&cnt[curg], (float)(end - runStart));
}

// ------------- decoder head -------------
__global__ void final_kernel(const float* __restrict__ pooled, const float* __restrict__ cnt,
                             const float* __restrict__ gf, const float* __restrict__ Wg,
                             const float* __restrict__ bg, const float* __restrict__ Wd1,
                             const float* __restrict__ bd1, const float* __restrict__ gamma,
                             const float* __restrict__ beta, const float* __restrict__ Wd2,
                             const float* __restrict__ bd2, float* __restrict__ out, int G) {
    __shared__ float sp[16 * 64], sg[16 * 64], sz[16 * 64], slog[16 * 256];
    const int tid = threadIdx.x;
    for (int i = tid; i < G * 64; i += 256) {
        int g = i >> 6;
        sp[i] = pooled[i] / fmaxf(cnt[g], 1.0f);
    }
    for (int i = tid; i < G * 64; i += 256) {
        int g = i >> 6, c = i & 63;
        float v = bg[c];
        #pragma unroll
        for (int k = 0; k < 4; k++) v += gf[g * 4 + k] * Wg[k * 64 + c];
        sg[i] = fmaxf(v, 0.0f);
    }
    __syncthreads();
    for (int i = tid; i < G * 64; i += 256) {
        int g = i >> 6, c = i & 63;
        float v = bd1[c];
        for (int k = 0; k < 64; k++) v += sp[g * 64 + k] * Wd1[k * 64 + c];
        for (int k = 0; k < 64; k++) v += sg[g * 64 + k] * Wd1[(64 + k) * 64 + c];
        v = v * gamma[c] + beta[c];
        sz[i] = fmaxf(v, 0.0f);
    }
    __syncthreads();
    for (int i = tid; i < G * 256; i += 256) {
        int g = i >> 8, j = i & 255;
        float v = bd2[j];
        for (int k = 0; k < 64; k++) v += sz[g * 64 + k] * Wd2[k * 256 + j];
        slog[i] = v;
    }
    __syncthreads();
    const int wid = tid >> 6, lane = tid & 63;
    for (int g = wid; g < G; g += 4) {
        float v0 = slog[g * 256 + lane],       v1 = slog[g * 256 + 64 + lane],
              v2 = slog[g * 256 + 128 + lane], v3 = slog[g * 256 + 192 + lane];
        float m = fmaxf(fmaxf(v0, v1), fmaxf(v2, v3));
        #pragma unroll
        for (int off = 32; off > 0; off >>= 1) m = fmaxf(m, __shfl_xor(m, off));
        float e0 = expf(v0 - m), e1 = expf(v1 - m), e2 = expf(v2 - m), e3 = expf(v3 - m);
        float s = e0 + e1 + e2 + e3;
        #pragma unroll
        for (int off = 32; off > 0; off >>= 1) s += __shfl_xor(s, off);
        float inv = 1.0f / s;
        out[g * 256 + lane]        = e0 * inv;
        out[g * 256 + 64 + lane]   = e1 * inv;
        out[g * 256 + 128 + lane]  = e2 * inv;
        out[g * 256 + 192 + lane]  = e3 * inv;
    }
}

extern "C" void kernel_launch(void* const* d_in, const int* in_sizes, int n_in,
                              void* d_out, int out_size, void* d_ws, size_t ws_size,
                              hipStream_t stream) {
    const float* x     = (const float*)d_in[0];
    const int*   ei    = (const int*)  d_in[1];
    const int*   batch = (const int*)  d_in[2];
    const float* gf    = (const float*)d_in[3];
    const float* W_enc = (const float*)d_in[4];
    const float* b_enc = (const float*)d_in[5];
    const float* W1  = (const float*)d_in[6];
    const float* as1 = (const float*)d_in[7];
    const float* ad1 = (const float*)d_in[8];
    const float* b1  = (const float*)d_in[9];
    const float* W2  = (const float*)d_in[10];
    const float* as2 = (const float*)d_in[11];
    const float* ad2 = (const float*)d_in[12];
    const float* b2  = (const float*)d_in[13];
    const float* W3  = (const float*)d_in[14];
    const float* as3 = (const float*)d_in[15];
    const float* ad3 = (const float*)d_in[16];
    const float* b3  = (const float*)d_in[17];
    const float* Wg  = (const float*)d_in[18];
    const float* bg  = (const float*)d_in[19];
    const float* Wd1 = (const float*)d_in[20];
    const float* bd1 = (const float*)d_in[21];
    const float* gm  = (const float*)d_in[22];
    const float* bt  = (const float*)d_in[23];
    const float* Wd2 = (const float*)d_in[24];
    const float* bd2 = (const float*)d_in[25];

    const int N  = in_sizes[2];
    const int E  = in_sizes[1] / 2;
    const int G  = in_sizes[3] / 4;
    const int Et = E + N;

    unsigned short* h16a = (unsigned short*)d_ws;                // [N,256] bf16 (A/ping)
    unsigned short* h16b = h16a + (size_t)N * 256;               // [N,256] bf16 (B/pong)
    unsigned short* Wt1  = h16b + (size_t)N * 256;               // [256,64]
    unsigned short* Wt2  = Wt1 + 256 * 64;                       // [256,256]
    unsigned short* Wt3  = Wt2 + 256 * 256;                      // [64,256]
    float* h3     = (float*)(Wt3 + 64 * 256);                    // [N,64] fp32
    float* a_s    = h3 + (size_t)N * 64;                         // [N,4]
    float* a_d    = a_s + (size_t)N * 4;                         // [N,4]
    float* wbuf   = a_d + (size_t)N * 4;                         // [4,Et]
    float* pooled = wbuf + (size_t)4 * Et;                       // [G,64]
    float* cnt    = pooled + (size_t)G * 64;                     // [G]
    int*   offsets = (int*)(cnt + G);                            // [N+1]
    int*   srcS    = offsets + (N + 1);                          // [Et]
    int*   dstS    = srcS + Et;                                  // [Et]
    int*   counts  = dstS + Et;                                  // [N]
    int*   cursor  = counts + N;                                 // [N]
    int*   blockSums = cursor + N;                               // [cdiv(N,1024)]

    dim3 blk(256);
    auto cdiv = [](int a, int b) { return (a + b - 1) / b; };
    const int eBlocks = cdiv(Et, 256);
    const int rowBlocks = cdiv(N, 64);
    const int nScanBlocks = cdiv(N, 1024);

    // ---------------- CSR build + weight prep ----------------
    hipMemsetAsync(counts, 0, (size_t)N * sizeof(int), stream);
    edge_hist_kernel<<<eBlocks, blk, 0, stream>>>(ei, counts, E, Et);
    scan_blocks<<<nScanBlocks, 1024, 0, stream>>>(counts, blockSums, N);
    scan_sums<<<1, 64, 0, stream>>>(blockSums, nScanBlocks);
    scan_add<<<cdiv(N + 1, 256), blk, 0, stream>>>(counts, blockSums, offsets, cursor, N, Et);
    edge_sort_kernel<<<eBlocks, blk, 0, stream>>>(ei, cursor, srcS, dstS, E, Et);
    wtrans_kernel<<<cdiv(64 * 256, 256), blk, 0, stream>>>(W1, Wt1, 64, 256);
    wtrans_kernel<<<cdiv(256 * 256, 256), blk, 0, stream>>>(W2, Wt2, 256, 256);
    wtrans_kernel<<<cdiv(256 * 64, 256), blk, 0, stream>>>(W3, Wt3, 256, 64);

    // encoder: h16a[:, :64] = bf16(x @ W_enc + b_enc)
    gemm_enc<<<dim3(rowBlocks, 1), blk, 0, stream>>>(x, W_enc, b_enc, h16a, N, 32, 64);

    // ---------------- conv1 (H=4, in=64) ----------------
    gemm_mfma<2><<<dim3(rowBlocks, 2), blk, 0, stream>>>(h16a, Wt1, h16b, N, 64, 256);
    att_scores16<4><<<cdiv(N, 4), blk, 0, stream>>>(h16b, as1, ad1, a_s, a_d, N);
    edge_weights_kernel<4><<<dim3(eBlocks, 4), blk, 0, stream>>>(srcS, dstS, a_s, a_d, wbuf, Et);
    gat_aggregate4<<<N, blk, 0, stream>>>(offsets, srcS, wbuf, h16b, b1, h16a, N, Et);

    // ---------------- conv2 (H=4, in=256) ----------------
    gemm_mfma<2><<<dim3(rowBlocks, 2), blk, 0, stream>>>(h16a, Wt2, h16b, N, 256, 256);
    att_scores16<4><<<cdiv(N, 4), blk, 0, stream>>>(h16b, as2, ad2, a_s, a_d, N);
    edge_weights_kernel<4><<<dim3(eBlocks, 4), blk, 0, stream>>>(srcS, dstS, a_s, a_d, wbuf, Et);
    gat_aggregate4<<<N, blk, 0, stream>>>(offsets, srcS, wbuf, h16b, b2, h16a, N, Et);

    // ---------------- conv3 (H=1, in=256, no concat) ----------------
    gemm_mfma<1><<<dim3(rowBlocks, 1), blk, 0, stream>>>(h16a, Wt3, h16b, N, 256, 64);
    att_scores16<1><<<cdiv(N, 4), blk, 0, stream>>>(h16b, as3, ad3, a_s, a_d, N);
    edge_weights_kernel<1><<<dim3(eBlocks, 1), blk, 0, stream>>>(srcS, dstS, a_s, a_d, wbuf, Et);
    gat_aggregate1<<<cdiv(N, 4), blk, 0, stream>>>(offsets, srcS, wbuf, h16b, b3, h3, N);

    // ---------------- mean pool + decoder head ----------------
    hipMemsetAsync(pooled, 0, (size_t)G * 64 * sizeof(float), stream);
    hipMemsetAsync(cnt, 0, (size_t)G * sizeof(float), stream);
    pool_kernel<<<512, blk, 0, stream>>>(h3, batch, pooled, cnt, N, 512 * 4);
    final_kernel<<<1, blk, 0, stream>>>(pooled, cnt, gf, Wg, bg, Wd1, bd1, gm, bt, Wd2, bd2,
                                        (float*)d_out, G);
}

// Round 8
// 640.236 us; speedup vs baseline: 3.7536x; 1.1334x over previous
//
#include <hip/hip_runtime.h>
#include <math.h>

#define NEG_SLOPE 0.2f

typedef __attribute__((ext_vector_type(8))) short short8;   // 8 bf16 = 4 VGPRs
typedef __attribute__((ext_vector_type(4))) float f32x4;    // MFMA acc

__device__ inline float b2f(unsigned short u) {
    union { unsigned int i; float f; } x; x.i = ((unsigned int)u) << 16; return x.f;
}
__device__ inline unsigned short f2b(float f) {
    union { float f; unsigned int i; } u; u.f = f;
    unsigned int r = u.i + 0x7FFF + ((u.i >> 16) & 1);   // round-to-nearest-even
    return (unsigned short)(r >> 16);
}

// ---------------- encoder GEMM: fp32 compute, bf16 out + bias ----------------
__global__ __launch_bounds__(256) void gemm_enc(const float* __restrict__ A,
                                                const float* __restrict__ B,
                                                const float* __restrict__ bias,
                                                unsigned short* __restrict__ C16,
                                                int Nrows, int K, int M) {
    __shared__ float sA[16][64];
    __shared__ float sB[16][64];
    const int tx = threadIdx.x & 15;
    const int ty = threadIdx.x >> 4;
    const int row0 = blockIdx.x * 64;
    const int lr = threadIdx.x >> 2;
    const int lk = (threadIdx.x & 3) << 2;
    const int br = threadIdx.x >> 4;
    const int bc = (threadIdx.x & 15) << 2;

    const int aRow = row0 + lr;
    const bool aValid = aRow < Nrows;
    const float* Aptr = A + (size_t)aRow * K + lk;
    const float* Bptr = B + (size_t)br * M + bc;

    float acc[4][4] = {{0,0,0,0},{0,0,0,0},{0,0,0,0},{0,0,0,0}};
    float4 a = aValid ? *(const float4*)Aptr : float4{0,0,0,0};
    float4 b = *(const float4*)Bptr;

    for (int kt = 0; kt < K; kt += 16) {
        __syncthreads();
        sA[lk+0][lr] = a.x; sA[lk+1][lr] = a.y; sA[lk+2][lr] = a.z; sA[lk+3][lr] = a.w;
        *(float4*)&sB[br][bc] = b;
        __syncthreads();
        if (kt + 16 < K) {
            a = aValid ? *(const float4*)(Aptr + kt + 16) : float4{0,0,0,0};
            b = *(const float4*)(Bptr + (size_t)(kt + 16) * M);
        }
        #pragma unroll
        for (int k = 0; k < 16; k++) {
            const float4 av = *(const float4*)&sA[k][ty << 2];
            const float4 bv = *(const float4*)&sB[k][tx << 2];
            acc[0][0] += av.x*bv.x; acc[0][1] += av.x*bv.y; acc[0][2] += av.x*bv.z; acc[0][3] += av.x*bv.w;
            acc[1][0] += av.y*bv.x; acc[1][1] += av.y*bv.y; acc[1][2] += av.y*bv.z; acc[1][3] += av.y*bv.w;
            acc[2][0] += av.z*bv.x; acc[2][1] += av.z*bv.y; acc[2][2] += av.z*bv.z; acc[2][3] += av.z*bv.w;
            acc[3][0] += av.w*bv.x; acc[3][1] += av.w*bv.y; acc[3][2] += av.w*bv.z; acc[3][3] += av.w*bv.w;
        }
    }
    float4 bb = *(const float4*)&bias[tx << 2];
    #pragma unroll
    for (int i = 0; i < 4; i++) {
        int r = row0 + (ty << 2) + i;
        if (r < Nrows) {
            ushort4 o = {f2b(acc[i][0]+bb.x), f2b(acc[i][1]+bb.y), f2b(acc[i][2]+bb.z), f2b(acc[i][3]+bb.w)};
            *(ushort4*)&C16[(size_t)r * M + (tx << 2)] = o;
        }
    }
}

// ---------------- weight prep: Wt[m][k] = bf16(W[k][m]) ----------------
__global__ void wtrans_kernel(const float* __restrict__ W, unsigned short* __restrict__ Wt,
                              int K, int M) {
    int i = blockIdx.x * 256 + threadIdx.x;
    if (i >= K * M) return;
    int k = i / M, m = i - k * M;
    Wt[(size_t)m * K + k] = f2b(W[i]);
}

// ---------------- MFMA GEMM: C16[N,M] = A16[N,K] @ Wt16^T ----------------
template<int CPW>
__global__ __launch_bounds__(256) void gemm_mfma(const unsigned short* __restrict__ A16,
                                                 const unsigned short* __restrict__ Bt16,
                                                 unsigned short* __restrict__ C16,
                                                 int Nrows, int K, int M) {
    constexpr int BN = CPW * 64;
    __shared__ unsigned short sA[64][40];
    __shared__ unsigned short sB[BN][40];
    const int tid = threadIdx.x;
    const int wave = tid >> 6;
    const int lane = tid & 63;
    const int quad = lane >> 4;
    const int l16 = lane & 15;
    const int row0 = blockIdx.x * 64;
    const int col0 = blockIdx.y * BN;
    const int sr = tid >> 2;
    const int sk = (tid & 3) << 3;

    f32x4 acc[4][CPW];
    #pragma unroll
    for (int i = 0; i < 4; i++)
        #pragma unroll
        for (int j = 0; j < CPW; j++) acc[i][j] = (f32x4){0,0,0,0};

    for (int kt = 0; kt < K; kt += 32) {
        __syncthreads();
        {
            int r = row0 + sr;
            uint4 z = {0,0,0,0};
            *(uint4*)&sA[sr][sk] = (r < Nrows) ? *(const uint4*)&A16[(size_t)r * K + kt + sk] : z;
        }
        #pragma unroll
        for (int i = 0; i < CPW; i++) {
            int c = col0 + sr + i * 64;
            *(uint4*)&sB[sr + i * 64][sk] = *(const uint4*)&Bt16[(size_t)c * K + kt + sk];
        }
        __syncthreads();
        short8 bf[CPW];
        #pragma unroll
        for (int j = 0; j < CPW; j++)
            bf[j] = *(const short8*)&sB[wave * (CPW * 16) + j * 16 + l16][quad * 8];
        #pragma unroll
        for (int i = 0; i < 4; i++) {
            short8 af = *(const short8*)&sA[i * 16 + l16][quad * 8];
            #pragma unroll
            for (int j = 0; j < CPW; j++)
                acc[i][j] = __builtin_amdgcn_mfma_f32_16x16x32_bf16(af, bf[j], acc[i][j], 0, 0, 0);
        }
    }
    #pragma unroll
    for (int i = 0; i < 4; i++) {
        #pragma unroll
        for (int j = 0; j < CPW; j++) {
            int col = col0 + wave * (CPW * 16) + j * 16 + l16;
            #pragma unroll
            for (int r = 0; r < 4; r++) {
                int row = row0 + i * 16 + quad * 4 + r;
                if (row < Nrows) C16[(size_t)row * M + col] = f2b(acc[i][j][r]);
            }
        }
    }
}

// ------------- per-node attention scores (bf16 h input) -------------
template<int H>
__global__ void att_scores16(const unsigned short* __restrict__ hW16,
                             const float* __restrict__ att_s, const float* __restrict__ att_d,
                             float* __restrict__ a_s, float* __restrict__ a_d, int N) {
    const int lane = threadIdx.x & 63;
    const int n = blockIdx.x * 4 + (threadIdx.x >> 6);
    if (n >= N) return;
    #pragma unroll
    for (int h = 0; h < H; h++) {
        float v = b2f(hW16[(size_t)n * (H * 64) + h * 64 + lane]);
        float s = v * att_s[h * 64 + lane];
        float d = v * att_d[h * 64 + lane];
        #pragma unroll
        for (int off = 32; off > 0; off >>= 1) {
            s += __shfl_xor(s, off);
            d += __shfl_xor(d, off);
        }
        if (lane == 0) { a_s[n * H + h] = s; a_d[n * H + h] = d; }
    }
}

// ------------- CSR build -------------
__global__ void edge_hist_kernel(const int* __restrict__ ei, int* __restrict__ counts,
                                 int E, int Et) {
    int e = blockIdx.x * 256 + threadIdx.x;
    if (e >= Et) return;
    int d = (e < E) ? ei[E + e] : e - E;
    atomicAdd(&counts[d], 1);
}

__global__ __launch_bounds__(1024) void scan_blocks(int* __restrict__ counts,
                                                    int* __restrict__ blockSums, int N) {
    __shared__ int wsum[16];
    const int tid = threadIdx.x;
    const int lane = tid & 63;
    const int wave = tid >> 6;
    int i = blockIdx.x * 1024 + tid;
    int v = (i < N) ? counts[i] : 0;
    int s = v;
    #pragma unroll
    for (int off = 1; off < 64; off <<= 1) {
        int t = __shfl_up(s, off);
        if (lane >= off) s += t;
    }
    if (lane == 63) wsum[wave] = s;
    __syncthreads();
    if (wave == 0 && lane < 16) {
        int ws = wsum[lane];
        #pragma unroll
        for (int off = 1; off < 16; off <<= 1) {
            int t = __shfl_up(ws, off);
            if (lane >= off) ws += t;
        }
        wsum[lane] = ws;
    }
    __syncthreads();
    int waveOff = (wave > 0) ? wsum[wave - 1] : 0;
    int incl = s + waveOff;
    if (i < N) counts[i] = incl - v;
    if (tid == 1023) blockSums[blockIdx.x] = incl;
}

__global__ void scan_sums(int* __restrict__ bs, int nb) {
    const int lane = threadIdx.x;
    int carry = 0;
    for (int base = 0; base < nb; base += 64) {
        int i = base + lane;
        int v = (i < nb) ? bs[i] : 0;
        int s = v;
        #pragma unroll
        for (int off = 1; off < 64; off <<= 1) {
            int t = __shfl_up(s, off);
            if (lane >= off) s += t;
        }
        if (i < nb) bs[i] = carry + s - v;
        carry += __shfl(s, 63);
    }
}

__global__ void scan_add(const int* __restrict__ excl, const int* __restrict__ blockSums,
                         int* __restrict__ offsets, int* __restrict__ cursor, int N, int Et) {
    int i = blockIdx.x * 256 + threadIdx.x;
    if (i < N) {
        int o = excl[i] + blockSums[i >> 10];
        offsets[i] = o;
        cursor[i] = o;
    }
    if (i == N) offsets[N] = Et;
}

__global__ void edge_sort_kernel(const int* __restrict__ ei, int* __restrict__ cursor,
                                 int* __restrict__ srcS, int* __restrict__ dstS, int E, int Et) {
    int e = blockIdx.x * 256 + threadIdx.x;
    if (e >= Et) return;
    int s, d;
    if (e < E) { s = ei[e]; d = ei[E + e]; } else { s = d = e - E; }
    int pos = atomicAdd(&cursor[d], 1);
    srcS[pos] = s;
    dstS[pos] = d;
}

// ------------- per-(edge,head) softmax weights -------------
template<int H>
__global__ void edge_weights_kernel(const int* __restrict__ srcS, const int* __restrict__ dstS,
                                    const float* __restrict__ a_s, const float* __restrict__ a_d,
                                    float* __restrict__ wbuf, int Et) {
    int e = blockIdx.x * 256 + threadIdx.x;
    if (e >= Et) return;
    int h = blockIdx.y;
    int s = srcS[e], d = dstS[e];
    float ev = a_s[s * H + h] + a_d[d * H + h];
    ev = (ev >= 0.0f) ? ev : NEG_SLOPE * ev;
    wbuf[(size_t)h * Et + e] = __expf(ev);
}

// ------------- fused gather-aggregate (H=4) -------------
__global__ void gat_aggregate4(const int* __restrict__ offsets, const int* __restrict__ srcS,
                               const float* __restrict__ wbuf,
                               const unsigned short* __restrict__ hW16,
                               const float* __restrict__ bias,
                               unsigned short* __restrict__ out16, int N, int Et) {
    const int n = blockIdx.x;
    if (n >= N) return;
    const int h = threadIdx.x >> 6;
    const int lane = threadIdx.x & 63;
    const int start = offsets[n], end = offsets[n + 1];
    const float* __restrict__ wrow = wbuf + (size_t)h * Et;
    const int voff = h * 64 + lane;
    float acc = 0.0f, den = 0.0f;
    int e = start;
    for (; e + 4 <= end; e += 4) {
        int s0 = srcS[e], s1 = srcS[e+1], s2 = srcS[e+2], s3 = srcS[e+3];
        float w0 = wrow[e], w1 = wrow[e+1], w2 = wrow[e+2], w3 = wrow[e+3];
        float v0 = b2f(hW16[(size_t)s0 * 256 + voff]);
        float v1 = b2f(hW16[(size_t)s1 * 256 + voff]);
        float v2 = b2f(hW16[(size_t)s2 * 256 + voff]);
        float v3 = b2f(hW16[(size_t)s3 * 256 + voff]);
        acc += w0 * v0; den += w0;
        acc += w1 * v1; den += w1;
        acc += w2 * v2; den += w2;
        acc += w3 * v3; den += w3;
    }
    for (; e < end; e++) {
        int s = srcS[e];
        float w = wrow[e];
        acc += w * b2f(hW16[(size_t)s * 256 + voff]);
        den += w;
    }
    float v = acc / (den + 1e-16f) + bias[voff];
    v = (v > 0.0f) ? v : expm1f(v);            // ELU
    out16[(size_t)n * 256 + voff] = f2b(v);
}

// ------------- H=1 variant; fp32 out (feeds pool) -------------
__global__ void gat_aggregate1(const int* __restrict__ offsets, const int* __restrict__ srcS,
                               const float* __restrict__ wbuf,
                               const unsigned short* __restrict__ hW16,
                               const float* __restrict__ bias,
                               float* __restrict__ out, int N) {
    const int n = blockIdx.x * 4 + (threadIdx.x >> 6);
    if (n >= N) return;
    const int lane = threadIdx.x & 63;
    const int start = offsets[n], end = offsets[n + 1];
    float acc = 0.0f, den = 0.0f;
    int e = start;
    for (; e + 4 <= end; e += 4) {
        int s0 = srcS[e], s1 = srcS[e+1], s2 = srcS[e+2], s3 = srcS[e+3];
        float w0 = wbuf[e], w1 = wbuf[e+1], w2 = wbuf[e+2], w3 = wbuf[e+3];
        float v0 = b2f(hW16[(size_t)s0 * 64 + lane]);
        float v1 = b2f(hW16[(size_t)s1 * 64 + lane]);
        float v2 = b2f(hW16[(size_t)s2 * 64 + lane]);
        float v3 = b2f(hW16[(size_t)s3 * 64 + lane]);
        acc += w0 * v0; den += w0;
        acc += w1 * v1; den += w1;
        acc += w2 * v2; den += w2;
        acc += w3 * v3; den += w3;
    }
    for (; e < end; e++) {
        int s = srcS[e];
        float w = wbuf[e];
        acc += w * b2f(hW16[(size_t)s * 64 + lane]);
        den += w;
    }
    out[(size_t)n * 64 + lane] = acc / (den + 1e-16f) + bias[lane];
}

// ------------- per-graph mean pool (batch is sorted) -------------
__global__ void pool_kernel(const float* __restrict__ h, const int* __restrict__ batch,
                            float* __restrict__ pooled, float* __restrict__ cnt,
                            int N, int nWaves) {
    const int w = blockIdx.x * 4 + (threadIdx.x >> 6);
    const int lane = threadIdx.x & 63;
    const int chunk = (N + nWaves - 1) / nWaves;
    int start = w * chunk;
    int end = min(N, start + chunk);
    if (start >= end) return;
    int curg = batch[start];
    int runStart = start;
    float acc = 0.0f;
    for (int n = start; n < end; n++) {
        int g = batch[n];
        if (g != curg) {
            atomicAdd(&pooled[curg * 64 + lane], acc);
            if (lane == 0) atomicAdd(&cnt[curg], (float)(n - runStart));
            acc = 0.0f; curg = g; runStart = n;
        }
        acc += h[(size_t)n * 64 + lane];
    }
    atomicAdd(&pooled[curg * 64 + lane], acc);
    if (lane == 0) atomicAdd(&cnt[curg], (float)(end - runStart));
}

// ------------- decoder head: one block PER GRAPH, coalesced weight reads -------------
__global__ __launch_bounds__(256) void final_kernel(
        const float* __restrict__ pooled, const float* __restrict__ cnt,
        const float* __restrict__ gf, const float* __restrict__ Wg,
        const float* __restrict__ bg, const float* __restrict__ Wd1,
        const float* __restrict__ bd1, const float* __restrict__ gamma,
        const float* __restrict__ beta, const float* __restrict__ Wd2,
        const float* __restrict__ bd2, float* __restrict__ out, int G) {
    const int g = blockIdx.x;
    const int tid = threadIdx.x;
    const int lane = tid & 63;
    const int wave = tid >> 6;
    __shared__ float spg[128];     // [sp(64) | sg(64)]
    __shared__ float sz[64];
    __shared__ float wred[8];

    if (tid < 64) {
        spg[tid] = pooled[g * 64 + tid] / fmaxf(cnt[g], 1.0f);
    } else if (tid < 128) {
        int c = tid - 64;
        float v = bg[c];
        #pragma unroll
        for (int k = 0; k < 4; k++) v += gf[g * 4 + k] * Wg[k * 64 + c];
        spg[64 + c] = fmaxf(v, 0.0f);
    }
    __syncthreads();
    if (tid < 64) {
        float v = bd1[tid];
        #pragma unroll 8
        for (int k = 0; k < 128; k++) v += spg[k] * Wd1[k * 64 + tid];
        v = v * gamma[tid] + beta[tid];
        sz[tid] = fmaxf(v, 0.0f);
    }
    __syncthreads();
    float v = bd2[tid];
    #pragma unroll 8
    for (int k = 0; k < 64; k++) v += sz[k] * Wd2[k * 256 + tid];
    // block softmax over 256 logits
    float m = v;
    #pragma unroll
    for (int off = 32; off > 0; off >>= 1) m = fmaxf(m, __shfl_xor(m, off));
    if (lane == 0) wred[wave] = m;
    __syncthreads();
    float M = fmaxf(fmaxf(wred[0], wred[1]), fmaxf(wred[2], wred[3]));
    float e = expf(v - M);
    float s = e;
    #pragma unroll
    for (int off = 32; off > 0; off >>= 1) s += __shfl_xor(s, off);
    if (lane == 0) wred[4 + wave] = s;
    __syncthreads();
    float S = (wred[4] + wred[5]) + (wred[6] + wred[7]);
    out[g * 256 + tid] = e / S;
}

extern "C" void kernel_launch(void* const* d_in, const int* in_sizes, int n_in,
                              void* d_out, int out_size, void* d_ws, size_t ws_size,
                              hipStream_t stream) {
    const float* x     = (const float*)d_in[0];
    const int*   ei    = (const int*)  d_in[1];
    const int*   batch = (const int*)  d_in[2];
    const float* gf    = (const float*)d_in[3];
    const float* W_enc = (const float*)d_in[4];
    const float* b_enc = (const float*)d_in[5];
    const float* W1  = (const float*)d_in[6];
    const float* as1 = (const float*)d_in[7];
    const float* ad1 = (const float*)d_in[8];
    const float* b1  = (const float*)d_in[9];
    const float* W2  = (const float*)d_in[10];
    const float* as2 = (const float*)d_in[11];
    const float* ad2 = (const float*)d_in[12];
    const float* b2  = (const float*)d_in[13];
    const float* W3  = (const float*)d_in[14];
    const float* as3 = (const float*)d_in[15];
    const float* ad3 = (const float*)d_in[16];
    const float* b3  = (const float*)d_in[17];
    const float* Wg  = (const float*)d_in[18];
    const float* bg  = (const float*)d_in[19];
    const float* Wd1 = (const float*)d_in[20];
    const float* bd1 = (const float*)d_in[21];
    const float* gm  = (const float*)d_in[22];
    const float* bt  = (const float*)d_in[23];
    const float* Wd2 = (const float*)d_in[24];
    const float* bd2 = (const float*)d_in[25];

    const int N  = in_sizes[2];
    const int E  = in_sizes[1] / 2;
    const int G  = in_sizes[3] / 4;
    const int Et = E + N;

    unsigned short* h16a = (unsigned short*)d_ws;                // [N,256] bf16 (ping)
    unsigned short* h16b = h16a + (size_t)N * 256;               // [N,256] bf16 (pong)
    unsigned short* Wt1  = h16b + (size_t)N * 256;               // [256,64]
    unsigned short* Wt2  = Wt1 + 256 * 64;                       // [256,256]
    unsigned short* Wt3  = Wt2 + 256 * 256;                      // [64,256]
    float* h3     = (float*)(Wt3 + 64 * 256);                    // [N,64] fp32
    float* a_s    = h3 + (size_t)N * 64;                         // [N,4]
    float* a_d    = a_s + (size_t)N * 4;                         // [N,4]
    float* wbuf   = a_d + (size_t)N * 4;                         // [4,Et]
    float* pooled = wbuf + (size_t)4 * Et;                       // [G,64]
    float* cnt    = pooled + (size_t)G * 64;                     // [G]
    int*   offsets = (int*)(cnt + G);                            // [N+1]
    int*   srcS    = offsets + (N + 1);                          // [Et]
    int*   dstS    = srcS + Et;                                  // [Et]
    int*   counts  = dstS + Et;                                  // [N]
    int*   cursor  = counts + N;                                 // [N]
    int*   blockSums = cursor + N;                               // [cdiv(N,1024)]

    dim3 blk(256);
    auto cdiv = [](int a, int b) { return (a + b - 1) / b; };
    const int eBlocks = cdiv(Et, 256);
    const int rowBlocks = cdiv(N, 64);
    const int nScanBlocks = cdiv(N, 1024);

    // ---------------- CSR build + weight prep ----------------
    hipMemsetAsync(counts, 0, (size_t)N * sizeof(int), stream);
    edge_hist_kernel<<<eBlocks, blk, 0, stream>>>(ei, counts, E, Et);
    scan_blocks<<<nScanBlocks, 1024, 0, stream>>>(counts, blockSums, N);
    scan_sums<<<1, 64, 0, stream>>>(blockSums, nScanBlocks);
    scan_add<<<cdiv(N + 1, 256), blk, 0, stream>>>(counts, blockSums, offsets, cursor, N, Et);
    edge_sort_kernel<<<eBlocks, blk, 0, stream>>>(ei, cursor, srcS, dstS, E, Et);
    wtrans_kernel<<<cdiv(64 * 256, 256), blk, 0, stream>>>(W1, Wt1, 64, 256);
    wtrans_kernel<<<cdiv(256 * 256, 256), blk, 0, stream>>>(W2, Wt2, 256, 256);
    wtrans_kernel<<<cdiv(256 * 64, 256), blk, 0, stream>>>(W3, Wt3, 256, 64);

    // encoder
    gemm_enc<<<dim3(rowBlocks, 1), blk, 0, stream>>>(x, W_enc, b_enc, h16a, N, 32, 64);

    // ---------------- conv1 (H=4, in=64) ----------------
    gemm_mfma<2><<<dim3(rowBlocks, 2), blk, 0, stream>>>(h16a, Wt1, h16b, N, 64, 256);
    att_scores16<4><<<cdiv(N, 4), blk, 0, stream>>>(h16b, as1, ad1, a_s, a_d, N);
    edge_weights_kernel<4><<<dim3(eBlocks, 4), blk, 0, stream>>>(srcS, dstS, a_s, a_d, wbuf, Et);
    gat_aggregate4<<<N, blk, 0, stream>>>(offsets, srcS, wbuf, h16b, b1, h16a, N, Et);

    // ---------------- conv2 (H=4, in=256) ----------------
    gemm_mfma<2><<<dim3(rowBlocks, 2), blk, 0, stream>>>(h16a, Wt2, h16b, N, 256, 256);
    att_scores16<4><<<cdiv(N, 4), blk, 0, stream>>>(h16b, as2, ad2, a_s, a_d, N);
    edge_weights_kernel<4><<<dim3(eBlocks, 4), blk, 0, stream>>>(srcS, dstS, a_s, a_d, wbuf, Et);
    gat_aggregate4<<<N, blk, 0, stream>>>(offsets, srcS, wbuf, h16b, b2, h16a, N, Et);

    // ---------------- conv3 (H=1, in=256, no concat) ----------------
    gemm_mfma<1><<<dim3(rowBlocks, 1), blk, 0, stream>>>(h16a, Wt3, h16b, N, 256, 64);
    att_scores16<1><<<cdiv(N, 4), blk, 0, stream>>>(h16b, as3, ad3, a_s, a_d, N);
    edge_weights_kernel<1><<<dim3(eBlocks, 1), blk, 0, stream>>>(srcS, dstS, a_s, a_d, wbuf, Et);
    gat_aggregate1<<<cdiv(N, 4), blk, 0, stream>>>(offsets, srcS, wbuf, h16b, b3, h3, N);

    // ---------------- mean pool + decoder head ----------------
    hipMemsetAsync(pooled, 0, (size_t)G * 64 * sizeof(float), stream);
    hipMemsetAsync(cnt, 0, (size_t)G * sizeof(float), stream);
    pool_kernel<<<512, blk, 0, stream>>>(h3, batch, pooled, cnt, N, 512 * 4);
    final_kernel<<<G, blk, 0, stream>>>(pooled, cnt, gf, Wg, bg, Wd1, bd1, gm, bt, Wd2, bd2,
                                        (float*)d_out, G);
}

// Round 9
// 586.146 us; speedup vs baseline: 4.1000x; 1.0923x over previous
//
#include <hip/hip_runtime.h>
#include <math.h>

#define NEG_SLOPE 0.2f

typedef __attribute__((ext_vector_type(8))) short short8;   // 8 bf16 = 4 VGPRs
typedef __attribute__((ext_vector_type(4))) float f32x4;    // MFMA acc

__device__ inline float b2f(unsigned short u) {
    union { unsigned int i; float f; } x; x.i = ((unsigned int)u) << 16; return x.f;
}
__device__ inline float b2f_lo(unsigned int u) {
    union { unsigned int i; float f; } x; x.i = u << 16; return x.f;
}
__device__ inline float b2f_hi(unsigned int u) {
    union { unsigned int i; float f; } x; x.i = u & 0xFFFF0000u; return x.f;
}
__device__ inline unsigned short f2b(float f) {
    union { float f; unsigned int i; } u; u.f = f;
    unsigned int r = u.i + 0x7FFF + ((u.i >> 16) & 1);   // round-to-nearest-even
    return (unsigned short)(r >> 16);
}

// ---------------- encoder GEMM: fp32 compute, bf16 out + bias ----------------
__global__ __launch_bounds__(256) void gemm_enc(const float* __restrict__ A,
                                                const float* __restrict__ B,
                                                const float* __restrict__ bias,
                                                unsigned short* __restrict__ C16,
                                                int Nrows, int K, int M) {
    __shared__ float sA[16][64];
    __shared__ float sB[16][64];
    const int tx = threadIdx.x & 15;
    const int ty = threadIdx.x >> 4;
    const int row0 = blockIdx.x * 64;
    const int lr = threadIdx.x >> 2;
    const int lk = (threadIdx.x & 3) << 2;
    const int br = threadIdx.x >> 4;
    const int bc = (threadIdx.x & 15) << 2;

    const int aRow = row0 + lr;
    const bool aValid = aRow < Nrows;
    const float* Aptr = A + (size_t)aRow * K + lk;
    const float* Bptr = B + (size_t)br * M + bc;

    float acc[4][4] = {{0,0,0,0},{0,0,0,0},{0,0,0,0},{0,0,0,0}};
    float4 a = aValid ? *(const float4*)Aptr : float4{0,0,0,0};
    float4 b = *(const float4*)Bptr;

    for (int kt = 0; kt < K; kt += 16) {
        __syncthreads();
        sA[lk+0][lr] = a.x; sA[lk+1][lr] = a.y; sA[lk+2][lr] = a.z; sA[lk+3][lr] = a.w;
        *(float4*)&sB[br][bc] = b;
        __syncthreads();
        if (kt + 16 < K) {
            a = aValid ? *(const float4*)(Aptr + kt + 16) : float4{0,0,0,0};
            b = *(const float4*)(Bptr + (size_t)(kt + 16) * M);
        }
        #pragma unroll
        for (int k = 0; k < 16; k++) {
            const float4 av = *(const float4*)&sA[k][ty << 2];
            const float4 bv = *(const float4*)&sB[k][tx << 2];
            acc[0][0] += av.x*bv.x; acc[0][1] += av.x*bv.y; acc[0][2] += av.x*bv.z; acc[0][3] += av.x*bv.w;
            acc[1][0] += av.y*bv.x; acc[1][1] += av.y*bv.y; acc[1][2] += av.y*bv.z; acc[1][3] += av.y*bv.w;
            acc[2][0] += av.z*bv.x; acc[2][1] += av.z*bv.y; acc[2][2] += av.z*bv.z; acc[2][3] += av.z*bv.w;
            acc[3][0] += av.w*bv.x; acc[3][1] += av.w*bv.y; acc[3][2] += av.w*bv.z; acc[3][3] += av.w*bv.w;
        }
    }
    float4 bb = *(const float4*)&bias[tx << 2];
    #pragma unroll
    for (int i = 0; i < 4; i++) {
        int r = row0 + (ty << 2) + i;
        if (r < Nrows) {
            ushort4 o = {f2b(acc[i][0]+bb.x), f2b(acc[i][1]+bb.y), f2b(acc[i][2]+bb.z), f2b(acc[i][3]+bb.w)};
            *(ushort4*)&C16[(size_t)r * M + (tx << 2)] = o;
        }
    }
}

// ---------------- weight prep: Wt[m][k] = bf16(W[k][m]) ----------------
__global__ void wtrans_kernel(const float* __restrict__ W, unsigned short* __restrict__ Wt,
                              int K, int M) {
    int i = blockIdx.x * 256 + threadIdx.x;
    if (i >= K * M) return;
    int k = i / M, m = i - k * M;
    Wt[(size_t)m * K + k] = f2b(W[i]);
}

// ---------------- MFMA GEMM: C16[N,M] = A16[N,K] @ Wt16^T ----------------
template<int CPW>
__global__ __launch_bounds__(256) void gemm_mfma(const unsigned short* __restrict__ A16,
                                                 const unsigned short* __restrict__ Bt16,
                                                 unsigned short* __restrict__ C16,
                                                 int Nrows, int K, int M) {
    constexpr int BN = CPW * 64;
    __shared__ unsigned short sA[64][40];
    __shared__ unsigned short sB[BN][40];
    const int tid = threadIdx.x;
    const int wave = tid >> 6;
    const int lane = tid & 63;
    const int quad = lane >> 4;
    const int l16 = lane & 15;
    const int row0 = blockIdx.x * 64;
    const int col0 = blockIdx.y * BN;
    const int sr = tid >> 2;
    const int sk = (tid & 3) << 3;

    f32x4 acc[4][CPW];
    #pragma unroll
    for (int i = 0; i < 4; i++)
        #pragma unroll
        for (int j = 0; j < CPW; j++) acc[i][j] = (f32x4){0,0,0,0};

    for (int kt = 0; kt < K; kt += 32) {
        __syncthreads();
        {
            int r = row0 + sr;
            uint4 z = {0,0,0,0};
            *(uint4*)&sA[sr][sk] = (r < Nrows) ? *(const uint4*)&A16[(size_t)r * K + kt + sk] : z;
        }
        #pragma unroll
        for (int i = 0; i < CPW; i++) {
            int c = col0 + sr + i * 64;
            *(uint4*)&sB[sr + i * 64][sk] = *(const uint4*)&Bt16[(size_t)c * K + kt + sk];
        }
        __syncthreads();
        short8 bf[CPW];
        #pragma unroll
        for (int j = 0; j < CPW; j++)
            bf[j] = *(const short8*)&sB[wave * (CPW * 16) + j * 16 + l16][quad * 8];
        #pragma unroll
        for (int i = 0; i < 4; i++) {
            short8 af = *(const short8*)&sA[i * 16 + l16][quad * 8];
            #pragma unroll
            for (int j = 0; j < CPW; j++)
                acc[i][j] = __builtin_amdgcn_mfma_f32_16x16x32_bf16(af, bf[j], acc[i][j], 0, 0, 0);
        }
    }
    #pragma unroll
    for (int i = 0; i < 4; i++) {
        #pragma unroll
        for (int j = 0; j < CPW; j++) {
            int col = col0 + wave * (CPW * 16) + j * 16 + l16;
            #pragma unroll
            for (int r = 0; r < 4; r++) {
                int row = row0 + i * 16 + quad * 4 + r;
                if (row < Nrows) C16[(size_t)row * M + col] = f2b(acc[i][j][r]);
            }
        }
    }
}

// ------------- per-node attention scores (bf16 h input) -------------
template<int H>
__global__ void att_scores16(const unsigned short* __restrict__ hW16,
                             const float* __restrict__ att_s, const float* __restrict__ att_d,
                             float* __restrict__ a_s, float* __restrict__ a_d, int N) {
    const int lane = threadIdx.x & 63;
    const int n = blockIdx.x * 4 + (threadIdx.x >> 6);
    if (n >= N) return;
    #pragma unroll
    for (int h = 0; h < H; h++) {
        float v = b2f(hW16[(size_t)n * (H * 64) + h * 64 + lane]);
        float s = v * att_s[h * 64 + lane];
        float d = v * att_d[h * 64 + lane];
        #pragma unroll
        for (int off = 32; off > 0; off >>= 1) {
            s += __shfl_xor(s, off);
            d += __shfl_xor(d, off);
        }
        if (lane == 0) { a_s[n * H + h] = s; a_d[n * H + h] = d; }
    }
}

// ------------- CSR build -------------
__global__ void edge_hist_kernel(const int* __restrict__ ei, int* __restrict__ counts,
                                 int E, int Et) {
    int e = blockIdx.x * 256 + threadIdx.x;
    if (e >= Et) return;
    int d = (e < E) ? ei[E + e] : e - E;
    atomicAdd(&counts[d], 1);
}

__global__ __launch_bounds__(1024) void scan_blocks(int* __restrict__ counts,
                                                    int* __restrict__ blockSums, int N) {
    __shared__ int wsum[16];
    const int tid = threadIdx.x;
    const int lane = tid & 63;
    const int wave = tid >> 6;
    int i = blockIdx.x * 1024 + tid;
    int v = (i < N) ? counts[i] : 0;
    int s = v;
    #pragma unroll
    for (int off = 1; off < 64; off <<= 1) {
        int t = __shfl_up(s, off);
        if (lane >= off) s += t;
    }
    if (lane == 63) wsum[wave] = s;
    __syncthreads();
    if (wave == 0 && lane < 16) {
        int ws = wsum[lane];
        #pragma unroll
        for (int off = 1; off < 16; off <<= 1) {
            int t = __shfl_up(ws, off);
            if (lane >= off) ws += t;
        }
        wsum[lane] = ws;
    }
    __syncthreads();
    int waveOff = (wave > 0) ? wsum[wave - 1] : 0;
    int incl = s + waveOff;
    if (i < N) counts[i] = incl - v;
    if (tid == 1023) blockSums[blockIdx.x] = incl;
}

__global__ void scan_sums(int* __restrict__ bs, int nb) {
    const int lane = threadIdx.x;
    int carry = 0;
    for (int base = 0; base < nb; base += 64) {
        int i = base + lane;
        int v = (i < nb) ? bs[i] : 0;
        int s = v;
        #pragma unroll
        for (int off = 1; off < 64; off <<= 1) {
            int t = __shfl_up(s, off);
            if (lane >= off) s += t;
        }
        if (i < nb) bs[i] = carry + s - v;
        carry += __shfl(s, 63);
    }
}

__global__ void scan_add(const int* __restrict__ excl, const int* __restrict__ blockSums,
                         int* __restrict__ offsets, int* __restrict__ cursor, int N, int Et) {
    int i = blockIdx.x * 256 + threadIdx.x;
    if (i < N) {
        int o = excl[i] + blockSums[i >> 10];
        offsets[i] = o;
        cursor[i] = o;
    }
    if (i == N) offsets[N] = Et;
}

__global__ void edge_sort_kernel(const int* __restrict__ ei, int* __restrict__ cursor,
                                 int* __restrict__ srcS, int E, int Et) {
    int e = blockIdx.x * 256 + threadIdx.x;
    if (e >= Et) return;
    int s, d;
    if (e < E) { s = ei[e]; d = ei[E + e]; } else { s = d = e - E; }
    int pos = atomicAdd(&cursor[d], 1);
    srcS[pos] = s;
}

// ------------- fused gather-aggregate (H=4): ONE WAVE PER NODE -------------
// lane covers channels 4*lane..4*lane+3 (head = lane>>4); one uint2 (8B) load per edge.
// Weights computed in-wave from a_s (s_load via readfirstlane) — no edge_weights pass.
__global__ __launch_bounds__(256) void gat_fused4(
        const int* __restrict__ offsets, const int* __restrict__ srcS,
        const float4* __restrict__ a_s4, const float4* __restrict__ a_d4,
        const unsigned short* __restrict__ hW16, const float* __restrict__ bias,
        unsigned short* __restrict__ out16, int N) {
    const int n = blockIdx.x * 4 + (threadIdx.x >> 6);
    if (n >= N) return;
    const int lane = threadIdx.x & 63;
    const int quad = lane >> 4;
    const int start = offsets[n], end = offsets[n + 1];
    const float4 ad = a_d4[n];
    float4 acc = {0, 0, 0, 0};
    float den = 0.0f;

    auto doEdge = [&](int s) {
        const float4 as = a_s4[s];                       // SGPR addr -> s_load_dwordx4
        float e0 = as.x + ad.x; e0 = (e0 >= 0.0f) ? e0 : NEG_SLOPE * e0;
        float e1 = as.y + ad.y; e1 = (e1 >= 0.0f) ? e1 : NEG_SLOPE * e1;
        float e2 = as.z + ad.z; e2 = (e2 >= 0.0f) ? e2 : NEG_SLOPE * e2;
        float e3 = as.w + ad.w; e3 = (e3 >= 0.0f) ? e3 : NEG_SLOPE * e3;
        float w0 = __expf(e0), w1 = __expf(e1), w2 = __expf(e2), w3 = __expf(e3);
        float w = (quad < 2) ? ((quad == 0) ? w0 : w1) : ((quad == 2) ? w2 : w3);
        const uint2 hv = *(const uint2*)&hW16[(size_t)s * 256 + (lane << 2)];
        acc.x += w * b2f_lo(hv.x);
        acc.y += w * b2f_hi(hv.x);
        acc.z += w * b2f_lo(hv.y);
        acc.w += w * b2f_hi(hv.y);
        den += w;
    };

    int e = start;
    for (; e + 2 <= end; e += 2) {
        int s0 = __builtin_amdgcn_readfirstlane(srcS[e]);
        int s1 = __builtin_amdgcn_readfirstlane(srcS[e + 1]);
        doEdge(s0);
        doEdge(s1);
    }
    if (e < end) doEdge(__builtin_amdgcn_readfirstlane(srcS[e]));

    const float inv = 1.0f / (den + 1e-16f);
    const float4 bb = *(const float4*)&bias[lane << 2];
    float v0 = acc.x * inv + bb.x; v0 = (v0 > 0.0f) ? v0 : expm1f(v0);
    float v1 = acc.y * inv + bb.y; v1 = (v1 > 0.0f) ? v1 : expm1f(v1);
    float v2 = acc.z * inv + bb.z; v2 = (v2 > 0.0f) ? v2 : expm1f(v2);
    float v3 = acc.w * inv + bb.w; v3 = (v3 > 0.0f) ? v3 : expm1f(v3);
    uint2 o;
    o.x = (unsigned int)f2b(v0) | ((unsigned int)f2b(v1) << 16);
    o.y = (unsigned int)f2b(v2) | ((unsigned int)f2b(v3) << 16);
    *(uint2*)&out16[(size_t)n * 256 + (lane << 2)] = o;
}

// ------------- H=1 fused variant: wave per node, inline weights; fp32 out -------------
__global__ __launch_bounds__(256) void gat_fused1(
        const int* __restrict__ offsets, const int* __restrict__ srcS,
        const float* __restrict__ a_s, const float* __restrict__ a_d,
        const unsigned short* __restrict__ hW16, const float* __restrict__ bias,
        float* __restrict__ out, int N) {
    const int n = blockIdx.x * 4 + (threadIdx.x >> 6);
    if (n >= N) return;
    const int lane = threadIdx.x & 63;
    const int start = offsets[n], end = offsets[n + 1];
    const float ad = a_d[n];
    float acc = 0.0f, den = 0.0f;

    auto doEdge = [&](int s) {
        float ev = a_s[s] + ad;                         // SGPR addr -> s_load
        ev = (ev >= 0.0f) ? ev : NEG_SLOPE * ev;
        float w = __expf(ev);
        acc += w * b2f(hW16[(size_t)s * 64 + lane]);
        den += w;
    };

    int e = start;
    for (; e + 2 <= end; e += 2) {
        int s0 = __builtin_amdgcn_readfirstlane(srcS[e]);
        int s1 = __builtin_amdgcn_readfirstlane(srcS[e + 1]);
        doEdge(s0);
        doEdge(s1);
    }
    if (e < end) doEdge(__builtin_amdgcn_readfirstlane(srcS[e]));

    out[(size_t)n * 64 + lane] = acc / (den + 1e-16f) + bias[lane];
}

// ------------- per-graph mean pool (batch is sorted) -------------
__global__ void pool_kernel(const float* __restrict__ h, const int* __restrict__ batch,
                            float* __restrict__ pooled, float* __restrict__ cnt,
                            int N, int nWaves) {
    const int w = blockIdx.x * 4 + (threadIdx.x >> 6);
    const int lane = threadIdx.x & 63;
    const int chunk = (N + nWaves - 1) / nWaves;
    int start = w * chunk;
    int end = min(N, start + chunk);
    if (start >= end) return;
    int curg = batch[start];
    int runStart = start;
    float acc = 0.0f;
    for (int n = start; n < end; n++) {
        int g = batch[n];
        if (g != curg) {
            atomicAdd(&pooled[curg * 64 + lane], acc);
            if (lane == 0) atomicAdd(&cnt[curg], (float)(n - runStart));
            acc = 0.0f; curg = g; runStart = n;
        }
        acc += h[(size_t)n * 64 + lane];
    }
    atomicAdd(&pooled[curg * 64 + lane], acc);
    if (lane == 0) atomicAdd(&cnt[curg], (float)(end - runStart));
}

// ------------- decoder head: one block per graph -------------
__global__ __launch_bounds__(256) void final_kernel(
        const float* __restrict__ pooled, const float* __restrict__ cnt,
        const float* __restrict__ gf, const float* __restrict__ Wg,
        const float* __restrict__ bg, const float* __restrict__ Wd1,
        const float* __restrict__ bd1, const float* __restrict__ gamma,
        const float* __restrict__ beta, const float* __restrict__ Wd2,
        const float* __restrict__ bd2, float* __restrict__ out, int G) {
    const int g = blockIdx.x;
    const int tid = threadIdx.x;
    const int lane = tid & 63;
    const int wave = tid >> 6;
    __shared__ float spg[128];
    __shared__ float sz[64];
    __shared__ float wred[8];

    if (tid < 64) {
        spg[tid] = pooled[g * 64 + tid] / fmaxf(cnt[g], 1.0f);
    } else if (tid < 128) {
        int c = tid - 64;
        float v = bg[c];
        #pragma unroll
        for (int k = 0; k < 4; k++) v += gf[g * 4 + k] * Wg[k * 64 + c];
        spg[64 + c] = fmaxf(v, 0.0f);
    }
    __syncthreads();
    if (tid < 64) {
        float v = bd1[tid];
        #pragma unroll 8
        for (int k = 0; k < 128; k++) v += spg[k] * Wd1[k * 64 + tid];
        v = v * gamma[tid] + beta[tid];
        sz[tid] = fmaxf(v, 0.0f);
    }
    __syncthreads();
    float v = bd2[tid];
    #pragma unroll 8
    for (int k = 0; k < 64; k++) v += sz[k] * Wd2[k * 256 + tid];
    float m = v;
    #pragma unroll
    for (int off = 32; off > 0; off >>= 1) m = fmaxf(m, __shfl_xor(m, off));
    if (lane == 0) wred[wave] = m;
    __syncthreads();
    float M = fmaxf(fmaxf(wred[0], wred[1]), fmaxf(wred[2], wred[3]));
    float e = expf(v - M);
    float s = e;
    #pragma unroll
    for (int off = 32; off > 0; off >>= 1) s += __shfl_xor(s, off);
    if (lane == 0) wred[4 + wave] = s;
    __syncthreads();
    float S = (wred[4] + wred[5]) + (wred[6] + wred[7]);
    out[g * 256 + tid] = e / S;
}

extern "C" void kernel_launch(void* const* d_in, const int* in_sizes, int n_in,
                              void* d_out, int out_size, void* d_ws, size_t ws_size,
                              hipStream_t stream) {
    const float* x     = (const float*)d_in[0];
    const int*   ei    = (const int*)  d_in[1];
    const int*   batch = (const int*)  d_in[2];
    const float* gf    = (const float*)d_in[3];
    const float* W_enc = (const float*)d_in[4];
    const float* b_enc = (const float*)d_in[5];
    const float* W1  = (const float*)d_in[6];
    const float* as1 = (const float*)d_in[7];
    const float* ad1 = (const float*)d_in[8];
    const float* b1  = (const float*)d_in[9];
    const float* W2  = (const float*)d_in[10];
    const float* as2 = (const float*)d_in[11];
    const float* ad2 = (const float*)d_in[12];
    const float* b2  = (const float*)d_in[13];
    const float* W3  = (const float*)d_in[14];
    const float* as3 = (const float*)d_in[15];
    const float* ad3 = (const float*)d_in[16];
    const float* b3  = (const float*)d_in[17];
    const float* Wg  = (const float*)d_in[18];
    const float* bg  = (const float*)d_in[19];
    const float* Wd1 = (const float*)d_in[20];
    const float* bd1 = (const float*)d_in[21];
    const float* gm  = (const float*)d_in[22];
    const float* bt  = (const float*)d_in[23];
    const float* Wd2 = (const float*)d_in[24];
    const float* bd2 = (const float*)d_in[25];

    const int N  = in_sizes[2];
    const int E  = in_sizes[1] / 2;
    const int G  = in_sizes[3] / 4;
    const int Et = E + N;

    unsigned short* h16a = (unsigned short*)d_ws;                // [N,256] bf16 (ping)
    unsigned short* h16b = h16a + (size_t)N * 256;               // [N,256] bf16 (pong)
    unsigned short* Wt1  = h16b + (size_t)N * 256;               // [256,64]
    unsigned short* Wt2  = Wt1 + 256 * 64;                       // [256,256]
    unsigned short* Wt3  = Wt2 + 256 * 256;                      // [64,256]
    float* h3     = (float*)(Wt3 + 64 * 256);                    // [N,64] fp32
    float* a_s    = h3 + (size_t)N * 64;                         // [N,4]
    float* a_d    = a_s + (size_t)N * 4;                         // [N,4]
    float* pooled = a_d + (size_t)N * 4;                         // [G,64]
    float* cnt    = pooled + (size_t)G * 64;                     // [G]
    int*   offsets = (int*)(cnt + G);                            // [N+1]
    int*   srcS    = offsets + (N + 1);                          // [Et]
    int*   counts  = srcS + Et;                                  // [N]
    int*   cursor  = counts + N;                                 // [N]
    int*   blockSums = cursor + N;                               // [cdiv(N,1024)]

    dim3 blk(256);
    auto cdiv = [](int a, int b) { return (a + b - 1) / b; };
    const int eBlocks = cdiv(Et, 256);
    const int rowBlocks = cdiv(N, 64);
    const int nScanBlocks = cdiv(N, 1024);

    // ---------------- CSR build + weight prep ----------------
    hipMemsetAsync(counts, 0, (size_t)N * sizeof(int), stream);
    edge_hist_kernel<<<eBlocks, blk, 0, stream>>>(ei, counts, E, Et);
    scan_blocks<<<nScanBlocks, 1024, 0, stream>>>(counts, blockSums, N);
    scan_sums<<<1, 64, 0, stream>>>(blockSums, nScanBlocks);
    scan_add<<<cdiv(N + 1, 256), blk, 0, stream>>>(counts, blockSums, offsets, cursor, N, Et);
    edge_sort_kernel<<<eBlocks, blk, 0, stream>>>(ei, cursor, srcS, E, Et);
    wtrans_kernel<<<cdiv(64 * 256, 256), blk, 0, stream>>>(W1, Wt1, 64, 256);
    wtrans_kernel<<<cdiv(256 * 256, 256), blk, 0, stream>>>(W2, Wt2, 256, 256);
    wtrans_kernel<<<cdiv(256 * 64, 256), blk, 0, stream>>>(W3, Wt3, 256, 64);

    // encoder
    gemm_enc<<<dim3(rowBlocks, 1), blk, 0, stream>>>(x, W_enc, b_enc, h16a, N, 32, 64);

    // ---------------- conv1 (H=4, in=64) ----------------
    gemm_mfma<2><<<dim3(rowBlocks, 2), blk, 0, stream>>>(h16a, Wt1, h16b, N, 64, 256);
    att_scores16<4><<<cdiv(N, 4), blk, 0, stream>>>(h16b, as1, ad1, a_s, a_d, N);
    gat_fused4<<<cdiv(N, 4), blk, 0, stream>>>(offsets, srcS, (const float4*)a_s,
                                               (const float4*)a_d, h16b, b1, h16a, N);

    // ---------------- conv2 (H=4, in=256) ----------------
    gemm_mfma<2><<<dim3(rowBlocks, 2), blk, 0, stream>>>(h16a, Wt2, h16b, N, 256, 256);
    att_scores16<4><<<cdiv(N, 4), blk, 0, stream>>>(h16b, as2, ad2, a_s, a_d, N);
    gat_fused4<<<cdiv(N, 4), blk, 0, stream>>>(offsets, srcS, (const float4*)a_s,
                                               (const float4*)a_d, h16b, b2, h16a, N);

    // ---------------- conv3 (H=1, in=256, no concat) ----------------
    gemm_mfma<1><<<dim3(rowBlocks, 1), blk, 0, stream>>>(h16a, Wt3, h16b, N, 256, 64);
    att_scores16<1><<<cdiv(N, 4), blk, 0, stream>>>(h16b, as3, ad3, a_s, a_d, N);
    gat_fused1<<<cdiv(N, 4), blk, 0, stream>>>(offsets, srcS, a_s, a_d, h16b, b3, h3, N);

    // ---------------- mean pool + decoder head ----------------
    hipMemsetAsync(pooled, 0, (size_t)G * 64 * sizeof(float), stream);
    hipMemsetAsync(cnt, 0, (size_t)G * sizeof(float), stream);
    pool_kernel<<<512, blk, 0, stream>>>(h3, batch, pooled, cnt, N, 512 * 4);
    final_kernel<<<G, blk, 0, stream>>>(pooled, cnt, gf, Wg, bg, Wd1, bd1, gm, bt, Wd2, bd2,
                                        (float*)d_out, G);
}

// Round 10
// 582.491 us; speedup vs baseline: 4.1257x; 1.0063x over previous
//
#include <hip/hip_runtime.h>
#include <math.h>

#define NEG_SLOPE 0.2f
#define LOG2E 1.4426950408889634f

typedef __attribute__((ext_vector_type(8))) short short8;   // 8 bf16 = 4 VGPRs
typedef __attribute__((ext_vector_type(4))) float f32x4;    // MFMA acc

__device__ inline float b2f(unsigned short u) {
    union { unsigned int i; float f; } x; x.i = ((unsigned int)u) << 16; return x.f;
}
__device__ inline float b2f_lo(unsigned int u) {
    union { unsigned int i; float f; } x; x.i = u << 16; return x.f;
}
__device__ inline float b2f_hi(unsigned int u) {
    union { unsigned int i; float f; } x; x.i = u & 0xFFFF0000u; return x.f;
}
__device__ inline unsigned short f2b(float f) {
    union { float f; unsigned int i; } u; u.f = f;
    unsigned int r = u.i + 0x7FFF + ((u.i >> 16) & 1);   // round-to-nearest-even
    return (unsigned short)(r >> 16);
}

// ---------------- encoder GEMM: fp32 compute, bf16 out + bias ----------------
__global__ __launch_bounds__(256) void gemm_enc(const float* __restrict__ A,
                                                const float* __restrict__ B,
                                                const float* __restrict__ bias,
                                                unsigned short* __restrict__ C16,
                                                int Nrows, int K, int M) {
    __shared__ float sA[16][64];
    __shared__ float sB[16][64];
    const int tx = threadIdx.x & 15;
    const int ty = threadIdx.x >> 4;
    const int row0 = blockIdx.x * 64;
    const int lr = threadIdx.x >> 2;
    const int lk = (threadIdx.x & 3) << 2;
    const int br = threadIdx.x >> 4;
    const int bc = (threadIdx.x & 15) << 2;

    const int aRow = row0 + lr;
    const bool aValid = aRow < Nrows;
    const float* Aptr = A + (size_t)aRow * K + lk;
    const float* Bptr = B + (size_t)br * M + bc;

    float acc[4][4] = {{0,0,0,0},{0,0,0,0},{0,0,0,0},{0,0,0,0}};
    float4 a = aValid ? *(const float4*)Aptr : float4{0,0,0,0};
    float4 b = *(const float4*)Bptr;

    for (int kt = 0; kt < K; kt += 16) {
        __syncthreads();
        sA[lk+0][lr] = a.x; sA[lk+1][lr] = a.y; sA[lk+2][lr] = a.z; sA[lk+3][lr] = a.w;
        *(float4*)&sB[br][bc] = b;
        __syncthreads();
        if (kt + 16 < K) {
            a = aValid ? *(const float4*)(Aptr + kt + 16) : float4{0,0,0,0};
            b = *(const float4*)(Bptr + (size_t)(kt + 16) * M);
        }
        #pragma unroll
        for (int k = 0; k < 16; k++) {
            const float4 av = *(const float4*)&sA[k][ty << 2];
            const float4 bv = *(const float4*)&sB[k][tx << 2];
            acc[0][0] += av.x*bv.x; acc[0][1] += av.x*bv.y; acc[0][2] += av.x*bv.z; acc[0][3] += av.x*bv.w;
            acc[1][0] += av.y*bv.x; acc[1][1] += av.y*bv.y; acc[1][2] += av.y*bv.z; acc[1][3] += av.y*bv.w;
            acc[2][0] += av.z*bv.x; acc[2][1] += av.z*bv.y; acc[2][2] += av.z*bv.z; acc[2][3] += av.z*bv.w;
            acc[3][0] += av.w*bv.x; acc[3][1] += av.w*bv.y; acc[3][2] += av.w*bv.z; acc[3][3] += av.w*bv.w;
        }
    }
    float4 bb = *(const float4*)&bias[tx << 2];
    #pragma unroll
    for (int i = 0; i < 4; i++) {
        int r = row0 + (ty << 2) + i;
        if (r < Nrows) {
            ushort4 o = {f2b(acc[i][0]+bb.x), f2b(acc[i][1]+bb.y), f2b(acc[i][2]+bb.z), f2b(acc[i][3]+bb.w)};
            *(ushort4*)&C16[(size_t)r * M + (tx << 2)] = o;
        }
    }
}

// ---------------- weight prep: Wt[m][k] = bf16(W[k][m]) ----------------
__global__ void wtrans_kernel(const float* __restrict__ W, unsigned short* __restrict__ Wt,
                              int K, int M) {
    int i = blockIdx.x * 256 + threadIdx.x;
    if (i >= K * M) return;
    int k = i / M, m = i - k * M;
    Wt[(size_t)m * K + k] = f2b(W[i]);
}

// ---------------- MFMA GEMM: C16[N,M] = A16[N,K] @ Wt16^T ----------------
template<int CPW>
__global__ __launch_bounds__(256) void gemm_mfma(const unsigned short* __restrict__ A16,
                                                 const unsigned short* __restrict__ Bt16,
                                                 unsigned short* __restrict__ C16,
                                                 int Nrows, int K, int M) {
    constexpr int BN = CPW * 64;
    __shared__ unsigned short sA[64][40];
    __shared__ unsigned short sB[BN][40];
    const int tid = threadIdx.x;
    const int wave = tid >> 6;
    const int lane = tid & 63;
    const int quad = lane >> 4;
    const int l16 = lane & 15;
    const int row0 = blockIdx.x * 64;
    const int col0 = blockIdx.y * BN;
    const int sr = tid >> 2;
    const int sk = (tid & 3) << 3;

    f32x4 acc[4][CPW];
    #pragma unroll
    for (int i = 0; i < 4; i++)
        #pragma unroll
        for (int j = 0; j < CPW; j++) acc[i][j] = (f32x4){0,0,0,0};

    for (int kt = 0; kt < K; kt += 32) {
        __syncthreads();
        {
            int r = row0 + sr;
            uint4 z = {0,0,0,0};
            *(uint4*)&sA[sr][sk] = (r < Nrows) ? *(const uint4*)&A16[(size_t)r * K + kt + sk] : z;
        }
        #pragma unroll
        for (int i = 0; i < CPW; i++) {
            int c = col0 + sr + i * 64;
            *(uint4*)&sB[sr + i * 64][sk] = *(const uint4*)&Bt16[(size_t)c * K + kt + sk];
        }
        __syncthreads();
        short8 bf[CPW];
        #pragma unroll
        for (int j = 0; j < CPW; j++)
            bf[j] = *(const short8*)&sB[wave * (CPW * 16) + j * 16 + l16][quad * 8];
        #pragma unroll
        for (int i = 0; i < 4; i++) {
            short8 af = *(const short8*)&sA[i * 16 + l16][quad * 8];
            #pragma unroll
            for (int j = 0; j < CPW; j++)
                acc[i][j] = __builtin_amdgcn_mfma_f32_16x16x32_bf16(af, bf[j], acc[i][j], 0, 0, 0);
        }
    }
    #pragma unroll
    for (int i = 0; i < 4; i++) {
        #pragma unroll
        for (int j = 0; j < CPW; j++) {
            int col = col0 + wave * (CPW * 16) + j * 16 + l16;
            #pragma unroll
            for (int r = 0; r < 4; r++) {
                int row = row0 + i * 16 + quad * 4 + r;
                if (row < Nrows) C16[(size_t)row * M + col] = f2b(acc[i][j][r]);
            }
        }
    }
}

// ------------- per-node attention scores (bf16 h input); scores pre-scaled by log2(e) -------------
template<int H>
__global__ void att_scores16(const unsigned short* __restrict__ hW16,
                             const float* __restrict__ att_s, const float* __restrict__ att_d,
                             float* __restrict__ a_s, float* __restrict__ a_d, int N) {
    const int lane = threadIdx.x & 63;
    const int n = blockIdx.x * 4 + (threadIdx.x >> 6);
    if (n >= N) return;
    #pragma unroll
    for (int h = 0; h < H; h++) {
        float v = b2f(hW16[(size_t)n * (H * 64) + h * 64 + lane]);
        float s = v * att_s[h * 64 + lane];
        float d = v * att_d[h * 64 + lane];
        #pragma unroll
        for (int off = 32; off > 0; off >>= 1) {
            s += __shfl_xor(s, off);
            d += __shfl_xor(d, off);
        }
        if (lane == 0) { a_s[n * H + h] = s * LOG2E; a_d[n * H + h] = d * LOG2E; }
    }
}

// ------------- CSR build -------------
__global__ void edge_hist_kernel(const int* __restrict__ ei, int* __restrict__ counts,
                                 int E, int Et) {
    int e = blockIdx.x * 256 + threadIdx.x;
    if (e >= Et) return;
    int d = (e < E) ? ei[E + e] : e - E;
    atomicAdd(&counts[d], 1);
}

__global__ __launch_bounds__(1024) void scan_blocks(int* __restrict__ counts,
                                                    int* __restrict__ blockSums, int N) {
    __shared__ int wsum[16];
    const int tid = threadIdx.x;
    const int lane = tid & 63;
    const int wave = tid >> 6;
    int i = blockIdx.x * 1024 + tid;
    int v = (i < N) ? counts[i] : 0;
    int s = v;
    #pragma unroll
    for (int off = 1; off < 64; off <<= 1) {
        int t = __shfl_up(s, off);
        if (lane >= off) s += t;
    }
    if (lane == 63) wsum[wave] = s;
    __syncthreads();
    if (wave == 0 && lane < 16) {
        int ws = wsum[lane];
        #pragma unroll
        for (int off = 1; off < 16; off <<= 1) {
            int t = __shfl_up(ws, off);
            if (lane >= off) ws += t;
        }
        wsum[lane] = ws;
    }
    __syncthreads();
    int waveOff = (wave > 0) ? wsum[wave - 1] : 0;
    int incl = s + waveOff;
    if (i < N) counts[i] = incl - v;
    if (tid == 1023) blockSums[blockIdx.x] = incl;
}

__global__ void scan_sums(int* __restrict__ bs, int nb) {
    const int lane = threadIdx.x;
    int carry = 0;
    for (int base = 0; base < nb; base += 64) {
        int i = base + lane;
        int v = (i < nb) ? bs[i] : 0;
        int s = v;
        #pragma unroll
        for (int off = 1; off < 64; off <<= 1) {
            int t = __shfl_up(s, off);
            if (lane >= off) s += t;
        }
        if (i < nb) bs[i] = carry + s - v;
        carry += __shfl(s, 63);
    }
}

__global__ void scan_add(const int* __restrict__ excl, const int* __restrict__ blockSums,
                         int* __restrict__ offsets, int* __restrict__ cursor, int N, int Et) {
    int i = blockIdx.x * 256 + threadIdx.x;
    if (i < N) {
        int o = excl[i] + blockSums[i >> 10];
        offsets[i] = o;
        cursor[i] = o;
    }
    if (i == N) offsets[N] = Et;
}

__global__ void edge_sort_kernel(const int* __restrict__ ei, int* __restrict__ cursor,
                                 int* __restrict__ srcS, int E, int Et) {
    int e = blockIdx.x * 256 + threadIdx.x;
    if (e >= Et) return;
    int s, d;
    if (e < E) { s = ei[e]; d = ei[E + e]; } else { s = d = e - E; }
    int pos = atomicAdd(&cursor[d], 1);
    srcS[pos] = s;
}

// ------------- fused gather-aggregate (H=4): wave per node, LDS-batched edge weights -------------
// Chunked by 64 edges: lane e computes the 4 exp2-weights of edge e (vectorized, amortized 64x),
// then the gather loop does ds_read broadcast + uint2 (8B) row load + 4 FMA per edge.
__global__ __launch_bounds__(256) void gat_fused4(
        const int* __restrict__ offsets, const int* __restrict__ srcS,
        const float4* __restrict__ a_s4, const float4* __restrict__ a_d4,
        const unsigned short* __restrict__ hW16, const float* __restrict__ bias,
        unsigned short* __restrict__ out16, int N) {
    __shared__ float wlds[4][64][4];
    const int wid = threadIdx.x >> 6;
    const int n = blockIdx.x * 4 + wid;
    if (n >= N) return;
    const int lane = threadIdx.x & 63;
    const int quad = lane >> 4;
    const int start = offsets[n], end = offsets[n + 1];
    const float4 ad = a_d4[n];
    float4 acc = {0, 0, 0, 0};
    float den = 0.0f;

    for (int e0 = start; e0 < end; e0 += 64) {
        const int cnt = min(64, end - e0);
        int sB = 0;
        if (lane < cnt) {
            sB = srcS[e0 + lane];
            const float4 as = a_s4[sB];
            float x0 = as.x + ad.x; x0 = fmaxf(x0, NEG_SLOPE * x0);
            float x1 = as.y + ad.y; x1 = fmaxf(x1, NEG_SLOPE * x1);
            float x2 = as.z + ad.z; x2 = fmaxf(x2, NEG_SLOPE * x2);
            float x3 = as.w + ad.w; x3 = fmaxf(x3, NEG_SLOPE * x3);
            wlds[wid][lane][0] = exp2f(x0);
            wlds[wid][lane][1] = exp2f(x1);
            wlds[wid][lane][2] = exp2f(x2);
            wlds[wid][lane][3] = exp2f(x3);
        }
        for (int j = 0; j < cnt; j++) {
            const int s = __builtin_amdgcn_readfirstlane(__shfl(sB, j));
            const float w = wlds[wid][j][quad];
            const uint2 hv = *(const uint2*)&hW16[(size_t)s * 256 + (lane << 2)];
            acc.x += w * b2f_lo(hv.x);
            acc.y += w * b2f_hi(hv.x);
            acc.z += w * b2f_lo(hv.y);
            acc.w += w * b2f_hi(hv.y);
            den += w;
        }
    }

    const float inv = 1.0f / (den + 1e-16f);
    const float4 bb = *(const float4*)&bias[lane << 2];
    float v0 = acc.x * inv + bb.x; v0 = (v0 > 0.0f) ? v0 : expm1f(v0);
    float v1 = acc.y * inv + bb.y; v1 = (v1 > 0.0f) ? v1 : expm1f(v1);
    float v2 = acc.z * inv + bb.z; v2 = (v2 > 0.0f) ? v2 : expm1f(v2);
    float v3 = acc.w * inv + bb.w; v3 = (v3 > 0.0f) ? v3 : expm1f(v3);
    uint2 o;
    o.x = (unsigned int)f2b(v0) | ((unsigned int)f2b(v1) << 16);
    o.y = (unsigned int)f2b(v2) | ((unsigned int)f2b(v3) << 16);
    *(uint2*)&out16[(size_t)n * 256 + (lane << 2)] = o;
}

// ------------- H=1 fused: wave per node, 2 edges/iter via half-waves; fp32 out -------------
__global__ __launch_bounds__(256) void gat_fused1(
        const int* __restrict__ offsets, const int* __restrict__ srcS,
        const float* __restrict__ a_s, const float* __restrict__ a_d,
        const unsigned short* __restrict__ hW16, const float* __restrict__ bias,
        float* __restrict__ out, int N) {
    const int n = blockIdx.x * 4 + (threadIdx.x >> 6);
    if (n >= N) return;
    const int lane = threadIdx.x & 63;
    const int half = lane >> 5;
    const int l32 = lane & 31;
    const int start = offsets[n], end = offsets[n + 1];
    const float ad = a_d[n];
    float accx = 0.0f, accy = 0.0f, den = 0.0f;

    for (int e = start + half; e < end; e += 2) {
        const int s = srcS[e];
        float ev = a_s[s] + ad;
        ev = fmaxf(ev, NEG_SLOPE * ev);
        const float w = exp2f(ev);
        const unsigned int hv = *(const unsigned int*)&hW16[(size_t)s * 64 + (l32 << 1)];
        accx += w * b2f_lo(hv);
        accy += w * b2f_hi(hv);
        den += w;
    }
    accx += __shfl_xor(accx, 32);
    accy += __shfl_xor(accy, 32);
    den  += __shfl_xor(den, 32);
    if (half == 0) {
        const float inv = 1.0f / (den + 1e-16f);
        float2 o = {accx * inv + bias[l32 * 2], accy * inv + bias[l32 * 2 + 1]};
        *(float2*)&out[(size_t)n * 64 + (l32 << 1)] = o;
    }
}

// ------------- per-graph mean pool (batch is sorted) -------------
__global__ void pool_kernel(const float* __restrict__ h, const int* __restrict__ batch,
                            float* __restrict__ pooled, float* __restrict__ cnt,
                            int N, int nWaves) {
    const int w = blockIdx.x * 4 + (threadIdx.x >> 6);
    const int lane = threadIdx.x & 63;
    const int chunk = (N + nWaves - 1) / nWaves;
    int start = w * chunk;
    int end = min(N, start + chunk);
    if (start >= end) return;
    int curg = batch[start];
    int runStart = start;
    float acc = 0.0f;
    for (int n = start; n < end; n++) {
        int g = batch[n];
        if (g != curg) {
            atomicAdd(&pooled[curg * 64 + lane], acc);
            if (lane == 0) atomicAdd(&cnt[curg], (float)(n - runStart));
            acc = 0.0f; curg = g; runStart = n;
        }
        acc += h[(size_t)n * 64 + lane];
    }
    atomicAdd(&pooled[curg * 64 + lane], acc);
    if (lane == 0) atomicAdd(&cnt[curg], (float)(end - runStart));
}

// ------------- decoder head: one block per graph -------------
__global__ __launch_bounds__(256) void final_kernel(
        const float* __restrict__ pooled, const float* __restrict__ cnt,
        const float* __restrict__ gf, const float* __restrict__ Wg,
        const float* __restrict__ bg, const float* __restrict__ Wd1,
        const float* __restrict__ bd1, const float* __restrict__ gamma,
        const float* __restrict__ beta, const float* __restrict__ Wd2,
        const float* __restrict__ bd2, float* __restrict__ out, int G) {
    const int g = blockIdx.x;
    const int tid = threadIdx.x;
    const int lane = tid & 63;
    const int wave = tid >> 6;
    __shared__ float spg[128];
    __shared__ float sz[64];
    __shared__ float wred[8];

    if (tid < 64) {
        spg[tid] = pooled[g * 64 + tid] / fmaxf(cnt[g], 1.0f);
    } else if (tid < 128) {
        int c = tid - 64;
        float v = bg[c];
        #pragma unroll
        for (int k = 0; k < 4; k++) v += gf[g * 4 + k] * Wg[k * 64 + c];
        spg[64 + c] = fmaxf(v, 0.0f);
    }
    __syncthreads();
    if (tid < 64) {
        float v = bd1[tid];
        #pragma unroll 8
        for (int k = 0; k < 128; k++) v += spg[k] * Wd1[k * 64 + tid];
        v = v * gamma[tid] + beta[tid];
        sz[tid] = fmaxf(v, 0.0f);
    }
    __syncthreads();
    float v = bd2[tid];
    #pragma unroll 8
    for (int k = 0; k < 64; k++) v += sz[k] * Wd2[k * 256 + tid];
    float m = v;
    #pragma unroll
    for (int off = 32; off > 0; off >>= 1) m = fmaxf(m, __shfl_xor(m, off));
    if (lane == 0) wred[wave] = m;
    __syncthreads();
    float M = fmaxf(fmaxf(wred[0], wred[1]), fmaxf(wred[2], wred[3]));
    float e = expf(v - M);
    float s = e;
    #pragma unroll
    for (int off = 32; off > 0; off >>= 1) s += __shfl_xor(s, off);
    if (lane == 0) wred[4 + wave] = s;
    __syncthreads();
    float S = (wred[4] + wred[5]) + (wred[6] + wred[7]);
    out[g * 256 + tid] = e / S;
}

extern "C" void kernel_launch(void* const* d_in, const int* in_sizes, int n_in,
                              void* d_out, int out_size, void* d_ws, size_t ws_size,
                              hipStream_t stream) {
    const float* x     = (const float*)d_in[0];
    const int*   ei    = (const int*)  d_in[1];
    const int*   batch = (const int*)  d_in[2];
    const float* gf    = (const float*)d_in[3];
    const float* W_enc = (const float*)d_in[4];
    const float* b_enc = (const float*)d_in[5];
    const float* W1  = (const float*)d_in[6];
    const float* as1 = (const float*)d_in[7];
    const float* ad1 = (const float*)d_in[8];
    const float* b1  = (const float*)d_in[9];
    const float* W2  = (const float*)d_in[10];
    const float* as2 = (const float*)d_in[11];
    const float* ad2 = (const float*)d_in[12];
    const float* b2  = (const float*)d_in[13];
    const float* W3  = (const float*)d_in[14];
    const float* as3 = (const float*)d_in[15];
    const float* ad3 = (const float*)d_in[16];
    const float* b3  = (const float*)d_in[17];
    const float* Wg  = (const float*)d_in[18];
    const float* bg  = (const float*)d_in[19];
    const float* Wd1 = (const float*)d_in[20];
    const float* bd1 = (const float*)d_in[21];
    const float* gm  = (const float*)d_in[22];
    const float* bt  = (const float*)d_in[23];
    const float* Wd2 = (const float*)d_in[24];
    const float* bd2 = (const float*)d_in[25];

    const int N  = in_sizes[2];
    const int E  = in_sizes[1] / 2;
    const int G  = in_sizes[3] / 4;
    const int Et = E + N;

    unsigned short* h16a = (unsigned short*)d_ws;                // [N,256] bf16 (ping)
    unsigned short* h16b = h16a + (size_t)N * 256;               // [N,256] bf16 (pong)
    unsigned short* Wt1  = h16b + (size_t)N * 256;               // [256,64]
    unsigned short* Wt2  = Wt1 + 256 * 64;                       // [256,256]
    unsigned short* Wt3  = Wt2 + 256 * 256;                      // [64,256]
    float* h3     = (float*)(Wt3 + 64 * 256);                    // [N,64] fp32
    float* a_s    = h3 + (size_t)N * 64;                         // [N,4]
    float* a_d    = a_s + (size_t)N * 4;                         // [N,4]
    float* pooled = a_d + (size_t)N * 4;                         // [G,64]
    float* cnt    = pooled + (size_t)G * 64;                     // [G]
    int*   offsets = (int*)(cnt + G);                            // [N+1]
    int*   srcS    = offsets + (N + 1);                          // [Et]
    int*   counts  = srcS + Et;                                  // [N]
    int*   cursor  = counts + N;                                 // [N]
    int*   blockSums = cursor + N;                               // [cdiv(N,1024)]

    dim3 blk(256);
    auto cdiv = [](int a, int b) { return (a + b - 1) / b; };
    const int eBlocks = cdiv(Et, 256);
    const int rowBlocks = cdiv(N, 64);
    const int nScanBlocks = cdiv(N, 1024);

    // ---------------- CSR build + weight prep ----------------
    hipMemsetAsync(counts, 0, (size_t)N * sizeof(int), stream);
    edge_hist_kernel<<<eBlocks, blk, 0, stream>>>(ei, counts, E, Et);
    scan_blocks<<<nScanBlocks, 1024, 0, stream>>>(counts, blockSums, N);
    scan_sums<<<1, 64, 0, stream>>>(blockSums, nScanBlocks);
    scan_add<<<cdiv(N + 1, 256), blk, 0, stream>>>(counts, blockSums, offsets, cursor, N, Et);
    edge_sort_kernel<<<eBlocks, blk, 0, stream>>>(ei, cursor, srcS, E, Et);
    wtrans_kernel<<<cdiv(64 * 256, 256), blk, 0, stream>>>(W1, Wt1, 64, 256);
    wtrans_kernel<<<cdiv(256 * 256, 256), blk, 0, stream>>>(W2, Wt2, 256, 256);
    wtrans_kernel<<<cdiv(256 * 64, 256), blk, 0, stream>>>(W3, Wt3, 256, 64);

    // encoder
    gemm_enc<<<dim3(rowBlocks, 1), blk, 0, stream>>>(x, W_enc, b_enc, h16a, N, 32, 64);

    // ---------------- conv1 (H=4, in=64) ----------------
    gemm_mfma<2><<<dim3(rowBlocks, 2), blk, 0, stream>>>(h16a, Wt1, h16b, N, 64, 256);
    att_scores16<4><<<cdiv(N, 4), blk, 0, stream>>>(h16b, as1, ad1, a_s, a_d, N);
    gat_fused4<<<cdiv(N, 4), blk, 0, stream>>>(offsets, srcS, (const float4*)a_s,
                                               (const float4*)a_d, h16b, b1, h16a, N);

    // ---------------- conv2 (H=4, in=256) ----------------
    gemm_mfma<2><<<dim3(rowBlocks, 2), blk, 0, stream>>>(h16a, Wt2, h16b, N, 256, 256);
    att_scores16<4><<<cdiv(N, 4), blk, 0, stream>>>(h16b, as2, ad2, a_s, a_d, N);
    gat_fused4<<<cdiv(N, 4), blk, 0, stream>>>(offsets, srcS, (const float4*)a_s,
                                               (const float4*)a_d, h16b, b2, h16a, N);

    // ---------------- conv3 (H=1, in=256, no concat) ----------------
    gemm_mfma<1><<<dim3(rowBlocks, 1), blk, 0, stream>>>(h16a, Wt3, h16b, N, 256, 64);
    att_scores16<1><<<cdiv(N, 4), blk, 0, stream>>>(h16b, as3, ad3, a_s, a_d, N);
    gat_fused1<<<cdiv(N, 4), blk, 0, stream>>>(offsets, srcS, a_s, a_d, h16b, b3, h3, N);

    // ---------------- mean pool + decoder head ----------------
    hipMemsetAsync(pooled, 0, (size_t)G * 64 * sizeof(float), stream);
    hipMemsetAsync(cnt, 0, (size_t)G * sizeof(float), stream);
    pool_kernel<<<512, blk, 0, stream>>>(h3, batch, pooled, cnt, N, 512 * 4);
    final_kernel<<<G, blk, 0, stream>>>(pooled, cnt, gf, Wg, bg, Wd1, bd1, gm, bt, Wd2, bd2,
                                        (float*)d_out, G);
}

// Round 11
// 501.635 us; speedup vs baseline: 4.7907x; 1.1612x over previous
//
#include <hip/hip_runtime.h>
#include <math.h>

#define NEG_SLOPE 0.2f
#define LOG2E 1.4426950408889634f

typedef __attribute__((ext_vector_type(8))) short short8;   // 8 bf16 = 4 VGPRs
typedef __attribute__((ext_vector_type(4))) float f32x4;    // MFMA acc

__device__ inline float b2f(unsigned short u) {
    union { unsigned int i; float f; } x; x.i = ((unsigned int)u) << 16; return x.f;
}
__device__ inline float b2f_lo(unsigned int u) {
    union { unsigned int i; float f; } x; x.i = u << 16; return x.f;
}
__device__ inline float b2f_hi(unsigned int u) {
    union { unsigned int i; float f; } x; x.i = u & 0xFFFF0000u; return x.f;
}
__device__ inline unsigned short f2b(float f) {
    union { float f; unsigned int i; } u; u.f = f;
    unsigned int r = u.i + 0x7FFF + ((u.i >> 16) & 1);   // round-to-nearest-even
    return (unsigned short)(r >> 16);
}

// ---------------- encoder GEMM: fp32 compute, bf16 out + bias ----------------
__global__ __launch_bounds__(256) void gemm_enc(const float* __restrict__ A,
                                                const float* __restrict__ B,
                                                const float* __restrict__ bias,
                                                unsigned short* __restrict__ C16,
                                                int Nrows, int K, int M) {
    __shared__ float sA[16][64];
    __shared__ float sB[16][64];
    const int tx = threadIdx.x & 15;
    const int ty = threadIdx.x >> 4;
    const int row0 = blockIdx.x * 64;
    const int lr = threadIdx.x >> 2;
    const int lk = (threadIdx.x & 3) << 2;
    const int br = threadIdx.x >> 4;
    const int bc = (threadIdx.x & 15) << 2;

    const int aRow = row0 + lr;
    const bool aValid = aRow < Nrows;
    const float* Aptr = A + (size_t)aRow * K + lk;
    const float* Bptr = B + (size_t)br * M + bc;

    float acc[4][4] = {{0,0,0,0},{0,0,0,0},{0,0,0,0},{0,0,0,0}};
    float4 a = aValid ? *(const float4*)Aptr : float4{0,0,0,0};
    float4 b = *(const float4*)Bptr;

    for (int kt = 0; kt < K; kt += 16) {
        __syncthreads();
        sA[lk+0][lr] = a.x; sA[lk+1][lr] = a.y; sA[lk+2][lr] = a.z; sA[lk+3][lr] = a.w;
        *(float4*)&sB[br][bc] = b;
        __syncthreads();
        if (kt + 16 < K) {
            a = aValid ? *(const float4*)(Aptr + kt + 16) : float4{0,0,0,0};
            b = *(const float4*)(Bptr + (size_t)(kt + 16) * M);
        }
        #pragma unroll
        for (int k = 0; k < 16; k++) {
            const float4 av = *(const float4*)&sA[k][ty << 2];
            const float4 bv = *(const float4*)&sB[k][tx << 2];
            acc[0][0] += av.x*bv.x; acc[0][1] += av.x*bv.y; acc[0][2] += av.x*bv.z; acc[0][3] += av.x*bv.w;
            acc[1][0] += av.y*bv.x; acc[1][1] += av.y*bv.y; acc[1][2] += av.y*bv.z; acc[1][3] += av.y*bv.w;
            acc[2][0] += av.z*bv.x; acc[2][1] += av.z*bv.y; acc[2][2] += av.z*bv.z; acc[2][3] += av.z*bv.w;
            acc[3][0] += av.w*bv.x; acc[3][1] += av.w*bv.y; acc[3][2] += av.w*bv.z; acc[3][3] += av.w*bv.w;
        }
    }
    float4 bb = *(const float4*)&bias[tx << 2];
    #pragma unroll
    for (int i = 0; i < 4; i++) {
        int r = row0 + (ty << 2) + i;
        if (r < Nrows) {
            ushort4 o = {f2b(acc[i][0]+bb.x), f2b(acc[i][1]+bb.y), f2b(acc[i][2]+bb.z), f2b(acc[i][3]+bb.w)};
            *(ushort4*)&C16[(size_t)r * M + (tx << 2)] = o;
        }
    }
}

// ---------------- weight prep: Wt[m][k] = bf16(W[k][m]) ----------------
__global__ void wtrans_kernel(const float* __restrict__ W, unsigned short* __restrict__ Wt,
                              int K, int M) {
    int i = blockIdx.x * 256 + threadIdx.x;
    if (i >= K * M) return;
    int k = i / M, m = i - k * M;
    Wt[(size_t)m * K + k] = f2b(W[i]);
}

// ---------------- MFMA GEMM: C16[N,M] = A16[N,K] @ Wt16^T ----------------
template<int CPW>
__global__ __launch_bounds__(256) void gemm_mfma(const unsigned short* __restrict__ A16,
                                                 const unsigned short* __restrict__ Bt16,
                                                 unsigned short* __restrict__ C16,
                                                 int Nrows, int K, int M) {
    constexpr int BN = CPW * 64;
    __shared__ unsigned short sA[64][40];
    __shared__ unsigned short sB[BN][40];
    const int tid = threadIdx.x;
    const int wave = tid >> 6;
    const int lane = tid & 63;
    const int quad = lane >> 4;
    const int l16 = lane & 15;
    const int row0 = blockIdx.x * 64;
    const int col0 = blockIdx.y * BN;
    const int sr = tid >> 2;
    const int sk = (tid & 3) << 3;

    f32x4 acc[4][CPW];
    #pragma unroll
    for (int i = 0; i < 4; i++)
        #pragma unroll
        for (int j = 0; j < CPW; j++) acc[i][j] = (f32x4){0,0,0,0};

    for (int kt = 0; kt < K; kt += 32) {
        __syncthreads();
        {
            int r = row0 + sr;
            uint4 z = {0,0,0,0};
            *(uint4*)&sA[sr][sk] = (r < Nrows) ? *(const uint4*)&A16[(size_t)r * K + kt + sk] : z;
        }
        #pragma unroll
        for (int i = 0; i < CPW; i++) {
            int c = col0 + sr + i * 64;
            *(uint4*)&sB[sr + i * 64][sk] = *(const uint4*)&Bt16[(size_t)c * K + kt + sk];
        }
        __syncthreads();
        short8 bf[CPW];
        #pragma unroll
        for (int j = 0; j < CPW; j++)
            bf[j] = *(const short8*)&sB[wave * (CPW * 16) + j * 16 + l16][quad * 8];
        #pragma unroll
        for (int i = 0; i < 4; i++) {
            short8 af = *(const short8*)&sA[i * 16 + l16][quad * 8];
            #pragma unroll
            for (int j = 0; j < CPW; j++)
                acc[i][j] = __builtin_amdgcn_mfma_f32_16x16x32_bf16(af, bf[j], acc[i][j], 0, 0, 0);
        }
    }
    #pragma unroll
    for (int i = 0; i < 4; i++) {
        #pragma unroll
        for (int j = 0; j < CPW; j++) {
            int col = col0 + wave * (CPW * 16) + j * 16 + l16;
            #pragma unroll
            for (int r = 0; r < 4; r++) {
                int row = row0 + i * 16 + quad * 4 + r;
                if (row < Nrows) C16[(size_t)row * M + col] = f2b(acc[i][j][r]);
            }
        }
    }
}

// ------------- attention scores H=4: wave per node, 1 uint2 load + quad reduction -------------
// lane = head*16 + ch/4; scores pre-scaled by log2(e).
__global__ void att_scores4(const unsigned short* __restrict__ hW16,
                            const float* __restrict__ att_s, const float* __restrict__ att_d,
                            float* __restrict__ a_s, float* __restrict__ a_d, int N) {
    const int lane = threadIdx.x & 63;
    const int n = blockIdx.x * 4 + (threadIdx.x >> 6);
    if (n >= N) return;
    const uint2 hv = *(const uint2*)&hW16[(size_t)n * 256 + (lane << 2)];
    const float4 sv = *(const float4*)&att_s[lane << 2];
    const float4 dv = *(const float4*)&att_d[lane << 2];
    const float v0 = b2f_lo(hv.x), v1 = b2f_hi(hv.x), v2 = b2f_lo(hv.y), v3 = b2f_hi(hv.y);
    float s = v0 * sv.x + v1 * sv.y + v2 * sv.z + v3 * sv.w;
    float d = v0 * dv.x + v1 * dv.y + v2 * dv.z + v3 * dv.w;
    #pragma unroll
    for (int off = 1; off < 16; off <<= 1) {
        s += __shfl_xor(s, off);
        d += __shfl_xor(d, off);
    }
    if ((lane & 15) == 0) {
        a_s[n * 4 + (lane >> 4)] = s * LOG2E;
        a_d[n * 4 + (lane >> 4)] = d * LOG2E;
    }
}

// ------------- attention scores H=1 (bf16 h input); pre-scaled by log2(e) -------------
__global__ void att_scores1(const unsigned short* __restrict__ hW16,
                            const float* __restrict__ att_s, const float* __restrict__ att_d,
                            float* __restrict__ a_s, float* __restrict__ a_d, int N) {
    const int lane = threadIdx.x & 63;
    const int n = blockIdx.x * 4 + (threadIdx.x >> 6);
    if (n >= N) return;
    float v = b2f(hW16[(size_t)n * 64 + lane]);
    float s = v * att_s[lane];
    float d = v * att_d[lane];
    #pragma unroll
    for (int off = 32; off > 0; off >>= 1) {
        s += __shfl_xor(s, off);
        d += __shfl_xor(d, off);
    }
    if (lane == 0) { a_s[n] = s * LOG2E; a_d[n] = d * LOG2E; }
}

// ------------- CSR build -------------
__global__ void edge_hist_kernel(const int* __restrict__ ei, int* __restrict__ counts,
                                 int E, int Et) {
    int e = blockIdx.x * 256 + threadIdx.x;
    if (e >= Et) return;
    int d = (e < E) ? ei[E + e] : e - E;
    atomicAdd(&counts[d], 1);
}

__global__ __launch_bounds__(1024) void scan_blocks(int* __restrict__ counts,
                                                    int* __restrict__ blockSums, int N) {
    __shared__ int wsum[16];
    const int tid = threadIdx.x;
    const int lane = tid & 63;
    const int wave = tid >> 6;
    int i = blockIdx.x * 1024 + tid;
    int v = (i < N) ? counts[i] : 0;
    int s = v;
    #pragma unroll
    for (int off = 1; off < 64; off <<= 1) {
        int t = __shfl_up(s, off);
        if (lane >= off) s += t;
    }
    if (lane == 63) wsum[wave] = s;
    __syncthreads();
    if (wave == 0 && lane < 16) {
        int ws = wsum[lane];
        #pragma unroll
        for (int off = 1; off < 16; off <<= 1) {
            int t = __shfl_up(ws, off);
            if (lane >= off) ws += t;
        }
        wsum[lane] = ws;
    }
    __syncthreads();
    int waveOff = (wave > 0) ? wsum[wave - 1] : 0;
    int incl = s + waveOff;
    if (i < N) counts[i] = incl - v;
    if (tid == 1023) blockSums[blockIdx.x] = incl;
}

__global__ void scan_sums(int* __restrict__ bs, int nb) {
    const int lane = threadIdx.x;
    int carry = 0;
    for (int base = 0; base < nb; base += 64) {
        int i = base + lane;
        int v = (i < nb) ? bs[i] : 0;
        int s = v;
        #pragma unroll
        for (int off = 1; off < 64; off <<= 1) {
            int t = __shfl_up(s, off);
            if (lane >= off) s += t;
        }
        if (i < nb) bs[i] = carry + s - v;
        carry += __shfl(s, 63);
    }
}

__global__ void scan_add(const int* __restrict__ excl, const int* __restrict__ blockSums,
                         int* __restrict__ offsets, int* __restrict__ cursor, int N, int Et) {
    int i = blockIdx.x * 256 + threadIdx.x;
    if (i < N) {
        int o = excl[i] + blockSums[i >> 10];
        offsets[i] = o;
        cursor[i] = o;
    }
    if (i == N) offsets[N] = Et;
}

__global__ void edge_sort_kernel(const int* __restrict__ ei, int* __restrict__ cursor,
                                 int* __restrict__ srcS, int E, int Et) {
    int e = blockIdx.x * 256 + threadIdx.x;
    if (e >= Et) return;
    int s, d;
    if (e < E) { s = ei[e]; d = ei[E + e]; } else { s = d = e - E; }
    int pos = atomicAdd(&cursor[d], 1);
    srcS[pos] = s;
}

// ------------- fused gather-aggregate (H=4): wave/node, LDS-batched weights+indices,
// gather loop unrolled x4 with 4 independent 512B row loads in flight -------------
__global__ __launch_bounds__(256) void gat_fused4(
        const int* __restrict__ offsets, const int* __restrict__ srcS,
        const float4* __restrict__ a_s4, const float4* __restrict__ a_d4,
        const unsigned short* __restrict__ hW16, const float* __restrict__ bias,
        unsigned short* __restrict__ out16, int N) {
    __shared__ float wlds[4][64][4];
    __shared__ int slds[4][64];
    const int wid = threadIdx.x >> 6;
    const int n = blockIdx.x * 4 + wid;
    if (n >= N) return;
    const int lane = threadIdx.x & 63;
    const int quad = lane >> 4;
    const int start = offsets[n], end = offsets[n + 1];
    const float4 ad = a_d4[n];
    float4 acc = {0, 0, 0, 0};
    float den = 0.0f;
    const int loff = lane << 2;

    for (int e0 = start; e0 < end; e0 += 64) {
        const int cnt = min(64, end - e0);
        if (lane < cnt) {
            int sB = srcS[e0 + lane];
            slds[wid][lane] = sB;
            const float4 as = a_s4[sB];
            float x0 = as.x + ad.x; x0 = fmaxf(x0, NEG_SLOPE * x0);
            float x1 = as.y + ad.y; x1 = fmaxf(x1, NEG_SLOPE * x1);
            float x2 = as.z + ad.z; x2 = fmaxf(x2, NEG_SLOPE * x2);
            float x3 = as.w + ad.w; x3 = fmaxf(x3, NEG_SLOPE * x3);
            wlds[wid][lane][0] = exp2f(x0);
            wlds[wid][lane][1] = exp2f(x1);
            wlds[wid][lane][2] = exp2f(x2);
            wlds[wid][lane][3] = exp2f(x3);
        }
        int j = 0;
        for (; j + 4 <= cnt; j += 4) {
            const int s0 = __builtin_amdgcn_readfirstlane(slds[wid][j + 0]);
            const int s1 = __builtin_amdgcn_readfirstlane(slds[wid][j + 1]);
            const int s2 = __builtin_amdgcn_readfirstlane(slds[wid][j + 2]);
            const int s3 = __builtin_amdgcn_readfirstlane(slds[wid][j + 3]);
            const float w0 = wlds[wid][j + 0][quad];
            const float w1 = wlds[wid][j + 1][quad];
            const float w2 = wlds[wid][j + 2][quad];
            const float w3 = wlds[wid][j + 3][quad];
            const uint2 h0 = *(const uint2*)&hW16[((size_t)s0 << 8) + loff];
            const uint2 h1 = *(const uint2*)&hW16[((size_t)s1 << 8) + loff];
            const uint2 h2 = *(const uint2*)&hW16[((size_t)s2 << 8) + loff];
            const uint2 h3 = *(const uint2*)&hW16[((size_t)s3 << 8) + loff];
            acc.x += w0 * b2f_lo(h0.x); acc.y += w0 * b2f_hi(h0.x);
            acc.z += w0 * b2f_lo(h0.y); acc.w += w0 * b2f_hi(h0.y);
            acc.x += w1 * b2f_lo(h1.x); acc.y += w1 * b2f_hi(h1.x);
            acc.z += w1 * b2f_lo(h1.y); acc.w += w1 * b2f_hi(h1.y);
            acc.x += w2 * b2f_lo(h2.x); acc.y += w2 * b2f_hi(h2.x);
            acc.z += w2 * b2f_lo(h2.y); acc.w += w2 * b2f_hi(h2.y);
            acc.x += w3 * b2f_lo(h3.x); acc.y += w3 * b2f_hi(h3.x);
            acc.z += w3 * b2f_lo(h3.y); acc.w += w3 * b2f_hi(h3.y);
            den += (w0 + w1) + (w2 + w3);
        }
        for (; j < cnt; j++) {
            const int s = __builtin_amdgcn_readfirstlane(slds[wid][j]);
            const float w = wlds[wid][j][quad];
            const uint2 hv = *(const uint2*)&hW16[((size_t)s << 8) + loff];
            acc.x += w * b2f_lo(hv.x); acc.y += w * b2f_hi(hv.x);
            acc.z += w * b2f_lo(hv.y); acc.w += w * b2f_hi(hv.y);
            den += w;
        }
    }

    const float inv = 1.0f / (den + 1e-16f);
    const float4 bb = *(const float4*)&bias[loff];
    float v0 = acc.x * inv + bb.x; v0 = (v0 > 0.0f) ? v0 : expm1f(v0);
    float v1 = acc.y * inv + bb.y; v1 = (v1 > 0.0f) ? v1 : expm1f(v1);
    float v2 = acc.z * inv + bb.z; v2 = (v2 > 0.0f) ? v2 : expm1f(v2);
    float v3 = acc.w * inv + bb.w; v3 = (v3 > 0.0f) ? v3 : expm1f(v3);
    uint2 o;
    o.x = (unsigned int)f2b(v0) | ((unsigned int)f2b(v1) << 16);
    o.y = (unsigned int)f2b(v2) | ((unsigned int)f2b(v3) << 16);
    *(uint2*)&out16[(size_t)n * 256 + loff] = o;
}

// ------------- H=1 fused: wave/node, LDS-batched weights, half-wave x4 unroll; fp32 out -------------
__global__ __launch_bounds__(256) void gat_fused1(
        const int* __restrict__ offsets, const int* __restrict__ srcS,
        const float* __restrict__ a_s, const float* __restrict__ a_d,
        const unsigned short* __restrict__ hW16, const float* __restrict__ bias,
        float* __restrict__ out, int N) {
    __shared__ float wlds[4][64];
    __shared__ int slds[4][64];
    const int wid = threadIdx.x >> 6;
    const int n = blockIdx.x * 4 + wid;
    if (n >= N) return;
    const int lane = threadIdx.x & 63;
    const int half = lane >> 5;
    const int l32 = lane & 31;
    const int start = offsets[n], end = offsets[n + 1];
    const float ad = a_d[n];
    float accx = 0.0f, accy = 0.0f, den = 0.0f;
    const int loff = l32 << 1;

    for (int e0 = start; e0 < end; e0 += 64) {
        const int cnt = min(64, end - e0);
        if (lane < cnt) {
            int sB = srcS[e0 + lane];
            slds[wid][lane] = sB;
            float ev = a_s[sB] + ad;
            ev = fmaxf(ev, NEG_SLOPE * ev);
            wlds[wid][lane] = exp2f(ev);
        }
        int j = half;
        for (; j + 8 <= cnt + half; j += 8) {
            const int s0 = slds[wid][j + 0];
            const int s1 = slds[wid][j + 2];
            const int s2 = slds[wid][j + 4];
            const int s3 = slds[wid][j + 6];
            const float w0 = wlds[wid][j + 0];
            const float w1 = wlds[wid][j + 2];
            const float w2 = wlds[wid][j + 4];
            const float w3 = wlds[wid][j + 6];
            const unsigned int h0 = *(const unsigned int*)&hW16[((size_t)s0 << 6) + loff];
            const unsigned int h1 = *(const unsigned int*)&hW16[((size_t)s1 << 6) + loff];
            const unsigned int h2 = *(const unsigned int*)&hW16[((size_t)s2 << 6) + loff];
            const unsigned int h3 = *(const unsigned int*)&hW16[((size_t)s3 << 6) + loff];
            accx += w0 * b2f_lo(h0); accy += w0 * b2f_hi(h0);
            accx += w1 * b2f_lo(h1); accy += w1 * b2f_hi(h1);
            accx += w2 * b2f_lo(h2); accy += w2 * b2f_hi(h2);
            accx += w3 * b2f_lo(h3); accy += w3 * b2f_hi(h3);
            den += (w0 + w1) + (w2 + w3);
        }
        for (; j < cnt; j += 2) {
            const int s = slds[wid][j];
            const float w = wlds[wid][j];
            const unsigned int hv = *(const unsigned int*)&hW16[((size_t)s << 6) + loff];
            accx += w * b2f_lo(hv);
            accy += w * b2f_hi(hv);
            den += w;
        }
    }
    accx += __shfl_xor(accx, 32);
    accy += __shfl_xor(accy, 32);
    den  += __shfl_xor(den, 32);
    if (half == 0) {
        const float inv = 1.0f / (den + 1e-16f);
        float2 o = {accx * inv + bias[loff], accy * inv + bias[loff + 1]};
        *(float2*)&out[(size_t)n * 64 + loff] = o;
    }
}

// ------------- per-graph mean pool (batch is sorted) -------------
__global__ void pool_kernel(const float* __restrict__ h, const int* __restrict__ batch,
                            float* __restrict__ pooled, float* __restrict__ cnt,
                            int N, int nWaves) {
    const int w = blockIdx.x * 4 + (threadIdx.x >> 6);
    const int lane = threadIdx.x & 63;
    const int chunk = (N + nWaves - 1) / nWaves;
    int start = w * chunk;
    int end = min(N, start + chunk);
    if (start >= end) return;
    int curg = batch[start];
    int runStart = start;
    float acc = 0.0f;
    for (int n = start; n < end; n++) {
        int g = batch[n];
        if (g != curg) {
            atomicAdd(&pooled[curg * 64 + lane], acc);
            if (lane == 0) atomicAdd(&cnt[curg], (float)(n - runStart));
            acc = 0.0f; curg = g; runStart = n;
        }
        acc += h[(size_t)n * 64 + lane];
    }
    atomicAdd(&pooled[curg * 64 + lane], acc);
    if (lane == 0) atomicAdd(&cnt[curg], (float)(end - runStart));
}

// ------------- decoder head: one block per graph -------------
__global__ __launch_bounds__(256) void final_kernel(
        const float* __restrict__ pooled, const float* __restrict__ cnt,
        const float* __restrict__ gf, const float* __restrict__ Wg,
        const float* __restrict__ bg, const float* __restrict__ Wd1,
        const float* __restrict__ bd1, const float* __restrict__ gamma,
        const float* __restrict__ beta, const float* __restrict__ Wd2,
        const float* __restrict__ bd2, float* __restrict__ out, int G) {
    const int g = blockIdx.x;
    const int tid = threadIdx.x;
    const int lane = tid & 63;
    const int wave = tid >> 6;
    __shared__ float spg[128];
    __shared__ float sz[64];
    __shared__ float wred[8];

    if (tid < 64) {
        spg[tid] = pooled[g * 64 + tid] / fmaxf(cnt[g], 1.0f);
    } else if (tid < 128) {
        int c = tid - 64;
        float v = bg[c];
        #pragma unroll
        for (int k = 0; k < 4; k++) v += gf[g * 4 + k] * Wg[k * 64 + c];
        spg[64 + c] = fmaxf(v, 0.0f);
    }
    __syncthreads();
    if (tid < 64) {
        float v = bd1[tid];
        #pragma unroll 8
        for (int k = 0; k < 128; k++) v += spg[k] * Wd1[k * 64 + tid];
        v = v * gamma[tid] + beta[tid];
        sz[tid] = fmaxf(v, 0.0f);
    }
    __syncthreads();
    float v = bd2[tid];
    #pragma unroll 8
    for (int k = 0; k < 64; k++) v += sz[k] * Wd2[k * 256 + tid];
    float m = v;
    #pragma unroll
    for (int off = 32; off > 0; off >>= 1) m = fmaxf(m, __shfl_xor(m, off));
    if (lane == 0) wred[wave] = m;
    __syncthreads();
    float M = fmaxf(fmaxf(wred[0], wred[1]), fmaxf(wred[2], wred[3]));
    float e = expf(v - M);
    float s = e;
    #pragma unroll
    for (int off = 32; off > 0; off >>= 1) s += __shfl_xor(s, off);
    if (lane == 0) wred[4 + wave] = s;
    __syncthreads();
    float S = (wred[4] + wred[5]) + (wred[6] + wred[7]);
    out[g * 256 + tid] = e / S;
}

extern "C" void kernel_launch(void* const* d_in, const int* in_sizes, int n_in,
                              void* d_out, int out_size, void* d_ws, size_t ws_size,
                              hipStream_t stream) {
    const float* x     = (const float*)d_in[0];
    const int*   ei    = (const int*)  d_in[1];
    const int*   batch = (const int*)  d_in[2];
    const float* gf    = (const float*)d_in[3];
    const float* W_enc = (const float*)d_in[4];
    const float* b_enc = (const float*)d_in[5];
    const float* W1  = (const float*)d_in[6];
    const float* as1 = (const float*)d_in[7];
    const float* ad1 = (const float*)d_in[8];
    const float* b1  = (const float*)d_in[9];
    const float* W2  = (const float*)d_in[10];
    const float* as2 = (const float*)d_in[11];
    const float* ad2 = (const float*)d_in[12];
    const float* b2  = (const float*)d_in[13];
    const float* W3  = (const float*)d_in[14];
    const float* as3 = (const float*)d_in[15];
    const float* ad3 = (const float*)d_in[16];
    const float* b3  = (const float*)d_in[17];
    const float* Wg  = (const float*)d_in[18];
    const float* bg  = (const float*)d_in[19];
    const float* Wd1 = (const float*)d_in[20];
    const float* bd1 = (const float*)d_in[21];
    const float* gm  = (const float*)d_in[22];
    const float* bt  = (const float*)d_in[23];
    const float* Wd2 = (const float*)d_in[24];
    const float* bd2 = (const float*)d_in[25];

    const int N  = in_sizes[2];
    const int E  = in_sizes[1] / 2;
    const int G  = in_sizes[3] / 4;
    const int Et = E + N;

    unsigned short* h16a = (unsigned short*)d_ws;                // [N,256] bf16 (ping)
    unsigned short* h16b = h16a + (size_t)N * 256;               // [N,256] bf16 (pong)
    unsigned short* Wt1  = h16b + (size_t)N * 256;               // [256,64]
    unsigned short* Wt2  = Wt1 + 256 * 64;                       // [256,256]
    unsigned short* Wt3  = Wt2 + 256 * 256;                      // [64,256]
    float* h3     = (float*)(Wt3 + 64 * 256);                    // [N,64] fp32
    float* a_s    = h3 + (size_t)N * 64;                         // [N,4]
    float* a_d    = a_s + (size_t)N * 4;                         // [N,4]
    float* pooled = a_d + (size_t)N * 4;                         // [G,64]
    float* cnt    = pooled + (size_t)G * 64;                     // [G]
    int*   offsets = (int*)(cnt + G);                            // [N+1]
    int*   srcS    = offsets + (N + 1);                          // [Et]
    int*   counts  = srcS + Et;                                  // [N]
    int*   cursor  = counts + N;                                 // [N]
    int*   blockSums = cursor + N;                               // [cdiv(N,1024)]

    dim3 blk(256);
    auto cdiv = [](int a, int b) { return (a + b - 1) / b; };
    const int eBlocks = cdiv(Et, 256);
    const int rowBlocks = cdiv(N, 64);
    const int nScanBlocks = cdiv(N, 1024);

    // ---------------- CSR build + weight prep ----------------
    hipMemsetAsync(counts, 0, (size_t)N * sizeof(int), stream);
    edge_hist_kernel<<<eBlocks, blk, 0, stream>>>(ei, counts, E, Et);
    scan_blocks<<<nScanBlocks, 1024, 0, stream>>>(counts, blockSums, N);
    scan_sums<<<1, 64, 0, stream>>>(blockSums, nScanBlocks);
    scan_add<<<cdiv(N + 1, 256), blk, 0, stream>>>(counts, blockSums, offsets, cursor, N, Et);
    edge_sort_kernel<<<eBlocks, blk, 0, stream>>>(ei, cursor, srcS, E, Et);
    wtrans_kernel<<<cdiv(64 * 256, 256), blk, 0, stream>>>(W1, Wt1, 64, 256);
    wtrans_kernel<<<cdiv(256 * 256, 256), blk, 0, stream>>>(W2, Wt2, 256, 256);
    wtrans_kernel<<<cdiv(256 * 64, 256), blk, 0, stream>>>(W3, Wt3, 256, 64);

    // encoder
    gemm_enc<<<dim3(rowBlocks, 1), blk, 0, stream>>>(x, W_enc, b_enc, h16a, N, 32, 64);

    // ---------------- conv1 (H=4, in=64) ----------------
    gemm_mfma<2><<<dim3(rowBlocks, 2), blk, 0, stream>>>(h16a, Wt1, h16b, N, 64, 256);
    att_scores4<<<cdiv(N, 4), blk, 0, stream>>>(h16b, as1, ad1, a_s, a_d, N);
    gat_fused4<<<cdiv(N, 4), blk, 0, stream>>>(offsets, srcS, (const float4*)a_s,
                                               (const float4*)a_d, h16b, b1, h16a, N);

    // ---------------- conv2 (H=4, in=256) ----------------
    gemm_mfma<2><<<dim3(rowBlocks, 2), blk, 0, stream>>>(h16a, Wt2, h16b, N, 256, 256);
    att_scores4<<<cdiv(N, 4), blk, 0, stream>>>(h16b, as2, ad2, a_s, a_d, N);
    gat_fused4<<<cdiv(N, 4), blk, 0, stream>>>(offsets, srcS, (const float4*)a_s,
                                               (const float4*)a_d, h16b, b2, h16a, N);

    // ---------------- conv3 (H=1, in=256, no concat) ----------------
    gemm_mfma<1><<<dim3(rowBlocks, 1), blk, 0, stream>>>(h16a, Wt3, h16b, N, 256, 64);
    att_scores1<<<cdiv(N, 4), blk, 0, stream>>>(h16b, as3, ad3, a_s, a_d, N);
    gat_fused1<<<cdiv(N, 4), blk, 0, stream>>>(offsets, srcS, a_s, a_d, h16b, b3, h3, N);

    // ---------------- mean pool + decoder head ----------------
    hipMemsetAsync(pooled, 0, (size_t)G * 64 * sizeof(float), stream);
    hipMemsetAsync(cnt, 0, (size_t)G * sizeof(float), stream);
    pool_kernel<<<512, blk, 0, stream>>>(h3, batch, pooled, cnt, N, 512 * 4);
    final_kernel<<<G, blk, 0, stream>>>(pooled, cnt, gf, Wg, bg, Wd1, bd1, gm, bt, Wd2, bd2,
                                        (float*)d_out, G);
}

// Round 12
// 481.777 us; speedup vs baseline: 4.9882x; 1.0412x over previous
//
#include <hip/hip_runtime.h>
#include <math.h>

#define NEG_SLOPE 0.2f
#define LOG2E 1.4426950408889634f

typedef __attribute__((ext_vector_type(8))) short short8;   // 8 bf16 = 4 VGPRs
typedef __attribute__((ext_vector_type(4))) float f32x4;    // MFMA acc

__device__ inline float b2f(unsigned short u) {
    union { unsigned int i; float f; } x; x.i = ((unsigned int)u) << 16; return x.f;
}
__device__ inline float b2f_lo(unsigned int u) {
    union { unsigned int i; float f; } x; x.i = u << 16; return x.f;
}
__device__ inline float b2f_hi(unsigned int u) {
    union { unsigned int i; float f; } x; x.i = u & 0xFFFF0000u; return x.f;
}
__device__ inline unsigned short f2b(float f) {
    union { float f; unsigned int i; } u; u.f = f;
    unsigned int r = u.i + 0x7FFF + ((u.i >> 16) & 1);   // round-to-nearest-even
    return (unsigned short)(r >> 16);
}

// ---------------- u-vector prep: u1[k][h] = sum_c W1[k][h*64+c] * att[h*64+c] ----------------
__global__ void uprep_kernel(const float* __restrict__ W1, const float* __restrict__ as1,
                             const float* __restrict__ ad1,
                             float* __restrict__ u1s, float* __restrict__ u1d) {
    int t = threadIdx.x;            // 256 threads: k = t>>2, h = t&3
    int k = t >> 2, h = t & 3;
    float s = 0.0f, d = 0.0f;
    for (int c = 0; c < 64; c++) {
        float w = W1[k * 256 + h * 64 + c];
        s += w * as1[h * 64 + c];
        d += w * ad1[h * 64 + c];
    }
    u1s[k * 4 + h] = s;
    u1d[k * 4 + h] = d;
}

// ---------------- encoder GEMM: fp32 compute, bf16 out + bias; fused conv1 scores ----------------
__global__ __launch_bounds__(256) void gemm_enc(const float* __restrict__ A,
                                                const float* __restrict__ B,
                                                const float* __restrict__ bias,
                                                unsigned short* __restrict__ C16,
                                                const float* __restrict__ u1s,
                                                const float* __restrict__ u1d,
                                                float* __restrict__ a_s,   // [N,4]
                                                float* __restrict__ a_d,
                                                int Nrows, int K, int M) {
    __shared__ float sA[16][64];
    __shared__ float sB[16][64];
    const int tx = threadIdx.x & 15;
    const int ty = threadIdx.x >> 4;
    const int row0 = blockIdx.x * 64;
    const int lr = threadIdx.x >> 2;
    const int lk = (threadIdx.x & 3) << 2;
    const int br = threadIdx.x >> 4;
    const int bc = (threadIdx.x & 15) << 2;

    const int aRow = row0 + lr;
    const bool aValid = aRow < Nrows;
    const float* Aptr = A + (size_t)aRow * K + lk;
    const float* Bptr = B + (size_t)br * M + bc;

    float acc[4][4] = {{0,0,0,0},{0,0,0,0},{0,0,0,0},{0,0,0,0}};
    float4 a = aValid ? *(const float4*)Aptr : float4{0,0,0,0};
    float4 b = *(const float4*)Bptr;

    for (int kt = 0; kt < K; kt += 16) {
        __syncthreads();
        sA[lk+0][lr] = a.x; sA[lk+1][lr] = a.y; sA[lk+2][lr] = a.z; sA[lk+3][lr] = a.w;
        *(float4*)&sB[br][bc] = b;
        __syncthreads();
        if (kt + 16 < K) {
            a = aValid ? *(const float4*)(Aptr + kt + 16) : float4{0,0,0,0};
            b = *(const float4*)(Bptr + (size_t)(kt + 16) * M);
        }
        #pragma unroll
        for (int k = 0; k < 16; k++) {
            const float4 av = *(const float4*)&sA[k][ty << 2];
            const float4 bv = *(const float4*)&sB[k][tx << 2];
            acc[0][0] += av.x*bv.x; acc[0][1] += av.x*bv.y; acc[0][2] += av.x*bv.z; acc[0][3] += av.x*bv.w;
            acc[1][0] += av.y*bv.x; acc[1][1] += av.y*bv.y; acc[1][2] += av.y*bv.z; acc[1][3] += av.y*bv.w;
            acc[2][0] += av.z*bv.x; acc[2][1] += av.z*bv.y; acc[2][2] += av.z*bv.z; acc[2][3] += av.z*bv.w;
            acc[3][0] += av.w*bv.x; acc[3][1] += av.w*bv.y; acc[3][2] += av.w*bv.z; acc[3][3] += av.w*bv.w;
        }
    }
    float4 bb = *(const float4*)&bias[tx << 2];
    #pragma unroll
    for (int i = 0; i < 4; i++) {
        acc[i][0] += bb.x; acc[i][1] += bb.y; acc[i][2] += bb.z; acc[i][3] += bb.w;
    }
    // fused conv1 attention scores (fp32): ps[i] = sum_k h[row,k]*u1s[k][:]
    float4 us[4], ud[4];
    #pragma unroll
    for (int j = 0; j < 4; j++) {
        us[j] = *(const float4*)&u1s[((tx << 2) + j) * 4];
        ud[j] = *(const float4*)&u1d[((tx << 2) + j) * 4];
    }
    #pragma unroll
    for (int i = 0; i < 4; i++) {
        float4 ps = {0,0,0,0}, pd = {0,0,0,0};
        #pragma unroll
        for (int j = 0; j < 4; j++) {
            ps.x += acc[i][j] * us[j].x; ps.y += acc[i][j] * us[j].y;
            ps.z += acc[i][j] * us[j].z; ps.w += acc[i][j] * us[j].w;
            pd.x += acc[i][j] * ud[j].x; pd.y += acc[i][j] * ud[j].y;
            pd.z += acc[i][j] * ud[j].z; pd.w += acc[i][j] * ud[j].w;
        }
        #pragma unroll
        for (int off = 1; off < 16; off <<= 1) {
            ps.x += __shfl_xor(ps.x, off); ps.y += __shfl_xor(ps.y, off);
            ps.z += __shfl_xor(ps.z, off); ps.w += __shfl_xor(ps.w, off);
            pd.x += __shfl_xor(pd.x, off); pd.y += __shfl_xor(pd.y, off);
            pd.z += __shfl_xor(pd.z, off); pd.w += __shfl_xor(pd.w, off);
        }
        int r = row0 + (ty << 2) + i;
        if (tx == 0 && r < Nrows) {
            float4 o1 = {ps.x * LOG2E, ps.y * LOG2E, ps.z * LOG2E, ps.w * LOG2E};
            float4 o2 = {pd.x * LOG2E, pd.y * LOG2E, pd.z * LOG2E, pd.w * LOG2E};
            *(float4*)&a_s[r * 4] = o1;
            *(float4*)&a_d[r * 4] = o2;
        }
    }
    #pragma unroll
    for (int i = 0; i < 4; i++) {
        int r = row0 + (ty << 2) + i;
        if (r < Nrows) {
            ushort4 o = {f2b(acc[i][0]), f2b(acc[i][1]), f2b(acc[i][2]), f2b(acc[i][3])};
            *(ushort4*)&C16[(size_t)r * M + (tx << 2)] = o;
        }
    }
}

// ---------------- weight prep: Wt[m][k] = bf16(W[k][m]) ----------------
__global__ void wtrans_kernel(const float* __restrict__ W, unsigned short* __restrict__ Wt,
                              int K, int M) {
    int i = blockIdx.x * 256 + threadIdx.x;
    if (i >= K * M) return;
    int k = i / M, m = i - k * M;
    Wt[(size_t)m * K + k] = f2b(W[i]);
}

// ---------------- MFMA GEMM: C16[N,M] = A16[N,K] @ Wt16^T ----------------
template<int CPW>
__global__ __launch_bounds__(256) void gemm_mfma(const unsigned short* __restrict__ A16,
                                                 const unsigned short* __restrict__ Bt16,
                                                 unsigned short* __restrict__ C16,
                                                 int Nrows, int K, int M) {
    constexpr int BN = CPW * 64;
    __shared__ unsigned short sA[64][40];
    __shared__ unsigned short sB[BN][40];
    const int tid = threadIdx.x;
    const int wave = tid >> 6;
    const int lane = tid & 63;
    const int quad = lane >> 4;
    const int l16 = lane & 15;
    const int row0 = blockIdx.x * 64;
    const int col0 = blockIdx.y * BN;
    const int sr = tid >> 2;
    const int sk = (tid & 3) << 3;

    f32x4 acc[4][CPW];
    #pragma unroll
    for (int i = 0; i < 4; i++)
        #pragma unroll
        for (int j = 0; j < CPW; j++) acc[i][j] = (f32x4){0,0,0,0};

    for (int kt = 0; kt < K; kt += 32) {
        __syncthreads();
        {
            int r = row0 + sr;
            uint4 z = {0,0,0,0};
            *(uint4*)&sA[sr][sk] = (r < Nrows) ? *(const uint4*)&A16[(size_t)r * K + kt + sk] : z;
        }
        #pragma unroll
        for (int i = 0; i < CPW; i++) {
            int c = col0 + sr + i * 64;
            *(uint4*)&sB[sr + i * 64][sk] = *(const uint4*)&Bt16[(size_t)c * K + kt + sk];
        }
        __syncthreads();
        short8 bf[CPW];
        #pragma unroll
        for (int j = 0; j < CPW; j++)
            bf[j] = *(const short8*)&sB[wave * (CPW * 16) + j * 16 + l16][quad * 8];
        #pragma unroll
        for (int i = 0; i < 4; i++) {
            short8 af = *(const short8*)&sA[i * 16 + l16][quad * 8];
            #pragma unroll
            for (int j = 0; j < CPW; j++)
                acc[i][j] = __builtin_amdgcn_mfma_f32_16x16x32_bf16(af, bf[j], acc[i][j], 0, 0, 0);
        }
    }
    #pragma unroll
    for (int i = 0; i < 4; i++) {
        #pragma unroll
        for (int j = 0; j < CPW; j++) {
            int col = col0 + wave * (CPW * 16) + j * 16 + l16;
            #pragma unroll
            for (int r = 0; r < 4; r++) {
                int row = row0 + i * 16 + quad * 4 + r;
                if (row < Nrows) C16[(size_t)row * M + col] = f2b(acc[i][j][r]);
            }
        }
    }
}

// ---------------- block-diagonal MFMA GEMM (conv1): out[:,h*64:+64] = ELU(agg[:,h*64:+64] @ W1_h + b) ----------------
// A16: [N,256] (head h cols h*64..); Bt16: [256][64] m-major; blockIdx.y = head.
__global__ __launch_bounds__(256) void gemm_bd64(const unsigned short* __restrict__ A16,
                                                 const unsigned short* __restrict__ Bt16,
                                                 const float* __restrict__ bias,
                                                 unsigned short* __restrict__ C16,
                                                 int Nrows) {
    __shared__ unsigned short sA[64][40];
    __shared__ unsigned short sB[64][40];
    const int tid = threadIdx.x;
    const int wave = tid >> 6;
    const int lane = tid & 63;
    const int quad = lane >> 4;
    const int l16 = lane & 15;
    const int h = blockIdx.y;
    const int row0 = blockIdx.x * 64;
    const int sr = tid >> 2;
    const int sk = (tid & 3) << 3;

    f32x4 acc[4];
    #pragma unroll
    for (int i = 0; i < 4; i++) acc[i] = (f32x4){0,0,0,0};

    #pragma unroll
    for (int kt = 0; kt < 64; kt += 32) {
        __syncthreads();
        {
            int r = row0 + sr;
            uint4 z = {0,0,0,0};
            *(uint4*)&sA[sr][sk] = (r < Nrows)
                ? *(const uint4*)&A16[(size_t)r * 256 + h * 64 + kt + sk] : z;
        }
        *(uint4*)&sB[sr][sk] = *(const uint4*)&Bt16[(size_t)(h * 64 + sr) * 64 + kt + sk];
        __syncthreads();
        short8 bf = *(const short8*)&sB[wave * 16 + l16][quad * 8];
        #pragma unroll
        for (int i = 0; i < 4; i++) {
            short8 af = *(const short8*)&sA[i * 16 + l16][quad * 8];
            acc[i] = __builtin_amdgcn_mfma_f32_16x16x32_bf16(af, bf, acc[i], 0, 0, 0);
        }
    }
    const int col = h * 64 + wave * 16 + l16;
    const float bb = bias[col];
    #pragma unroll
    for (int i = 0; i < 4; i++) {
        #pragma unroll
        for (int r = 0; r < 4; r++) {
            int row = row0 + i * 16 + quad * 4 + r;
            if (row < Nrows) {
                float v = acc[i][r] + bb;
                v = (v > 0.0f) ? v : expm1f(v);        // ELU
                C16[(size_t)row * 256 + col] = f2b(v);
            }
        }
    }
}

// ------------- attention scores H=4 (output space, conv2): wave/node, quad reduction -------------
__global__ void att_scores4(const unsigned short* __restrict__ hW16,
                            const float* __restrict__ att_s, const float* __restrict__ att_d,
                            float* __restrict__ a_s, float* __restrict__ a_d, int N) {
    const int lane = threadIdx.x & 63;
    const int n = blockIdx.x * 4 + (threadIdx.x >> 6);
    if (n >= N) return;
    const uint2 hv = *(const uint2*)&hW16[(size_t)n * 256 + (lane << 2)];
    const float4 sv = *(const float4*)&att_s[lane << 2];
    const float4 dv = *(const float4*)&att_d[lane << 2];
    const float v0 = b2f_lo(hv.x), v1 = b2f_hi(hv.x), v2 = b2f_lo(hv.y), v3 = b2f_hi(hv.y);
    float s = v0 * sv.x + v1 * sv.y + v2 * sv.z + v3 * sv.w;
    float d = v0 * dv.x + v1 * dv.y + v2 * dv.z + v3 * dv.w;
    #pragma unroll
    for (int off = 1; off < 16; off <<= 1) {
        s += __shfl_xor(s, off);
        d += __shfl_xor(d, off);
    }
    if ((lane & 15) == 0) {
        a_s[n * 4 + (lane >> 4)] = s * LOG2E;
        a_d[n * 4 + (lane >> 4)] = d * LOG2E;
    }
}

// ------------- attention scores H=1 (conv3) -------------
__global__ void att_scores1(const unsigned short* __restrict__ hW16,
                            const float* __restrict__ att_s, const float* __restrict__ att_d,
                            float* __restrict__ a_s, float* __restrict__ a_d, int N) {
    const int lane = threadIdx.x & 63;
    const int n = blockIdx.x * 4 + (threadIdx.x >> 6);
    if (n >= N) return;
    float v = b2f(hW16[(size_t)n * 64 + lane]);
    float s = v * att_s[lane];
    float d = v * att_d[lane];
    #pragma unroll
    for (int off = 32; off > 0; off >>= 1) {
        s += __shfl_xor(s, off);
        d += __shfl_xor(d, off);
    }
    if (lane == 0) { a_s[n] = s * LOG2E; a_d[n] = d * LOG2E; }
}

// ------------- CSR build -------------
__global__ void edge_hist_kernel(const int* __restrict__ ei, int* __restrict__ counts,
                                 int E, int Et) {
    int e = blockIdx.x * 256 + threadIdx.x;
    if (e >= Et) return;
    int d = (e < E) ? ei[E + e] : e - E;
    atomicAdd(&counts[d], 1);
}

__global__ __launch_bounds__(1024) void scan_blocks(int* __restrict__ counts,
                                                    int* __restrict__ blockSums, int N) {
    __shared__ int wsum[16];
    const int tid = threadIdx.x;
    const int lane = tid & 63;
    const int wave = tid >> 6;
    int i = blockIdx.x * 1024 + tid;
    int v = (i < N) ? counts[i] : 0;
    int s = v;
    #pragma unroll
    for (int off = 1; off < 64; off <<= 1) {
        int t = __shfl_up(s, off);
        if (lane >= off) s += t;
    }
    if (lane == 63) wsum[wave] = s;
    __syncthreads();
    if (wave == 0 && lane < 16) {
        int ws = wsum[lane];
        #pragma unroll
        for (int off = 1; off < 16; off <<= 1) {
            int t = __shfl_up(ws, off);
            if (lane >= off) ws += t;
        }
        wsum[lane] = ws;
    }
    __syncthreads();
    int waveOff = (wave > 0) ? wsum[wave - 1] : 0;
    int incl = s + waveOff;
    if (i < N) counts[i] = incl - v;
    if (tid == 1023) blockSums[blockIdx.x] = incl;
}

__global__ void scan_sums(int* __restrict__ bs, int nb) {
    const int lane = threadIdx.x;
    int carry = 0;
    for (int base = 0; base < nb; base += 64) {
        int i = base + lane;
        int v = (i < nb) ? bs[i] : 0;
        int s = v;
        #pragma unroll
        for (int off = 1; off < 64; off <<= 1) {
            int t = __shfl_up(s, off);
            if (lane >= off) s += t;
        }
        if (i < nb) bs[i] = carry + s - v;
        carry += __shfl(s, 63);
    }
}

__global__ void scan_add(const int* __restrict__ excl, const int* __restrict__ blockSums,
                         int* __restrict__ offsets, int* __restrict__ cursor, int N, int Et) {
    int i = blockIdx.x * 256 + threadIdx.x;
    if (i < N) {
        int o = excl[i] + blockSums[i >> 10];
        offsets[i] = o;
        cursor[i] = o;
    }
    if (i == N) offsets[N] = Et;
}

__global__ void edge_sort_kernel(const int* __restrict__ ei, int* __restrict__ cursor,
                                 int* __restrict__ srcS, int E, int Et) {
    int e = blockIdx.x * 256 + threadIdx.x;
    if (e >= Et) return;
    int s, d;
    if (e < E) { s = ei[e]; d = ei[E + e]; } else { s = d = e - E; }
    int pos = atomicAdd(&cursor[d], 1);
    srcS[pos] = s;
}

// ------------- conv1 aggregate in INPUT space (64-dim, 4 per-head accumulators) -------------
// wave/node; half-waves process alternating edges; lane covers channels 2*l32, 2*l32+1 for all 4 heads.
__global__ __launch_bounds__(256) void gat_agg_in64(
        const int* __restrict__ offsets, const int* __restrict__ srcS,
        const float4* __restrict__ a_s4, const float4* __restrict__ a_d4,
        const unsigned short* __restrict__ h16,    // [N,64]
        unsigned short* __restrict__ out16,        // [N,256] = [head][64]
        int N) {
    __shared__ float wlds[4][64][4];
    __shared__ int slds[4][64];
    const int wid = threadIdx.x >> 6;
    const int n = blockIdx.x * 4 + wid;
    if (n >= N) return;
    const int lane = threadIdx.x & 63;
    const int half = lane >> 5;
    const int l32 = lane & 31;
    const int start = offsets[n], end = offsets[n + 1];
    const float4 ad = a_d4[n];
    float2 acc[4] = {{0,0},{0,0},{0,0},{0,0}};
    float4 den = {0,0,0,0};
    const int loff = l32 << 1;

    for (int e0 = start; e0 < end; e0 += 64) {
        const int cnt = min(64, end - e0);
        if (lane < cnt) {
            int sB = srcS[e0 + lane];
            slds[wid][lane] = sB;
            const float4 as = a_s4[sB];
            float x0 = as.x + ad.x; x0 = fmaxf(x0, NEG_SLOPE * x0);
            float x1 = as.y + ad.y; x1 = fmaxf(x1, NEG_SLOPE * x1);
            float x2 = as.z + ad.z; x2 = fmaxf(x2, NEG_SLOPE * x2);
            float x3 = as.w + ad.w; x3 = fmaxf(x3, NEG_SLOPE * x3);
            wlds[wid][lane][0] = exp2f(x0);
            wlds[wid][lane][1] = exp2f(x1);
            wlds[wid][lane][2] = exp2f(x2);
            wlds[wid][lane][3] = exp2f(x3);
        }
        int j = half;
        for (; j + 4 <= cnt + half; j += 4) {      // 2 edges per half per iter
            const int s0 = slds[wid][j];
            const int s1 = slds[wid][j + 2];
            const float4 w0 = *(const float4*)&wlds[wid][j][0];
            const float4 w1 = *(const float4*)&wlds[wid][j + 2][0];
            const unsigned int g0 = *(const unsigned int*)&h16[((size_t)s0 << 6) + loff];
            const unsigned int g1 = *(const unsigned int*)&h16[((size_t)s1 << 6) + loff];
            const float v0l = b2f_lo(g0), v0h = b2f_hi(g0);
            const float v1l = b2f_lo(g1), v1h = b2f_hi(g1);
            acc[0].x += w0.x * v0l + w1.x * v1l; acc[0].y += w0.x * v0h + w1.x * v1h;
            acc[1].x += w0.y * v0l + w1.y * v1l; acc[1].y += w0.y * v0h + w1.y * v1h;
            acc[2].x += w0.z * v0l + w1.z * v1l; acc[2].y += w0.z * v0h + w1.z * v1h;
            acc[3].x += w0.w * v0l + w1.w * v1l; acc[3].y += w0.w * v0h + w1.w * v1h;
            den.x += w0.x + w1.x; den.y += w0.y + w1.y;
            den.z += w0.z + w1.z; den.w += w0.w + w1.w;
        }
        for (; j < cnt; j += 2) {
            const int s = slds[wid][j];
            const float4 w = *(const float4*)&wlds[wid][j][0];
            const unsigned int g = *(const unsigned int*)&h16[((size_t)s << 6) + loff];
            const float vl = b2f_lo(g), vh = b2f_hi(g);
            acc[0].x += w.x * vl; acc[0].y += w.x * vh;
            acc[1].x += w.y * vl; acc[1].y += w.y * vh;
            acc[2].x += w.z * vl; acc[2].y += w.z * vh;
            acc[3].x += w.w * vl; acc[3].y += w.w * vh;
            den.x += w.x; den.y += w.y; den.z += w.z; den.w += w.w;
        }
    }
    #pragma unroll
    for (int h = 0; h < 4; h++) {
        acc[h].x += __shfl_xor(acc[h].x, 32);
        acc[h].y += __shfl_xor(acc[h].y, 32);
    }
    den.x += __shfl_xor(den.x, 32); den.y += __shfl_xor(den.y, 32);
    den.z += __shfl_xor(den.z, 32); den.w += __shfl_xor(den.w, 32);
    if (half == 0) {
        const float i0 = 1.0f / (den.x + 1e-16f);
        const float i1 = 1.0f / (den.y + 1e-16f);
        const float i2 = 1.0f / (den.z + 1e-16f);
        const float i3 = 1.0f / (den.w + 1e-16f);
        unsigned int o0 = (unsigned int)f2b(acc[0].x * i0) | ((unsigned int)f2b(acc[0].y * i0) << 16);
        unsigned int o1 = (unsigned int)f2b(acc[1].x * i1) | ((unsigned int)f2b(acc[1].y * i1) << 16);
        unsigned int o2 = (unsigned int)f2b(acc[2].x * i2) | ((unsigned int)f2b(acc[2].y * i2) << 16);
        unsigned int o3 = (unsigned int)f2b(acc[3].x * i3) | ((unsigned int)f2b(acc[3].y * i3) << 16);
        *(unsigned int*)&out16[(size_t)n * 256 + 0 * 64 + loff] = o0;
        *(unsigned int*)&out16[(size_t)n * 256 + 1 * 64 + loff] = o1;
        *(unsigned int*)&out16[(size_t)n * 256 + 2 * 64 + loff] = o2;
        *(unsigned int*)&out16[(size_t)n * 256 + 3 * 64 + loff] = o3;
    }
}

// ------------- conv2 aggregate (output space, 256-dim), +bias+ELU, bf16 out -------------
__global__ __launch_bounds__(256) void gat_fused4(
        const int* __restrict__ offsets, const int* __restrict__ srcS,
        const float4* __restrict__ a_s4, const float4* __restrict__ a_d4,
        const unsigned short* __restrict__ hW16, const float* __restrict__ bias,
        unsigned short* __restrict__ out16, int N) {
    __shared__ float wlds[4][64][4];
    __shared__ int slds[4][64];
    const int wid = threadIdx.x >> 6;
    const int n = blockIdx.x * 4 + wid;
    if (n >= N) return;
    const int lane = threadIdx.x & 63;
    const int quad = lane >> 4;
    const int start = offsets[n], end = offsets[n + 1];
    const float4 ad = a_d4[n];
    float4 acc = {0, 0, 0, 0};
    float den = 0.0f;
    const int loff = lane << 2;

    for (int e0 = start; e0 < end; e0 += 64) {
        const int cnt = min(64, end - e0);
        if (lane < cnt) {
            int sB = srcS[e0 + lane];
            slds[wid][lane] = sB;
            const float4 as = a_s4[sB];
            float x0 = as.x + ad.x; x0 = fmaxf(x0, NEG_SLOPE * x0);
            float x1 = as.y + ad.y; x1 = fmaxf(x1, NEG_SLOPE * x1);
            float x2 = as.z + ad.z; x2 = fmaxf(x2, NEG_SLOPE * x2);
            float x3 = as.w + ad.w; x3 = fmaxf(x3, NEG_SLOPE * x3);
            wlds[wid][lane][0] = exp2f(x0);
            wlds[wid][lane][1] = exp2f(x1);
            wlds[wid][lane][2] = exp2f(x2);
            wlds[wid][lane][3] = exp2f(x3);
        }
        int j = 0;
        for (; j + 4 <= cnt; j += 4) {
            const int s0 = __builtin_amdgcn_readfirstlane(slds[wid][j + 0]);
            const int s1 = __builtin_amdgcn_readfirstlane(slds[wid][j + 1]);
            const int s2 = __builtin_amdgcn_readfirstlane(slds[wid][j + 2]);
            const int s3 = __builtin_amdgcn_readfirstlane(slds[wid][j + 3]);
            const float w0 = wlds[wid][j + 0][quad];
            const float w1 = wlds[wid][j + 1][quad];
            const float w2 = wlds[wid][j + 2][quad];
            const float w3 = wlds[wid][j + 3][quad];
            const uint2 h0 = *(const uint2*)&hW16[((size_t)s0 << 8) + loff];
            const uint2 h1 = *(const uint2*)&hW16[((size_t)s1 << 8) + loff];
            const uint2 h2 = *(const uint2*)&hW16[((size_t)s2 << 8) + loff];
            const uint2 h3 = *(const uint2*)&hW16[((size_t)s3 << 8) + loff];
            acc.x += w0 * b2f_lo(h0.x); acc.y += w0 * b2f_hi(h0.x);
            acc.z += w0 * b2f_lo(h0.y); acc.w += w0 * b2f_hi(h0.y);
            acc.x += w1 * b2f_lo(h1.x); acc.y += w1 * b2f_hi(h1.x);
            acc.z += w1 * b2f_lo(h1.y); acc.w += w1 * b2f_hi(h1.y);
            acc.x += w2 * b2f_lo(h2.x); acc.y += w2 * b2f_hi(h2.x);
            acc.z += w2 * b2f_lo(h2.y); acc.w += w2 * b2f_hi(h2.y);
            acc.x += w3 * b2f_lo(h3.x); acc.y += w3 * b2f_hi(h3.x);
            acc.z += w3 * b2f_lo(h3.y); acc.w += w3 * b2f_hi(h3.y);
            den += (w0 + w1) + (w2 + w3);
        }
        for (; j < cnt; j++) {
            const int s = __builtin_amdgcn_readfirstlane(slds[wid][j]);
            const float w = wlds[wid][j][quad];
            const uint2 hv = *(const uint2*)&hW16[((size_t)s << 8) + loff];
            acc.x += w * b2f_lo(hv.x); acc.y += w * b2f_hi(hv.x);
            acc.z += w * b2f_lo(hv.y); acc.w += w * b2f_hi(hv.y);
            den += w;
        }
    }

    const float inv = 1.0f / (den + 1e-16f);
    const float4 bb = *(const float4*)&bias[loff];
    float v0 = acc.x * inv + bb.x; v0 = (v0 > 0.0f) ? v0 : expm1f(v0);
    float v1 = acc.y * inv + bb.y; v1 = (v1 > 0.0f) ? v1 : expm1f(v1);
    float v2 = acc.z * inv + bb.z; v2 = (v2 > 0.0f) ? v2 : expm1f(v2);
    float v3 = acc.w * inv + bb.w; v3 = (v3 > 0.0f) ? v3 : expm1f(v3);
    uint2 o;
    o.x = (unsigned int)f2b(v0) | ((unsigned int)f2b(v1) << 16);
    o.y = (unsigned int)f2b(v2) | ((unsigned int)f2b(v3) << 16);
    *(uint2*)&out16[(size_t)n * 256 + loff] = o;
}

// ------------- H=1 fused (conv3): wave/node, LDS-batched weights, half-wave x4; fp32 out -------------
__global__ __launch_bounds__(256) void gat_fused1(
        const int* __restrict__ offsets, const int* __restrict__ srcS,
        const float* __restrict__ a_s, const float* __restrict__ a_d,
        const unsigned short* __restrict__ hW16, const float* __restrict__ bias,
        float* __restrict__ out, int N) {
    __shared__ float wlds[4][64];
    __shared__ int slds[4][64];
    const int wid = threadIdx.x >> 6;
    const int n = blockIdx.x * 4 + wid;
    if (n >= N) return;
    const int lane = threadIdx.x & 63;
    const int half = lane >> 5;
    const int l32 = lane & 31;
    const int start = offsets[n], end = offsets[n + 1];
    const float ad = a_d[n];
    float accx = 0.0f, accy = 0.0f, den = 0.0f;
    const int loff = l32 << 1;

    for (int e0 = start; e0 < end; e0 += 64) {
        const int cnt = min(64, end - e0);
        if (lane < cnt) {
            int sB = srcS[e0 + lane];
            slds[wid][lane] = sB;
            float ev = a_s[sB] + ad;
            ev = fmaxf(ev, NEG_SLOPE * ev);
            wlds[wid][lane] = exp2f(ev);
        }
        int j = half;
        for (; j + 8 <= cnt + half; j += 8) {
            const int s0 = slds[wid][j + 0];
            const int s1 = slds[wid][j + 2];
            const int s2 = slds[wid][j + 4];
            const int s3 = slds[wid][j + 6];
            const float w0 = wlds[wid][j + 0];
            const float w1 = wlds[wid][j + 2];
            const float w2 = wlds[wid][j + 4];
            const float w3 = wlds[wid][j + 6];
            const unsigned int h0 = *(const unsigned int*)&hW16[((size_t)s0 << 6) + loff];
            const unsigned int h1 = *(const unsigned int*)&hW16[((size_t)s1 << 6) + loff];
            const unsigned int h2 = *(const unsigned int*)&hW16[((size_t)s2 << 6) + loff];
            const unsigned int h3 = *(const unsigned int*)&hW16[((size_t)s3 << 6) + loff];
            accx += w0 * b2f_lo(h0); accy += w0 * b2f_hi(h0);
            accx += w1 * b2f_lo(h1); accy += w1 * b2f_hi(h1);
            accx += w2 * b2f_lo(h2); accy += w2 * b2f_hi(h2);
            accx += w3 * b2f_lo(h3); accy += w3 * b2f_hi(h3);
            den += (w0 + w1) + (w2 + w3);
        }
        for (; j < cnt; j += 2) {
            const int s = slds[wid][j];
            const float w = wlds[wid][j];
            const unsigned int hv = *(const unsigned int*)&hW16[((size_t)s << 6) + loff];
            accx += w * b2f_lo(hv);
            accy += w * b2f_hi(hv);
            den += w;
        }
    }
    accx += __shfl_xor(accx, 32);
    accy += __shfl_xor(accy, 32);
    den  += __shfl_xor(den, 32);
    if (half == 0) {
        const float inv = 1.0f / (den + 1e-16f);
        float2 o = {accx * inv + bias[loff], accy * inv + bias[loff + 1]};
        *(float2*)&out[(size_t)n * 64 + loff] = o;
    }
}

// ------------- per-graph mean pool (batch is sorted) -------------
__global__ void pool_kernel(const float* __restrict__ h, const int* __restrict__ batch,
                            float* __restrict__ pooled, float* __restrict__ cnt,
                            int N, int nWaves) {
    const int w = blockIdx.x * 4 + (threadIdx.x >> 6);
    const int lane = threadIdx.x & 63;
    const int chunk = (N + nWaves - 1) / nWaves;
    int start = w * chunk;
    int end = min(N, start + chunk);
    if (start >= end) return;
    int curg = batch[start];
    int runStart = start;
    float acc = 0.0f;
    for (int n = start; n < end; n++) {
        int g = batch[n];
        if (g != curg) {
            atomicAdd(&pooled[curg * 64 + lane], acc);
            if (lane == 0) atomicAdd(&cnt[curg], (float)(n - runStart));
            acc = 0.0f; curg = g; runStart = n;
        }
        acc += h[(size_t)n * 64 + lane];
    }
    atomicAdd(&pooled[curg * 64 + lane], acc);
    if (lane == 0) atomicAdd(&cnt[curg], (float)(end - runStart));
}

// ------------- decoder head: one block per graph -------------
__global__ __launch_bounds__(256) void final_kernel(
        const float* __restrict__ pooled, const float* __restrict__ cnt,
        const float* __restrict__ gf, const float* __restrict__ Wg,
        const float* __restrict__ bg, const float* __restrict__ Wd1,
        const float* __restrict__ bd1, const float* __restrict__ gamma,
        const float* __restrict__ beta, const float* __restrict__ Wd2,
        const float* __restrict__ bd2, float* __restrict__ out, int G) {
    const int g = blockIdx.x;
    const int tid = threadIdx.x;
    const int lane = tid & 63;
    const int wave = tid >> 6;
    __shared__ float spg[128];
    __shared__ float sz[64];
    __shared__ float wred[8];

    if (tid < 64) {
        spg[tid] = pooled[g * 64 + tid] / fmaxf(cnt[g], 1.0f);
    } else if (tid < 128) {
        int c = tid - 64;
        float v = bg[c];
        #pragma unroll
        for (int k = 0; k < 4; k++) v += gf[g * 4 + k] * Wg[k * 64 + c];
        spg[64 + c] = fmaxf(v, 0.0f);
    }
    __syncthreads();
    if (tid < 64) {
        float v = bd1[tid];
        #pragma unroll 8
        for (int k = 0; k < 128; k++) v += spg[k] * Wd1[k * 64 + tid];
        v = v * gamma[tid] + beta[tid];
        sz[tid] = fmaxf(v, 0.0f);
    }
    __syncthreads();
    float v = bd2[tid];
    #pragma unroll 8
    for (int k = 0; k < 64; k++) v += sz[k] * Wd2[k * 256 + tid];
    float m = v;
    #pragma unroll
    for (int off = 32; off > 0; off >>= 1) m = fmaxf(m, __shfl_xor(m, off));
    if (lane == 0) wred[wave] = m;
    __syncthreads();
    float M = fmaxf(fmaxf(wred[0], wred[1]), fmaxf(wred[2], wred[3]));
    float e = expf(v - M);
    float s = e;
    #pragma unroll
    for (int off = 32; off > 0; off >>= 1) s += __shfl_xor(s, off);
    if (lane == 0) wred[4 + wave] = s;
    __syncthreads();
    float S = (wred[4] + wred[5]) + (wred[6] + wred[7]);
    out[g * 256 + tid] = e / S;
}

extern "C" void kernel_launch(void* const* d_in, const int* in_sizes, int n_in,
                              void* d_out, int out_size, void* d_ws, size_t ws_size,
                              hipStream_t stream) {
    const float* x     = (const float*)d_in[0];
    const int*   ei    = (const int*)  d_in[1];
    const int*   batch = (const int*)  d_in[2];
    const float* gf    = (const float*)d_in[3];
    const float* W_enc = (const float*)d_in[4];
    const float* b_enc = (const float*)d_in[5];
    const float* W1  = (const float*)d_in[6];
    const float* as1 = (const float*)d_in[7];
    const float* ad1 = (const float*)d_in[8];
    const float* b1  = (const float*)d_in[9];
    const float* W2  = (const float*)d_in[10];
    const float* as2 = (const float*)d_in[11];
    const float* ad2 = (const float*)d_in[12];
    const float* b2  = (const float*)d_in[13];
    const float* W3  = (const float*)d_in[14];
    const float* as3 = (const float*)d_in[15];
    const float* ad3 = (const float*)d_in[16];
    const float* b3  = (const float*)d_in[17];
    const float* Wg  = (const float*)d_in[18];
    const float* bg  = (const float*)d_in[19];
    const float* Wd1 = (const float*)d_in[20];
    const float* bd1 = (const float*)d_in[21];
    const float* gm  = (const float*)d_in[22];
    const float* bt  = (const float*)d_in[23];
    const float* Wd2 = (const float*)d_in[24];
    const float* bd2 = (const float*)d_in[25];

    const int N  = in_sizes[2];
    const int E  = in_sizes[1] / 2;
    const int G  = in_sizes[3] / 4;
    const int Et = E + N;

    unsigned short* h16a = (unsigned short*)d_ws;                // [N,256] bf16
    unsigned short* h16b = h16a + (size_t)N * 256;               // [N,256] bf16
    unsigned short* h1_16 = h16b + (size_t)N * 256;              // [N,64] bf16
    unsigned short* Wt1  = h1_16 + (size_t)N * 64;               // [256,64]
    unsigned short* Wt2  = Wt1 + 256 * 64;                       // [256,256]
    unsigned short* Wt3  = Wt2 + 256 * 256;                      // [64,256]
    float* h3     = (float*)(Wt3 + 64 * 256);                    // [N,64] fp32
    float* a_s    = h3 + (size_t)N * 64;                         // [N,4]
    float* a_d    = a_s + (size_t)N * 4;                         // [N,4]
    float* u1s    = a_d + (size_t)N * 4;                         // [64,4]
    float* u1d    = u1s + 256;                                   // [64,4]
    float* pooled = u1d + 256;                                   // [G,64]
    float* cnt    = pooled + (size_t)G * 64;                     // [G]
    int*   offsets = (int*)(cnt + G);                            // [N+1]
    int*   srcS    = offsets + (N + 1);                          // [Et]
    int*   counts  = srcS + Et;                                  // [N]
    int*   cursor  = counts + N;                                 // [N]
    int*   blockSums = cursor + N;                               // [cdiv(N,1024)]

    dim3 blk(256);
    auto cdiv = [](int a, int b) { return (a + b - 1) / b; };
    const int eBlocks = cdiv(Et, 256);
    const int rowBlocks = cdiv(N, 64);
    const int nScanBlocks = cdiv(N, 1024);

    // ---------------- CSR build + weight prep ----------------
    hipMemsetAsync(counts, 0, (size_t)N * sizeof(int), stream);
    edge_hist_kernel<<<eBlocks, blk, 0, stream>>>(ei, counts, E, Et);
    scan_blocks<<<nScanBlocks, 1024, 0, stream>>>(counts, blockSums, N);
    scan_sums<<<1, 64, 0, stream>>>(blockSums, nScanBlocks);
    scan_add<<<cdiv(N + 1, 256), blk, 0, stream>>>(counts, blockSums, offsets, cursor, N, Et);
    edge_sort_kernel<<<eBlocks, blk, 0, stream>>>(ei, cursor, srcS, E, Et);
    wtrans_kernel<<<cdiv(64 * 256, 256), blk, 0, stream>>>(W1, Wt1, 64, 256);
    wtrans_kernel<<<cdiv(256 * 256, 256), blk, 0, stream>>>(W2, Wt2, 256, 256);
    wtrans_kernel<<<cdiv(256 * 64, 256), blk, 0, stream>>>(W3, Wt3, 256, 64);
    uprep_kernel<<<1, blk, 0, stream>>>(W1, as1, ad1, u1s, u1d);

    // encoder: x -> h1 bf16, + fused conv1 scores (fp32 acc . u1)
    gemm_enc<<<dim3(rowBlocks, 1), blk, 0, stream>>>(x, W_enc, b_enc, h1_16,
                                                     u1s, u1d, a_s, a_d, N, 32, 64);

    // ---------------- conv1 (H=4, in=64): aggregate FIRST (input space), then block-diag GEMM ----------------
    gat_agg_in64<<<cdiv(N, 4), blk, 0, stream>>>(offsets, srcS, (const float4*)a_s,
                                                 (const float4*)a_d, h1_16, h16a, N);
    gemm_bd64<<<dim3(rowBlocks, 4), blk, 0, stream>>>(h16a, Wt1, b1, h16b, N);   // h2 (+b1, ELU)

    // ---------------- conv2 (H=4, in=256): GEMM -> scores -> aggregate ----------------
    gemm_mfma<2><<<dim3(rowBlocks, 2), blk, 0, stream>>>(h16b, Wt2, h16a, N, 256, 256);
    att_scores4<<<cdiv(N, 4), blk, 0, stream>>>(h16a, as2, ad2, a_s, a_d, N);
    gat_fused4<<<cdiv(N, 4), blk, 0, stream>>>(offsets, srcS, (const float4*)a_s,
                                               (const float4*)a_d, h16a, b2, h16b, N);

    // ---------------- conv3 (H=1, in=256, no concat) ----------------
    gemm_mfma<1><<<dim3(rowBlocks, 1), blk, 0, stream>>>(h16b, Wt3, h1_16, N, 256, 64);
    att_scores1<<<cdiv(N, 4), blk, 0, stream>>>(h1_16, as3, ad3, a_s, a_d, N);
    gat_fused1<<<cdiv(N, 4), blk, 0, stream>>>(offsets, srcS, a_s, a_d, h1_16, b3, h3, N);

    // ---------------- mean pool + decoder head ----------------
    hipMemsetAsync(pooled, 0, (size_t)G * 64 * sizeof(float), stream);
    hipMemsetAsync(cnt, 0, (size_t)G * sizeof(float), stream);
    pool_kernel<<<512, blk, 0, stream>>>(h3, batch, pooled, cnt, N, 512 * 4);
    final_kernel<<<G, blk, 0, stream>>>(pooled, cnt, gf, Wg, bg, Wd1, bd1, gm, bt, Wd2, bd2,
                                        (float*)d_out, G);
}

// Round 13
// 470.790 us; speedup vs baseline: 5.1046x; 1.0233x over previous
//
#include <hip/hip_runtime.h>
#include <math.h>

#define NEG_SLOPE 0.2f
#define LOG2E 1.4426950408889634f

typedef __attribute__((ext_vector_type(8))) short short8;   // 8 bf16 = 4 VGPRs
typedef __attribute__((ext_vector_type(4))) float f32x4;    // MFMA acc

__device__ inline float b2f(unsigned short u) {
    union { unsigned int i; float f; } x; x.i = ((unsigned int)u) << 16; return x.f;
}
__device__ inline float b2f_lo(unsigned int u) {
    union { unsigned int i; float f; } x; x.i = u << 16; return x.f;
}
__device__ inline float b2f_hi(unsigned int u) {
    union { unsigned int i; float f; } x; x.i = u & 0xFFFF0000u; return x.f;
}
__device__ inline unsigned short f2b(float f) {
    union { float f; unsigned int i; } u; u.f = f;
    unsigned int r = u.i + 0x7FFF + ((u.i >> 16) & 1);   // round-to-nearest-even
    return (unsigned short)(r >> 16);
}

// ---------------- combined prep: Wt1/Wt2/Wt3 transpose+bf16 and u1 vectors ----------------
// blocks 0..63: W1[64,256]->Wt1 ; 64..319: W2[256,256]->Wt2 ; 320..383: W3[256,64]->Wt3 ; 384: uprep
__global__ void prep_kernel(const float* __restrict__ W1, const float* __restrict__ W2,
                            const float* __restrict__ W3, const float* __restrict__ as1,
                            const float* __restrict__ ad1,
                            unsigned short* __restrict__ Wt1, unsigned short* __restrict__ Wt2,
                            unsigned short* __restrict__ Wt3,
                            float* __restrict__ u1s, float* __restrict__ u1d) {
    const int b = blockIdx.x;
    const int t = threadIdx.x;
    if (b < 64) {
        int i = b * 256 + t;                    // K=64, M=256
        int k = i >> 8, m = i & 255;
        Wt1[(size_t)m * 64 + k] = f2b(W1[i]);
    } else if (b < 320) {
        int i = (b - 64) * 256 + t;             // K=256, M=256
        int k = i >> 8, m = i & 255;
        Wt2[(size_t)m * 256 + k] = f2b(W2[i]);
    } else if (b < 384) {
        int i = (b - 320) * 256 + t;            // K=256, M=64
        int k = i >> 6, m = i & 63;
        Wt3[(size_t)m * 256 + k] = f2b(W3[i]);
    } else {
        int k = t >> 2, h = t & 3;
        float s = 0.0f, d = 0.0f;
        for (int c = 0; c < 64; c++) {
            float w = W1[k * 256 + h * 64 + c];
            s += w * as1[h * 64 + c];
            d += w * ad1[h * 64 + c];
        }
        u1s[k * 4 + h] = s;
        u1d[k * 4 + h] = d;
    }
}

// ---------------- encoder GEMM: fp32 compute, bf16 out + bias; fused conv1 scores ----------------
__global__ __launch_bounds__(256) void gemm_enc(const float* __restrict__ A,
                                                const float* __restrict__ B,
                                                const float* __restrict__ bias,
                                                unsigned short* __restrict__ C16,
                                                const float* __restrict__ u1s,
                                                const float* __restrict__ u1d,
                                                float* __restrict__ a_s,   // [N,4]
                                                float* __restrict__ a_d,
                                                int Nrows, int K, int M) {
    __shared__ float sA[16][64];
    __shared__ float sB[16][64];
    const int tx = threadIdx.x & 15;
    const int ty = threadIdx.x >> 4;
    const int row0 = blockIdx.x * 64;
    const int lr = threadIdx.x >> 2;
    const int lk = (threadIdx.x & 3) << 2;
    const int br = threadIdx.x >> 4;
    const int bc = (threadIdx.x & 15) << 2;

    const int aRow = row0 + lr;
    const bool aValid = aRow < Nrows;
    const float* Aptr = A + (size_t)aRow * K + lk;
    const float* Bptr = B + (size_t)br * M + bc;

    float acc[4][4] = {{0,0,0,0},{0,0,0,0},{0,0,0,0},{0,0,0,0}};
    float4 a = aValid ? *(const float4*)Aptr : float4{0,0,0,0};
    float4 b = *(const float4*)Bptr;

    for (int kt = 0; kt < K; kt += 16) {
        __syncthreads();
        sA[lk+0][lr] = a.x; sA[lk+1][lr] = a.y; sA[lk+2][lr] = a.z; sA[lk+3][lr] = a.w;
        *(float4*)&sB[br][bc] = b;
        __syncthreads();
        if (kt + 16 < K) {
            a = aValid ? *(const float4*)(Aptr + kt + 16) : float4{0,0,0,0};
            b = *(const float4*)(Bptr + (size_t)(kt + 16) * M);
        }
        #pragma unroll
        for (int k = 0; k < 16; k++) {
            const float4 av = *(const float4*)&sA[k][ty << 2];
            const float4 bv = *(const float4*)&sB[k][tx << 2];
            acc[0][0] += av.x*bv.x; acc[0][1] += av.x*bv.y; acc[0][2] += av.x*bv.z; acc[0][3] += av.x*bv.w;
            acc[1][0] += av.y*bv.x; acc[1][1] += av.y*bv.y; acc[1][2] += av.y*bv.z; acc[1][3] += av.y*bv.w;
            acc[2][0] += av.z*bv.x; acc[2][1] += av.z*bv.y; acc[2][2] += av.z*bv.z; acc[2][3] += av.z*bv.w;
            acc[3][0] += av.w*bv.x; acc[3][1] += av.w*bv.y; acc[3][2] += av.w*bv.z; acc[3][3] += av.w*bv.w;
        }
    }
    float4 bb = *(const float4*)&bias[tx << 2];
    #pragma unroll
    for (int i = 0; i < 4; i++) {
        acc[i][0] += bb.x; acc[i][1] += bb.y; acc[i][2] += bb.z; acc[i][3] += bb.w;
    }
    float4 us[4], ud[4];
    #pragma unroll
    for (int j = 0; j < 4; j++) {
        us[j] = *(const float4*)&u1s[((tx << 2) + j) * 4];
        ud[j] = *(const float4*)&u1d[((tx << 2) + j) * 4];
    }
    #pragma unroll
    for (int i = 0; i < 4; i++) {
        float4 ps = {0,0,0,0}, pd = {0,0,0,0};
        #pragma unroll
        for (int j = 0; j < 4; j++) {
            ps.x += acc[i][j] * us[j].x; ps.y += acc[i][j] * us[j].y;
            ps.z += acc[i][j] * us[j].z; ps.w += acc[i][j] * us[j].w;
            pd.x += acc[i][j] * ud[j].x; pd.y += acc[i][j] * ud[j].y;
            pd.z += acc[i][j] * ud[j].z; pd.w += acc[i][j] * ud[j].w;
        }
        #pragma unroll
        for (int off = 1; off < 16; off <<= 1) {
            ps.x += __shfl_xor(ps.x, off); ps.y += __shfl_xor(ps.y, off);
            ps.z += __shfl_xor(ps.z, off); ps.w += __shfl_xor(ps.w, off);
            pd.x += __shfl_xor(pd.x, off); pd.y += __shfl_xor(pd.y, off);
            pd.z += __shfl_xor(pd.z, off); pd.w += __shfl_xor(pd.w, off);
        }
        int r = row0 + (ty << 2) + i;
        if (tx == 0 && r < Nrows) {
            float4 o1 = {ps.x * LOG2E, ps.y * LOG2E, ps.z * LOG2E, ps.w * LOG2E};
            float4 o2 = {pd.x * LOG2E, pd.y * LOG2E, pd.z * LOG2E, pd.w * LOG2E};
            *(float4*)&a_s[r * 4] = o1;
            *(float4*)&a_d[r * 4] = o2;
        }
    }
    #pragma unroll
    for (int i = 0; i < 4; i++) {
        int r = row0 + (ty << 2) + i;
        if (r < Nrows) {
            ushort4 o = {f2b(acc[i][0]), f2b(acc[i][1]), f2b(acc[i][2]), f2b(acc[i][3])};
            *(ushort4*)&C16[(size_t)r * M + (tx << 2)] = o;
        }
    }
}

// ---------------- MFMA GEMM: C16[N,M] = A16[N,K] @ Wt16^T; optional fused scores ----------------
// SCORES=1: a_s/a_d[N,H] written from fp32 accumulators (H = M/64).
template<int CPW, int SCORES>
__global__ __launch_bounds__(256) void gemm_mfma(const unsigned short* __restrict__ A16,
                                                 const unsigned short* __restrict__ Bt16,
                                                 unsigned short* __restrict__ C16,
                                                 const float* __restrict__ att_s,
                                                 const float* __restrict__ att_d,
                                                 float* __restrict__ a_s,
                                                 float* __restrict__ a_d,
                                                 int Nrows, int K, int M, int H) {
    constexpr int BN = CPW * 64;
    __shared__ unsigned short sA[64][40];
    __shared__ unsigned short sB[BN][40];
    const int tid = threadIdx.x;
    const int wave = tid >> 6;
    const int lane = tid & 63;
    const int quad = lane >> 4;
    const int l16 = lane & 15;
    const int row0 = blockIdx.x * 64;
    const int col0 = blockIdx.y * BN;
    const int sr = tid >> 2;
    const int sk = (tid & 3) << 3;

    f32x4 acc[4][CPW];
    #pragma unroll
    for (int i = 0; i < 4; i++)
        #pragma unroll
        for (int j = 0; j < CPW; j++) acc[i][j] = (f32x4){0,0,0,0};

    for (int kt = 0; kt < K; kt += 32) {
        __syncthreads();
        {
            int r = row0 + sr;
            uint4 z = {0,0,0,0};
            *(uint4*)&sA[sr][sk] = (r < Nrows) ? *(const uint4*)&A16[(size_t)r * K + kt + sk] : z;
        }
        #pragma unroll
        for (int i = 0; i < CPW; i++) {
            int c = col0 + sr + i * 64;
            *(uint4*)&sB[sr + i * 64][sk] = *(const uint4*)&Bt16[(size_t)c * K + kt + sk];
        }
        __syncthreads();
        short8 bf[CPW];
        #pragma unroll
        for (int j = 0; j < CPW; j++)
            bf[j] = *(const short8*)&sB[wave * (CPW * 16) + j * 16 + l16][quad * 8];
        #pragma unroll
        for (int i = 0; i < 4; i++) {
            short8 af = *(const short8*)&sA[i * 16 + l16][quad * 8];
            #pragma unroll
            for (int j = 0; j < CPW; j++)
                acc[i][j] = __builtin_amdgcn_mfma_f32_16x16x32_bf16(af, bf[j], acc[i][j], 0, 0, 0);
        }
    }
    if (SCORES) {
        __shared__ float sSD[64][CPW][2];
        for (int t = tid; t < 64 * CPW * 2; t += 256) ((float*)sSD)[t] = 0.0f;
        __syncthreads();
        const int hib = (wave * CPW * 16) >> 6;      // all j of a wave share a head (CPW<=2)
        float avs[CPW], avd[CPW];
        #pragma unroll
        for (int j = 0; j < CPW; j++) {
            int c = col0 + wave * (CPW * 16) + j * 16 + l16;
            avs[j] = att_s[c];
            avd[j] = att_d[c];
        }
        #pragma unroll
        for (int i = 0; i < 4; i++) {
            float ps[4] = {0,0,0,0}, pd[4] = {0,0,0,0};
            #pragma unroll
            for (int j = 0; j < CPW; j++)
                #pragma unroll
                for (int r = 0; r < 4; r++) {
                    ps[r] += acc[i][j][r] * avs[j];
                    pd[r] += acc[i][j][r] * avd[j];
                }
            #pragma unroll
            for (int off = 1; off < 16; off <<= 1)
                #pragma unroll
                for (int r = 0; r < 4; r++) {
                    ps[r] += __shfl_xor(ps[r], off);
                    pd[r] += __shfl_xor(pd[r], off);
                }
            if (l16 == 0) {
                #pragma unroll
                for (int r = 0; r < 4; r++) {
                    atomicAdd(&sSD[i * 16 + quad * 4 + r][hib][0], ps[r]);
                    atomicAdd(&sSD[i * 16 + quad * 4 + r][hib][1], pd[r]);
                }
            }
        }
        __syncthreads();
        for (int t = tid; t < 64 * CPW; t += 256) {
            int row = t & 63, hb = t >> 6;
            int r = row0 + row;
            if (r < Nrows) {
                int hg = (col0 >> 6) + hb;
                a_s[r * H + hg] = sSD[row][hb][0] * LOG2E;
                a_d[r * H + hg] = sSD[row][hb][1] * LOG2E;
            }
        }
    }
    #pragma unroll
    for (int i = 0; i < 4; i++) {
        #pragma unroll
        for (int j = 0; j < CPW; j++) {
            int col = col0 + wave * (CPW * 16) + j * 16 + l16;
            #pragma unroll
            for (int r = 0; r < 4; r++) {
                int row = row0 + i * 16 + quad * 4 + r;
                if (row < Nrows) C16[(size_t)row * M + col] = f2b(acc[i][j][r]);
            }
        }
    }
}

// ---------------- block-diagonal MFMA GEMM (conv1): out[:,h*64:+64] = ELU(agg_h @ W1_h + b) ----------------
__global__ __launch_bounds__(256) void gemm_bd64(const unsigned short* __restrict__ A16,
                                                 const unsigned short* __restrict__ Bt16,
                                                 const float* __restrict__ bias,
                                                 unsigned short* __restrict__ C16,
                                                 int Nrows) {
    __shared__ unsigned short sA[64][40];
    __shared__ unsigned short sB[64][40];
    const int tid = threadIdx.x;
    const int wave = tid >> 6;
    const int lane = tid & 63;
    const int quad = lane >> 4;
    const int l16 = lane & 15;
    const int h = blockIdx.y;
    const int row0 = blockIdx.x * 64;
    const int sr = tid >> 2;
    const int sk = (tid & 3) << 3;

    f32x4 acc[4];
    #pragma unroll
    for (int i = 0; i < 4; i++) acc[i] = (f32x4){0,0,0,0};

    #pragma unroll
    for (int kt = 0; kt < 64; kt += 32) {
        __syncthreads();
        {
            int r = row0 + sr;
            uint4 z = {0,0,0,0};
            *(uint4*)&sA[sr][sk] = (r < Nrows)
                ? *(const uint4*)&A16[(size_t)r * 256 + h * 64 + kt + sk] : z;
        }
        *(uint4*)&sB[sr][sk] = *(const uint4*)&Bt16[(size_t)(h * 64 + sr) * 64 + kt + sk];
        __syncthreads();
        short8 bf = *(const short8*)&sB[wave * 16 + l16][quad * 8];
        #pragma unroll
        for (int i = 0; i < 4; i++) {
            short8 af = *(const short8*)&sA[i * 16 + l16][quad * 8];
            acc[i] = __builtin_amdgcn_mfma_f32_16x16x32_bf16(af, bf, acc[i], 0, 0, 0);
        }
    }
    const int col = h * 64 + wave * 16 + l16;
    const float bb = bias[col];
    #pragma unroll
    for (int i = 0; i < 4; i++) {
        #pragma unroll
        for (int r = 0; r < 4; r++) {
            int row = row0 + i * 16 + quad * 4 + r;
            if (row < Nrows) {
                float v = acc[i][r] + bb;
                v = (v > 0.0f) ? v : expm1f(v);        // ELU
                C16[(size_t)row * 256 + col] = f2b(v);
            }
        }
    }
}

// ------------- CSR build -------------
__global__ void edge_hist_kernel(const int* __restrict__ ei, int* __restrict__ counts,
                                 int E, int Et) {
    int e = blockIdx.x * 256 + threadIdx.x;
    if (e >= Et) return;
    int d = (e < E) ? ei[E + e] : e - E;
    atomicAdd(&counts[d], 1);
}

__global__ __launch_bounds__(1024) void scan_blocks(int* __restrict__ counts,
                                                    int* __restrict__ blockSums, int N) {
    __shared__ int wsum[16];
    const int tid = threadIdx.x;
    const int lane = tid & 63;
    const int wave = tid >> 6;
    int i = blockIdx.x * 1024 + tid;
    int v = (i < N) ? counts[i] : 0;
    int s = v;
    #pragma unroll
    for (int off = 1; off < 64; off <<= 1) {
        int t = __shfl_up(s, off);
        if (lane >= off) s += t;
    }
    if (lane == 63) wsum[wave] = s;
    __syncthreads();
    if (wave == 0 && lane < 16) {
        int ws = wsum[lane];
        #pragma unroll
        for (int off = 1; off < 16; off <<= 1) {
            int t = __shfl_up(ws, off);
            if (lane >= off) ws += t;
        }
        wsum[lane] = ws;
    }
    __syncthreads();
    int waveOff = (wave > 0) ? wsum[wave - 1] : 0;
    int incl = s + waveOff;
    if (i < N) counts[i] = incl - v;
    if (tid == 1023) blockSums[blockIdx.x] = incl;
}

__global__ void scan_sums(int* __restrict__ bs, int nb) {
    const int lane = threadIdx.x;
    int carry = 0;
    for (int base = 0; base < nb; base += 64) {
        int i = base + lane;
        int v = (i < nb) ? bs[i] : 0;
        int s = v;
        #pragma unroll
        for (int off = 1; off < 64; off <<= 1) {
            int t = __shfl_up(s, off);
            if (lane >= off) s += t;
        }
        if (i < nb) bs[i] = carry + s - v;
        carry += __shfl(s, 63);
    }
}

__global__ void scan_add(const int* __restrict__ excl, const int* __restrict__ blockSums,
                         int* __restrict__ offsets, int* __restrict__ cursor, int N, int Et) {
    int i = blockIdx.x * 256 + threadIdx.x;
    if (i < N) {
        int o = excl[i] + blockSums[i >> 10];
        offsets[i] = o;
        cursor[i] = o;
    }
    if (i == N) offsets[N] = Et;
}

__global__ void edge_sort_kernel(const int* __restrict__ ei, int* __restrict__ cursor,
                                 int* __restrict__ srcS, int E, int Et) {
    int e = blockIdx.x * 256 + threadIdx.x;
    if (e >= Et) return;
    int s, d;
    if (e < E) { s = ei[e]; d = ei[E + e]; } else { s = d = e - E; }
    int pos = atomicAdd(&cursor[d], 1);
    srcS[pos] = s;
}

// ------------- conv1 aggregate in INPUT space (64-dim, 4 per-head accumulators) -------------
__global__ __launch_bounds__(256) void gat_agg_in64(
        const int* __restrict__ offsets, const int* __restrict__ srcS,
        const float4* __restrict__ a_s4, const float4* __restrict__ a_d4,
        const unsigned short* __restrict__ h16,    // [N,64]
        unsigned short* __restrict__ out16,        // [N,256] = [head][64]
        int N) {
    __shared__ float wlds[4][64][4];
    __shared__ int slds[4][64];
    const int wid = threadIdx.x >> 6;
    const int n = blockIdx.x * 4 + wid;
    if (n >= N) return;
    const int lane = threadIdx.x & 63;
    const int half = lane >> 5;
    const int l32 = lane & 31;
    const int start = offsets[n], end = offsets[n + 1];
    const float4 ad = a_d4[n];
    float2 acc[4] = {{0,0},{0,0},{0,0},{0,0}};
    float4 den = {0,0,0,0};
    const int loff = l32 << 1;

    for (int e0 = start; e0 < end; e0 += 64) {
        const int cnt = min(64, end - e0);
        if (lane < cnt) {
            int sB = srcS[e0 + lane];
            slds[wid][lane] = sB;
            const float4 as = a_s4[sB];
            float x0 = as.x + ad.x; x0 = fmaxf(x0, NEG_SLOPE * x0);
            float x1 = as.y + ad.y; x1 = fmaxf(x1, NEG_SLOPE * x1);
            float x2 = as.z + ad.z; x2 = fmaxf(x2, NEG_SLOPE * x2);
            float x3 = as.w + ad.w; x3 = fmaxf(x3, NEG_SLOPE * x3);
            wlds[wid][lane][0] = exp2f(x0);
            wlds[wid][lane][1] = exp2f(x1);
            wlds[wid][lane][2] = exp2f(x2);
            wlds[wid][lane][3] = exp2f(x3);
        }
        int j = half;
        for (; j + 8 <= cnt + half; j += 8) {      // 4 edges per half per iter
            int ss[4]; float4 ww[4]; unsigned int gg[4];
            #pragma unroll
            for (int u = 0; u < 4; u++) {
                ss[u] = slds[wid][j + 2 * u];
                ww[u] = *(const float4*)&wlds[wid][j + 2 * u][0];
            }
            #pragma unroll
            for (int u = 0; u < 4; u++)
                gg[u] = *(const unsigned int*)&h16[((size_t)ss[u] << 6) + loff];
            #pragma unroll
            for (int u = 0; u < 4; u++) {
                const float vl = b2f_lo(gg[u]), vh = b2f_hi(gg[u]);
                acc[0].x += ww[u].x * vl; acc[0].y += ww[u].x * vh;
                acc[1].x += ww[u].y * vl; acc[1].y += ww[u].y * vh;
                acc[2].x += ww[u].z * vl; acc[2].y += ww[u].z * vh;
                acc[3].x += ww[u].w * vl; acc[3].y += ww[u].w * vh;
                den.x += ww[u].x; den.y += ww[u].y; den.z += ww[u].z; den.w += ww[u].w;
            }
        }
        for (; j < cnt; j += 2) {
            const int s = slds[wid][j];
            const float4 w = *(const float4*)&wlds[wid][j][0];
            const unsigned int g = *(const unsigned int*)&h16[((size_t)s << 6) + loff];
            const float vl = b2f_lo(g), vh = b2f_hi(g);
            acc[0].x += w.x * vl; acc[0].y += w.x * vh;
            acc[1].x += w.y * vl; acc[1].y += w.y * vh;
            acc[2].x += w.z * vl; acc[2].y += w.z * vh;
            acc[3].x += w.w * vl; acc[3].y += w.w * vh;
            den.x += w.x; den.y += w.y; den.z += w.z; den.w += w.w;
        }
    }
    #pragma unroll
    for (int h = 0; h < 4; h++) {
        acc[h].x += __shfl_xor(acc[h].x, 32);
        acc[h].y += __shfl_xor(acc[h].y, 32);
    }
    den.x += __shfl_xor(den.x, 32); den.y += __shfl_xor(den.y, 32);
    den.z += __shfl_xor(den.z, 32); den.w += __shfl_xor(den.w, 32);
    if (half == 0) {
        const float i0 = 1.0f / (den.x + 1e-16f);
        const float i1 = 1.0f / (den.y + 1e-16f);
        const float i2 = 1.0f / (den.z + 1e-16f);
        const float i3 = 1.0f / (den.w + 1e-16f);
        unsigned int o0 = (unsigned int)f2b(acc[0].x * i0) | ((unsigned int)f2b(acc[0].y * i0) << 16);
        unsigned int o1 = (unsigned int)f2b(acc[1].x * i1) | ((unsigned int)f2b(acc[1].y * i1) << 16);
        unsigned int o2 = (unsigned int)f2b(acc[2].x * i2) | ((unsigned int)f2b(acc[2].y * i2) << 16);
        unsigned int o3 = (unsigned int)f2b(acc[3].x * i3) | ((unsigned int)f2b(acc[3].y * i3) << 16);
        *(unsigned int*)&out16[(size_t)n * 256 + 0 * 64 + loff] = o0;
        *(unsigned int*)&out16[(size_t)n * 256 + 1 * 64 + loff] = o1;
        *(unsigned int*)&out16[(size_t)n * 256 + 2 * 64 + loff] = o2;
        *(unsigned int*)&out16[(size_t)n * 256 + 3 * 64 + loff] = o3;
    }
}

// ------------- conv2 aggregate (output space, 256-dim), x8 unrolled gather, +bias+ELU -------------
__global__ __launch_bounds__(256) void gat_fused4(
        const int* __restrict__ offsets, const int* __restrict__ srcS,
        const float4* __restrict__ a_s4, const float4* __restrict__ a_d4,
        const unsigned short* __restrict__ hW16, const float* __restrict__ bias,
        unsigned short* __restrict__ out16, int N) {
    __shared__ float wlds[4][64][4];
    __shared__ int slds[4][64];
    const int wid = threadIdx.x >> 6;
    const int n = blockIdx.x * 4 + wid;
    if (n >= N) return;
    const int lane = threadIdx.x & 63;
    const int quad = lane >> 4;
    const int start = offsets[n], end = offsets[n + 1];
    const float4 ad = a_d4[n];
    float4 acc = {0, 0, 0, 0};
    float den = 0.0f;
    const int loff = lane << 2;

    for (int e0 = start; e0 < end; e0 += 64) {
        const int cnt = min(64, end - e0);
        if (lane < cnt) {
            int sB = srcS[e0 + lane];
            slds[wid][lane] = sB;
            const float4 as = a_s4[sB];
            float x0 = as.x + ad.x; x0 = fmaxf(x0, NEG_SLOPE * x0);
            float x1 = as.y + ad.y; x1 = fmaxf(x1, NEG_SLOPE * x1);
            float x2 = as.z + ad.z; x2 = fmaxf(x2, NEG_SLOPE * x2);
            float x3 = as.w + ad.w; x3 = fmaxf(x3, NEG_SLOPE * x3);
            wlds[wid][lane][0] = exp2f(x0);
            wlds[wid][lane][1] = exp2f(x1);
            wlds[wid][lane][2] = exp2f(x2);
            wlds[wid][lane][3] = exp2f(x3);
        }
        int j = 0;
        for (; j + 8 <= cnt; j += 8) {
            int ss[8]; float ww[8]; uint2 hh[8];
            #pragma unroll
            for (int u = 0; u < 8; u++) {
                ss[u] = __builtin_amdgcn_readfirstlane(slds[wid][j + u]);
                ww[u] = wlds[wid][j + u][quad];
            }
            #pragma unroll
            for (int u = 0; u < 8; u++)
                hh[u] = *(const uint2*)&hW16[((size_t)ss[u] << 8) + loff];
            #pragma unroll
            for (int u = 0; u < 8; u++) {
                acc.x += ww[u] * b2f_lo(hh[u].x); acc.y += ww[u] * b2f_hi(hh[u].x);
                acc.z += ww[u] * b2f_lo(hh[u].y); acc.w += ww[u] * b2f_hi(hh[u].y);
                den += ww[u];
            }
        }
        for (; j < cnt; j++) {
            const int s = __builtin_amdgcn_readfirstlane(slds[wid][j]);
            const float w = wlds[wid][j][quad];
            const uint2 hv = *(const uint2*)&hW16[((size_t)s << 8) + loff];
            acc.x += w * b2f_lo(hv.x); acc.y += w * b2f_hi(hv.x);
            acc.z += w * b2f_lo(hv.y); acc.w += w * b2f_hi(hv.y);
            den += w;
        }
    }

    const float inv = 1.0f / (den + 1e-16f);
    const float4 bb = *(const float4*)&bias[loff];
    float v0 = acc.x * inv + bb.x; v0 = (v0 > 0.0f) ? v0 : expm1f(v0);
    float v1 = acc.y * inv + bb.y; v1 = (v1 > 0.0f) ? v1 : expm1f(v1);
    float v2 = acc.z * inv + bb.z; v2 = (v2 > 0.0f) ? v2 : expm1f(v2);
    float v3 = acc.w * inv + bb.w; v3 = (v3 > 0.0f) ? v3 : expm1f(v3);
    uint2 o;
    o.x = (unsigned int)f2b(v0) | ((unsigned int)f2b(v1) << 16);
    o.y = (unsigned int)f2b(v2) | ((unsigned int)f2b(v3) << 16);
    *(uint2*)&out16[(size_t)n * 256 + loff] = o;
}

// ------------- H=1 fused (conv3): wave/node, LDS-batched weights, half-wave x4; fp32 out -------------
__global__ __launch_bounds__(256) void gat_fused1(
        const int* __restrict__ offsets, const int* __restrict__ srcS,
        const float* __restrict__ a_s, const float* __restrict__ a_d,
        const unsigned short* __restrict__ hW16, const float* __restrict__ bias,
        float* __restrict__ out, int N) {
    __shared__ float wlds[4][64];
    __shared__ int slds[4][64];
    const int wid = threadIdx.x >> 6;
    const int n = blockIdx.x * 4 + wid;
    if (n >= N) return;
    const int lane = threadIdx.x & 63;
    const int half = lane >> 5;
    const int l32 = lane & 31;
    const int start = offsets[n], end = offsets[n + 1];
    const float ad = a_d[n];
    float accx = 0.0f, accy = 0.0f, den = 0.0f;
    const int loff = l32 << 1;

    for (int e0 = start; e0 < end; e0 += 64) {
        const int cnt = min(64, end - e0);
        if (lane < cnt) {
            int sB = srcS[e0 + lane];
            slds[wid][lane] = sB;
            float ev = a_s[sB] + ad;
            ev = fmaxf(ev, NEG_SLOPE * ev);
            wlds[wid][lane] = exp2f(ev);
        }
        int j = half;
        for (; j + 8 <= cnt + half; j += 8) {
            const int s0 = slds[wid][j + 0];
            const int s1 = slds[wid][j + 2];
            const int s2 = slds[wid][j + 4];
            const int s3 = slds[wid][j + 6];
            const float w0 = wlds[wid][j + 0];
            const float w1 = wlds[wid][j + 2];
            const float w2 = wlds[wid][j + 4];
            const float w3 = wlds[wid][j + 6];
            const unsigned int h0 = *(const unsigned int*)&hW16[((size_t)s0 << 6) + loff];
            const unsigned int h1 = *(const unsigned int*)&hW16[((size_t)s1 << 6) + loff];
            const unsigned int h2 = *(const unsigned int*)&hW16[((size_t)s2 << 6) + loff];
            const unsigned int h3 = *(const unsigned int*)&hW16[((size_t)s3 << 6) + loff];
            accx += w0 * b2f_lo(h0); accy += w0 * b2f_hi(h0);
            accx += w1 * b2f_lo(h1); accy += w1 * b2f_hi(h1);
            accx += w2 * b2f_lo(h2); accy += w2 * b2f_hi(h2);
            accx += w3 * b2f_lo(h3); accy += w3 * b2f_hi(h3);
            den += (w0 + w1) + (w2 + w3);
        }
        for (; j < cnt; j += 2) {
            const int s = slds[wid][j];
            const float w = wlds[wid][j];
            const unsigned int hv = *(const unsigned int*)&hW16[((size_t)s << 6) + loff];
            accx += w * b2f_lo(hv);
            accy += w * b2f_hi(hv);
            den += w;
        }
    }
    accx += __shfl_xor(accx, 32);
    accy += __shfl_xor(accy, 32);
    den  += __shfl_xor(den, 32);
    if (half == 0) {
        const float inv = 1.0f / (den + 1e-16f);
        float2 o = {accx * inv + bias[loff], accy * inv + bias[loff + 1]};
        *(float2*)&out[(size_t)n * 64 + loff] = o;
    }
}

// ------------- per-graph mean pool (batch is sorted) -------------
__global__ void pool_kernel(const float* __restrict__ h, const int* __restrict__ batch,
                            float* __restrict__ pooled, float* __restrict__ cnt,
                            int N, int nWaves) {
    const int w = blockIdx.x * 4 + (threadIdx.x >> 6);
    const int lane = threadIdx.x & 63;
    const int chunk = (N + nWaves - 1) / nWaves;
    int start = w * chunk;
    int end = min(N, start + chunk);
    if (start >= end) return;
    int curg = batch[start];
    int runStart = start;
    float acc = 0.0f;
    for (int n = start; n < end; n++) {
        int g = batch[n];
        if (g != curg) {
            atomicAdd(&pooled[curg * 64 + lane], acc);
            if (lane == 0) atomicAdd(&cnt[curg], (float)(n - runStart));
            acc = 0.0f; curg = g; runStart = n;
        }
        acc += h[(size_t)n * 64 + lane];
    }
    atomicAdd(&pooled[curg * 64 + lane], acc);
    if (lane == 0) atomicAdd(&cnt[curg], (float)(end - runStart));
}

// ------------- decoder head: one block per graph -------------
__global__ __launch_bounds__(256) void final_kernel(
        const float* __restrict__ pooled, const float* __restrict__ cnt,
        const float* __restrict__ gf, const float* __restrict__ Wg,
        const float* __restrict__ bg, const float* __restrict__ Wd1,
        const float* __restrict__ bd1, const float* __restrict__ gamma,
        const float* __restrict__ beta, const float* __restrict__ Wd2,
        const float* __restrict__ bd2, float* __restrict__ out, int G) {
    const int g = blockIdx.x;
    const int tid = threadIdx.x;
    const int lane = tid & 63;
    const int wave = tid >> 6;
    __shared__ float spg[128];
    __shared__ float sz[64];
    __shared__ float wred[8];

    if (tid < 64) {
        spg[tid] = pooled[g * 64 + tid] / fmaxf(cnt[g], 1.0f);
    } else if (tid < 128) {
        int c = tid - 64;
        float v = bg[c];
        #pragma unroll
        for (int k = 0; k < 4; k++) v += gf[g * 4 + k] * Wg[k * 64 + c];
        spg[64 + c] = fmaxf(v, 0.0f);
    }
    __syncthreads();
    if (tid < 64) {
        float v = bd1[tid];
        #pragma unroll 8
        for (int k = 0; k < 128; k++) v += spg[k] * Wd1[k * 64 + tid];
        v = v * gamma[tid] + beta[tid];
        sz[tid] = fmaxf(v, 0.0f);
    }
    __syncthreads();
    float v = bd2[tid];
    #pragma unroll 8
    for (int k = 0; k < 64; k++) v += sz[k] * Wd2[k * 256 + tid];
    float m = v;
    #pragma unroll
    for (int off = 32; off > 0; off >>= 1) m = fmaxf(m, __shfl_xor(m, off));
    if (lane == 0) wred[wave] = m;
    __syncthreads();
    float M = fmaxf(fmaxf(wred[0], wred[1]), fmaxf(wred[2], wred[3]));
    float e = expf(v - M);
    float s = e;
    #pragma unroll
    for (int off = 32; off > 0; off >>= 1) s += __shfl_xor(s, off);
    if (lane == 0) wred[4 + wave] = s;
    __syncthreads();
    float S = (wred[4] + wred[5]) + (wred[6] + wred[7]);
    out[g * 256 + tid] = e / S;
}

extern "C" void kernel_launch(void* const* d_in, const int* in_sizes, int n_in,
                              void* d_out, int out_size, void* d_ws, size_t ws_size,
                              hipStream_t stream) {
    const float* x     = (const float*)d_in[0];
    const int*   ei    = (const int*)  d_in[1];
    const int*   batch = (const int*)  d_in[2];
    const float* gf    = (const float*)d_in[3];
    const float* W_enc = (const float*)d_in[4];
    const float* b_enc = (const float*)d_in[5];
    const float* W1  = (const float*)d_in[6];
    const float* as1 = (const float*)d_in[7];
    const float* ad1 = (const float*)d_in[8];
    const float* b1  = (const float*)d_in[9];
    const float* W2  = (const float*)d_in[10];
    const float* as2 = (const float*)d_in[11];
    const float* ad2 = (const float*)d_in[12];
    const float* b2  = (const float*)d_in[13];
    const float* W3  = (const float*)d_in[14];
    const float* as3 = (const float*)d_in[15];
    const float* ad3 = (const float*)d_in[16];
    const float* b3  = (const float*)d_in[17];
    const float* Wg  = (const float*)d_in[18];
    const float* bg  = (const float*)d_in[19];
    const float* Wd1 = (const float*)d_in[20];
    const float* bd1 = (const float*)d_in[21];
    const float* gm  = (const float*)d_in[22];
    const float* bt  = (const float*)d_in[23];
    const float* Wd2 = (const float*)d_in[24];
    const float* bd2 = (const float*)d_in[25];

    const int N  = in_sizes[2];
    const int E  = in_sizes[1] / 2;
    const int G  = in_sizes[3] / 4;
    const int Et = E + N;

    unsigned short* h16a = (unsigned short*)d_ws;                // [N,256] bf16
    unsigned short* h16b = h16a + (size_t)N * 256;               // [N,256] bf16
    unsigned short* h1_16 = h16b + (size_t)N * 256;              // [N,64] bf16
    unsigned short* Wt1  = h1_16 + (size_t)N * 64;               // [256,64]
    unsigned short* Wt2  = Wt1 + 256 * 64;                       // [256,256]
    unsigned short* Wt3  = Wt2 + 256 * 256;                      // [64,256]
    float* h3     = (float*)(Wt3 + 64 * 256);                    // [N,64] fp32
    float* a_s    = h3 + (size_t)N * 64;                         // [N,4]
    float* a_d    = a_s + (size_t)N * 4;                         // [N,4]
    float* u1s    = a_d + (size_t)N * 4;                         // [64,4]
    float* u1d    = u1s + 256;                                   // [64,4]
    float* pooled = u1d + 256;                                   // [G,64]
    float* cnt    = pooled + (size_t)G * 64;                     // [G]
    int*   offsets = (int*)(cnt + G);                            // [N+1]
    int*   srcS    = offsets + (N + 1);                          // [Et]
    int*   counts  = srcS + Et;                                  // [N]
    int*   cursor  = counts + N;                                 // [N]
    int*   blockSums = cursor + N;                               // [cdiv(N,1024)]

    dim3 blk(256);
    auto cdiv = [](int a, int b) { return (a + b - 1) / b; };
    const int eBlocks = cdiv(Et, 256);
    const int rowBlocks = cdiv(N, 64);
    const int nScanBlocks = cdiv(N, 1024);

    // ---------------- CSR build + combined weight prep ----------------
    hipMemsetAsync(counts, 0, (size_t)N * sizeof(int), stream);
    edge_hist_kernel<<<eBlocks, blk, 0, stream>>>(ei, counts, E, Et);
    scan_blocks<<<nScanBlocks, 1024, 0, stream>>>(counts, blockSums, N);
    scan_sums<<<1, 64, 0, stream>>>(blockSums, nScanBlocks);
    scan_add<<<cdiv(N + 1, 256), blk, 0, stream>>>(counts, blockSums, offsets, cursor, N, Et);
    edge_sort_kernel<<<eBlocks, blk, 0, stream>>>(ei, cursor, srcS, E, Et);
    prep_kernel<<<385, blk, 0, stream>>>(W1, W2, W3, as1, ad1, Wt1, Wt2, Wt3, u1s, u1d);

    // encoder: x -> h1 bf16, + fused conv1 scores (fp32 acc . u1)
    gemm_enc<<<dim3(rowBlocks, 1), blk, 0, stream>>>(x, W_enc, b_enc, h1_16,
                                                     u1s, u1d, a_s, a_d, N, 32, 64);

    // ---------------- conv1 (H=4, in=64): aggregate FIRST (input space), then block-diag GEMM ----------------
    gat_agg_in64<<<cdiv(N, 4), blk, 0, stream>>>(offsets, srcS, (const float4*)a_s,
                                                 (const float4*)a_d, h1_16, h16a, N);
    gemm_bd64<<<dim3(rowBlocks, 4), blk, 0, stream>>>(h16a, Wt1, b1, h16b, N);   // h2 (+b1, ELU)

    // ---------------- conv2 (H=4, in=256): GEMM (+fused scores) -> aggregate ----------------
    gemm_mfma<2, 1><<<dim3(rowBlocks, 2), blk, 0, stream>>>(h16b, Wt2, h16a,
                                                            as2, ad2, a_s, a_d, N, 256, 256, 4);
    gat_fused4<<<cdiv(N, 4), blk, 0, stream>>>(offsets, srcS, (const float4*)a_s,
                                               (const float4*)a_d, h16a, b2, h16b, N);

    // ---------------- conv3 (H=1, in=256, no concat): GEMM (+fused scores) -> aggregate ----------------
    gemm_mfma<1, 1><<<dim3(rowBlocks, 1), blk, 0, stream>>>(h16b, Wt3, h1_16,
                                                            as3, ad3, a_s, a_d, N, 256, 64, 1);
    gat_fused1<<<cdiv(N, 4), blk, 0, stream>>>(offsets, srcS, a_s, a_d, h1_16, b3, h3, N);

    // ---------------- mean pool + decoder head ----------------
    hipMemsetAsync(pooled, 0, (size_t)G * 64 * sizeof(float), stream);
    hipMemsetAsync(cnt, 0, (size_t)G * sizeof(float), stream);
    pool_kernel<<<512, blk, 0, stream>>>(h3, batch, pooled, cnt, N, 512 * 4);
    final_kernel<<<G, blk, 0, stream>>>(pooled, cnt, gf, Wg, bg, Wd1, bd1, gm, bt, Wd2, bd2,
                                        (float*)d_out, G);
}